// Round 2
// baseline (996.790 us; speedup 1.0000x reference)
//
#include <hip/hip_runtime.h>
#include <hip/hip_bf16.h>

typedef __hip_bfloat16 bf16;

#define B_    64
#define T_    50
#define BT    3200
#define N_    22
#define C_    64
#define O_    64
#define NO    (N_ * O_)        // 1408
#define NN    (N_ * N_)        // 484
#define BTN   70400
#define ELEMS 4505600          // BT * N_ * O_

static __device__ __forceinline__ float bf2f(bf16 v) { return __bfloat162float(v); }
static __device__ __forceinline__ bf16  f2bf(float v) { return __float2bfloat16(v); }

// ---------------------------------------------------------------------------
// Kernel 1: build dense softmax adjacency tensors A_s, A_c in layout
// A[(i*N+j)*O + o]  (lane-o contiguous for coalesced reads in main_pass).
// A includes the diagonal (main_pass special-cases j==i to use h0).
// ---------------------------------------------------------------------------
__global__ void build_A_kernel(const float* __restrict__ e_s, const int* __restrict__ rs,
                               const int* __restrict__ cs, int nnz_s,
                               const float* __restrict__ e_c, const int* __restrict__ rc,
                               const int* __restrict__ cc, int nnz_c,
                               float* __restrict__ A_s, float* __restrict__ A_c) {
    int id = blockIdx.x * blockDim.x + threadIdx.x;
    if (id >= 2 * O_ * N_) return;
    int t   = id / (O_ * N_);
    int rem = id % (O_ * N_);
    int o   = rem / N_;
    int i   = rem % N_;
    const float* e    = t ? e_c : e_s;
    const int*   rows = t ? rc  : rs;
    const int*   cols = t ? cc  : cs;
    int          nnz  = t ? nnz_c : nnz_s;
    float*       A    = t ? A_c : A_s;

    float row[N_];
    #pragma unroll
    for (int j = 0; j < N_; j++) row[j] = 0.f;
    float s = 0.f;
    for (int k = 0; k < nnz; k++) {
        if (rows[k] == i) {
            float v = expf(e[o * nnz + k]);   // softmax over sparse entries;
            row[cols[k]] = v;                 // NEG entries underflow to exactly 0
            s += v;
        }
    }
    float inv = 1.f / s;
    for (int j = 0; j < N_; j++) A[(i * N_ + j) * O_ + o] = row[j] * inv;
}

// ---------------------------------------------------------------------------
// Kernel 2: per-(b,t) fused pass.
//   x tile -> LDS; closed-form dis; h0/h1 (sym,con) + dis@W_dis; A/att mixing;
//   writes xs,yc,z (bf16 staging) and per-block BN partial sums (f32, from
//   unrounded accumulators).
// ---------------------------------------------------------------------------
__launch_bounds__(256)
__global__ void main_pass(const float* __restrict__ x, const float* __restrict__ Wsym,
                          const float* __restrict__ Wcon, const float* __restrict__ Wdis,
                          const float* __restrict__ att, const float* __restrict__ bdis,
                          const float* __restrict__ A_s, const float* __restrict__ A_c,
                          bf16* __restrict__ xs, bf16* __restrict__ yc,
                          bf16* __restrict__ z, float* __restrict__ part1) {
    __shared__ float xt[NO];
    __shared__ float dt[NO];
    __shared__ float h1s[NO];
    __shared__ float h1c[NO];
    __shared__ float hdw[NO];
    __shared__ float sS1[C_];
    __shared__ float sS2[C_];
    __shared__ float red[256];

    const int bt  = blockIdx.x;
    const int tid = threadIdx.x;
    const size_t base = (size_t)bt * NO;

    for (int idx = tid; idx < NO; idx += 256) xt[idx] = x[base + idx];
    __syncthreads();

    if (tid < C_) {
        float s = 0.f, s2 = 0.f;
        #pragma unroll
        for (int i = 0; i < N_; i++) { float v = xt[i * C_ + tid]; s += v; s2 += v * v; }
        sS1[tid] = s; sS2[tid] = s2;
    }
    __syncthreads();

    // dis[j,c] = sqrt(S2 - 2 x S1 + N x^2) + 1e-8   (sum over the other N axis)
    for (int idx = tid; idx < NO; idx += 256) {
        int c = idx & 63;
        float v  = xt[idx];
        float d2 = sS2[c] - 2.f * v * sS1[c] + (float)N_ * v * v;
        dt[idx] = sqrtf(fmaxf(d2, 0.f)) + 1e-8f;
    }
    __syncthreads();

    const int o  = tid & 63;
    const int ib = tid >> 6;          // wave-uniform

    float a0s[6], a1s[6], a0c[6], a1c[6], adw[6];
    #pragma unroll
    for (int k = 0; k < 6; k++) { a0s[k] = a1s[k] = a0c[k] = a1c[k] = adw[k] = 0.f; }

    // 5 small matmuls, weight loads hoisted to the c-loop (L1/L2-resident)
    for (int c = 0; c < C_; c++) {
        float w0s = Wsym[c * O_ + o];
        float w1s = Wsym[C_ * O_ + c * O_ + o];
        float w0c = Wcon[c * O_ + o];
        float w1c = Wcon[C_ * O_ + c * O_ + o];
        float wd  = Wdis[c * O_ + o];
        #pragma unroll
        for (int k = 0; k < 6; k++) {
            int i = ib + 4 * k;
            if (i < N_) {
                float xv = xt[i * C_ + c];
                float dv = dt[i * C_ + c];
                a0s[k] = fmaf(xv, w0s, a0s[k]);
                a1s[k] = fmaf(xv, w1s, a1s[k]);
                a0c[k] = fmaf(xv, w0c, a0c[k]);
                a1c[k] = fmaf(xv, w1c, a1c[k]);
                adw[k] = fmaf(dv, wd,  adw[k]);
            }
        }
    }
    #pragma unroll
    for (int k = 0; k < 6; k++) {
        int i = ib + 4 * k;
        if (i < N_) { h1s[i * O_ + o] = a1s[k]; h1c[i * O_ + o] = a1c[k]; hdw[i * O_ + o] = adw[k]; }
    }
    __syncthreads();

    float st[6];
    #pragma unroll
    for (int q = 0; q < 6; q++) st[q] = 0.f;
    float bd = bdis[o];

    #pragma unroll
    for (int k = 0; k < 6; k++) {
        int i = ib + 4 * k;
        if (i < N_) {
            float xsv = 0.f, ycv = 0.f, zv = 0.f;
            #pragma unroll
            for (int j = 0; j < N_; j++) {
                float as = A_s[(i * N_ + j) * O_ + o];
                float ac = A_c[(i * N_ + j) * O_ + o];
                float at = att[i * N_ + j];
                float hs = (j == i) ? a0s[k] : h1s[j * O_ + o];   // diag uses h0
                float hc = (j == i) ? a0c[k] : h1c[j * O_ + o];
                xsv = fmaf(as, hs, xsv);
                ycv = fmaf(ac, hc, ycv);
                zv  = fmaf(at, hdw[j * O_ + o], zv);
            }
            zv += bd;
            size_t oi = base + i * O_ + o;
            xs[oi] = f2bf(xsv); yc[oi] = f2bf(ycv); z[oi] = f2bf(zv);
            st[0] += xsv; st[1] += xsv * xsv;
            st[2] += ycv; st[3] += ycv * ycv;
            st[4] += zv;  st[5] += zv  * zv;
        }
    }

    // cross-wave reduce (4 threads share one o) -> per-block partials
    #pragma unroll
    for (int q = 0; q < 6; q++) {
        red[tid] = st[q];
        __syncthreads();
        if (tid < 64)
            part1[(size_t)bt * 384 + q * 64 + tid] =
                (red[tid] + red[tid + 64]) + (red[tid + 128] + red[tid + 192]);
        __syncthreads();
    }
}

// ---------------------------------------------------------------------------
// Kernel 3/5: reduce per-block partials -> per-channel BN affine (a = g*rstd,
// c = beta - mu*a), stored as scale[t*128 + {0,64} + o].
// ---------------------------------------------------------------------------
__global__ void reduce_stats(const float* __restrict__ part, int rowlen,
                             const float* __restrict__ gammas, const float* __restrict__ betas,
                             int gbase, float* __restrict__ scale) {
    const int t = blockIdx.x;
    const int tid = threadIdx.x;
    const int o = tid & 63, g = tid >> 6;
    const float* p = part + 2 * t * 64;
    float s = 0.f, s2 = 0.f;
    for (int bt = g; bt < BT; bt += 4) {
        s  += p[(size_t)bt * rowlen + o];
        s2 += p[(size_t)bt * rowlen + 64 + o];
    }
    __shared__ float rs[256], rs2[256];
    rs[tid] = s; rs2[tid] = s2;
    __syncthreads();
    if (tid < 64) {
        float S   = (rs[tid] + rs[tid + 64]) + (rs[tid + 128] + rs[tid + 192]);
        float SS  = (rs2[tid] + rs2[tid + 64]) + (rs2[tid + 128] + rs2[tid + 192]);
        const float invn = 1.f / (float)BTN;
        float mu   = S * invn;
        float var  = SS * invn - mu * mu;
        float rstd = rsqrtf(var + 1e-5f);
        float a = gammas[(gbase + t) * 64 + o] * rstd;
        float c = betas[(gbase + t) * 64 + o] - mu * a;
        scale[t * 128 + o]      = a;
        scale[t * 128 + 64 + o] = c;
    }
}

// ---------------------------------------------------------------------------
// Kernel 4: BN+ReLU+concat in LDS, 192-length channel mix with cat_w staged
// in LDS as bf16 (0.4% rel rounding, well under threshold; f32 would exceed
// the 64KB default LDS limit together with cat). Writes out2 (bf16) +
// BN partials (f32 from unrounded accumulators).
// ---------------------------------------------------------------------------
__launch_bounds__(256)
__global__ void mix_pass(const bf16* __restrict__ xs, const bf16* __restrict__ yc,
                         const bf16* __restrict__ z, const float* __restrict__ scale1,
                         const float* __restrict__ cat_w,
                         bf16* __restrict__ out2, float* __restrict__ part2) {
    __shared__ float cat[192 * N_];      // [f][i]
    __shared__ bf16  cwT[192 * 64];      // [f][o]
    __shared__ float red[256];

    const int bt  = blockIdx.x;
    const int tid = threadIdx.x;
    const size_t base = (size_t)bt * NO;

    for (int idx = tid; idx < 192 * 64; idx += 256) {
        int o = idx / 192, f = idx % 192;
        cwT[f * 64 + o] = f2bf(cat_w[idx]);
    }
    for (int idx = tid; idx < NO; idx += 256) {
        int i = idx >> 6, c = idx & 63;
        float v0 = bf2f(xs[base + idx]);
        float v1 = bf2f(yc[base + idx]);
        float v2 = bf2f(z [base + idx]);
        cat[c * N_ + i]          = fmaxf(fmaf(v0, scale1[c],       scale1[64 + c]),  0.f);
        cat[(64 + c) * N_ + i]   = fmaxf(fmaf(v1, scale1[128 + c], scale1[192 + c]), 0.f);
        cat[(128 + c) * N_ + i]  = fmaxf(fmaf(v2, scale1[256 + c], scale1[320 + c]), 0.f);
    }
    __syncthreads();

    const int o = tid & 63, ib = tid >> 6;
    float acc[6];
    #pragma unroll
    for (int k = 0; k < 6; k++) acc[k] = 0.f;

    for (int f = 0; f < 192; f++) {
        float w = bf2f(cwT[f * 64 + o]);
        #pragma unroll
        for (int k = 0; k < 6; k++) {
            int i = ib + 4 * k;
            if (i < N_) acc[k] = fmaf(w, cat[f * N_ + i], acc[k]);
        }
    }

    float s = 0.f, s2 = 0.f;
    #pragma unroll
    for (int k = 0; k < 6; k++) {
        int i = ib + 4 * k;
        if (i < N_) {
            float v = acc[k];
            out2[base + i * 64 + o] = f2bf(v);
            s += v; s2 += v * v;
        }
    }
    red[tid] = s; __syncthreads();
    if (tid < 64)
        part2[(size_t)bt * 128 + tid] =
            (red[tid] + red[tid + 64]) + (red[tid + 128] + red[tid + 192]);
    __syncthreads();
    red[tid] = s2; __syncthreads();
    if (tid < 64)
        part2[(size_t)bt * 128 + 64 + tid] =
            (red[tid] + red[tid + 64]) + (red[tid + 128] + red[tid + 192]);
}

// ---------------------------------------------------------------------------
// Kernel 6: final BN + ReLU + f32 store, vectorized (4 elems/thread).
// ---------------------------------------------------------------------------
__global__ void final_pass(const bf16* __restrict__ out2, const float* __restrict__ scale2,
                           float* __restrict__ out) {
    const int gid = blockIdx.x * 256 + threadIdx.x;
    const int idx = gid * 4;
    ushort4 u = reinterpret_cast<const ushort4*>(out2)[gid];
    const int o = idx & 63;   // idx % 4 == 0, 64 % 4 == 0 -> o..o+3 within channel dim
    bf16 b0 = *reinterpret_cast<bf16*>(&u.x);
    bf16 b1 = *reinterpret_cast<bf16*>(&u.y);
    bf16 b2 = *reinterpret_cast<bf16*>(&u.z);
    bf16 b3 = *reinterpret_cast<bf16*>(&u.w);
    float4 r;
    r.x = fmaxf(fmaf(bf2f(b0), scale2[o],     scale2[64 + o]),     0.f);
    r.y = fmaxf(fmaf(bf2f(b1), scale2[o + 1], scale2[64 + o + 1]), 0.f);
    r.z = fmaxf(fmaf(bf2f(b2), scale2[o + 2], scale2[64 + o + 2]), 0.f);
    r.w = fmaxf(fmaf(bf2f(b3), scale2[o + 3], scale2[64 + o + 3]), 0.f);
    reinterpret_cast<float4*>(out)[gid] = r;
}

// ---------------------------------------------------------------------------
extern "C" void kernel_launch(void* const* d_in, const int* in_sizes, int n_in,
                              void* d_out, int out_size, void* d_ws, size_t ws_size,
                              hipStream_t stream) {
    const float* x      = (const float*)d_in[0];
    const float* W_sym  = (const float*)d_in[1];
    const float* e_sym  = (const float*)d_in[2];
    const float* W_con  = (const float*)d_in[3];
    const float* e_con  = (const float*)d_in[4];
    const float* W_dis  = (const float*)d_in[5];
    const float* att    = (const float*)d_in[6];
    const float* b_dis  = (const float*)d_in[7];
    const float* cat_w  = (const float*)d_in[8];
    const float* gammas = (const float*)d_in[9];
    const float* betas  = (const float*)d_in[10];
    const int* rows_sym = (const int*)d_in[11];
    const int* cols_sym = (const int*)d_in[12];
    const int* rows_con = (const int*)d_in[13];
    const int* cols_con = (const int*)d_in[14];
    const int nnz_s = in_sizes[2] / 64;
    const int nnz_c = in_sizes[4] / 64;

    // workspace carve-up (f32 sections first, then bf16 staging; all 16B-aligned)
    char* p = (char*)d_ws;
    float* A_s    = (float*)p; p += (size_t)NN * O_ * 4;
    float* A_c    = (float*)p; p += (size_t)NN * O_ * 4;
    float* part1  = (float*)p; p += (size_t)BT * 384 * 4;
    float* part2  = (float*)p; p += (size_t)BT * 128 * 4;
    float* scale1 = (float*)p; p += 384 * 4;
    float* scale2 = (float*)p; p += 128 * 4;
    bf16*  xsb    = (bf16*)p;  p += (size_t)ELEMS * 2;
    bf16*  ycb    = (bf16*)p;  p += (size_t)ELEMS * 2;
    bf16*  zb     = (bf16*)p;  p += (size_t)ELEMS * 2;
    bf16*  out2   = (bf16*)p;  p += (size_t)ELEMS * 2;

    build_A_kernel<<<11, 256, 0, stream>>>(e_sym, rows_sym, cols_sym, nnz_s,
                                           e_con, rows_con, cols_con, nnz_c, A_s, A_c);
    main_pass<<<BT, 256, 0, stream>>>(x, W_sym, W_con, W_dis, att, b_dis,
                                      A_s, A_c, xsb, ycb, zb, part1);
    reduce_stats<<<3, 256, 0, stream>>>(part1, 384, gammas, betas, 0, scale1);
    mix_pass<<<BT, 256, 0, stream>>>(xsb, ycb, zb, scale1, cat_w, out2, part2);
    reduce_stats<<<1, 256, 0, stream>>>(part2, 128, gammas, betas, 3, scale2);
    final_pass<<<ELEMS / 1024, 256, 0, stream>>>(out2, scale2, (float*)d_out);
}

// Round 3
// 382.093 us; speedup vs baseline: 2.6088x; 2.6088x over previous
//
#include <hip/hip_runtime.h>
#include <hip/hip_bf16.h>

typedef __hip_bfloat16 bf16;

#define BT    3200
#define N_    22
#define O_    64
#define NO    1408           // N_*64
#define NN    484
#define BTN   70400
#define ELEMS 4505600        // BT*N_*64

static __device__ __forceinline__ float bf2f(bf16 v) { return __bfloat162float(v); }
static __device__ __forceinline__ bf16  f2bf(float v) { return __float2bfloat16(v); }
static __device__ __forceinline__ void unp(unsigned u, float& lo, float& hi) {
    lo = __uint_as_float(u << 16);
    hi = __uint_as_float(u & 0xffff0000u);
}

// ---------------------------------------------------------------------------
// Kernel 1: dense softmax adjacency, interleaved AA[((i*22+j)*64+o)*2 + t]
// (t=0 sym, t=1 con) so main_pass gets both coefficients in one b64 load.
// ---------------------------------------------------------------------------
__global__ void build_AA(const float* __restrict__ e_s, const int* __restrict__ rs,
                         const int* __restrict__ cs, int nnz_s,
                         const float* __restrict__ e_c, const int* __restrict__ rc,
                         const int* __restrict__ cc, int nnz_c,
                         float* __restrict__ AA) {
    int id = blockIdx.x * 256 + threadIdx.x;
    if (id >= 2 * 64 * N_) return;
    int t   = id / (64 * N_);
    int rem = id % (64 * N_);
    int o   = rem / N_;
    int i   = rem % N_;
    const float* e    = t ? e_c : e_s;
    const int*   rows = t ? rc  : rs;
    const int*   cols = t ? cc  : cs;
    int          nnz  = t ? nnz_c : nnz_s;

    float row[N_];
    #pragma unroll
    for (int j = 0; j < N_; j++) row[j] = 0.f;
    float s = 0.f;
    for (int k = 0; k < nnz; k++) {
        if (rows[k] == i) {
            float v = expf(e[o * nnz + k]);
            row[cols[k]] = v;
            s += v;
        }
    }
    float inv = 1.f / s;
    for (int j = 0; j < N_; j++) AA[((size_t)(i * N_ + j) * 64 + o) * 2 + t] = row[j] * inv;
}

// ---------------------------------------------------------------------------
// Kernel 2: per-(b,t) fused pass (v2).
//  - x tile float4-staged; dis closed-form
//  - 5 matmuls with float4 broadcast LDS reads (3 b128 / 4 c-steps)
//  - h1s/h1c/hdw interleaved -> one b128 read per (j)
//  - mixing uses full-A sum + diagonal correction A_ii*(h0-h1) (no branches)
//  - 2-sync partial reduction
// ---------------------------------------------------------------------------
__launch_bounds__(256)
__global__ void main_pass(const float* __restrict__ x, const float* __restrict__ Wsym,
                          const float* __restrict__ Wcon, const float* __restrict__ Wdis,
                          const float* __restrict__ att, const float* __restrict__ bdis,
                          const float* __restrict__ AA,
                          bf16* __restrict__ xs, bf16* __restrict__ yc,
                          bf16* __restrict__ z, float* __restrict__ part1) {
    __shared__ float xt[NO];          // [i][c]
    __shared__ float dt[1536];        // [i][c]; tail reused as 'red' after matmul
    __shared__ float hh[24 * 64 * 4]; // [j][o]{h1s,h1c,hdw,pad}
    __shared__ float attL[NN];
    __shared__ float sS1[64], sS2[64];
    float* red = dt;                  // 24*64 = 1536 floats, reused post-matmul

    const int bt  = blockIdx.x;
    const int tid = threadIdx.x;
    const size_t base = (size_t)bt * NO;

    for (int idx = tid; idx < NO / 4; idx += 256)
        ((float4*)xt)[idx] = ((const float4*)(x + base))[idx];
    for (int idx = tid; idx < NN; idx += 256) attL[idx] = att[idx];
    __syncthreads();

    if (tid < 64) {
        float s = 0.f, s2 = 0.f;
        #pragma unroll
        for (int i = 0; i < N_; i++) { float v = xt[i * 64 + tid]; s += v; s2 += v * v; }
        sS1[tid] = s; sS2[tid] = s2;
    }
    __syncthreads();

    for (int idx = tid; idx < NO; idx += 256) {
        int c = idx & 63;
        float v  = xt[idx];
        float d2 = sS2[c] - 2.f * v * sS1[c] + (float)N_ * v * v;
        dt[idx] = sqrtf(fmaxf(d2, 0.f)) + 1e-8f;
    }
    __syncthreads();

    const int o  = tid & 63;
    const int ib = tid >> 6;    // wave-uniform

    float a0s[6], a1s[6], a0c[6], a1c[6], adw[6];
    #pragma unroll
    for (int k = 0; k < 6; k++) { a0s[k] = a1s[k] = a0c[k] = a1c[k] = adw[k] = 0.f; }

    for (int c4 = 0; c4 < 64; c4 += 4) {
        float4 xv[6], dv[6];
        #pragma unroll
        for (int k = 0; k < 6; k++) {
            int i  = ib + 4 * k;
            int ii = (i < N_) ? i : 0;          // garbage accs for invalid k never used
            xv[k] = *(const float4*)&xt[ii * 64 + c4];
            dv[k] = *(const float4*)&dt[ii * 64 + c4];
        }
        #pragma unroll
        for (int cc = 0; cc < 4; cc++) {
            int c = c4 + cc;
            float w0s = Wsym[c * 64 + o];
            float w1s = Wsym[4096 + c * 64 + o];
            float w0c = Wcon[c * 64 + o];
            float w1c = Wcon[4096 + c * 64 + o];
            float wd  = Wdis[c * 64 + o];
            #pragma unroll
            for (int k = 0; k < 6; k++) {
                float xvv = ((const float*)&xv[k])[cc];
                float dvv = ((const float*)&dv[k])[cc];
                a0s[k] = fmaf(xvv, w0s, a0s[k]);
                a1s[k] = fmaf(xvv, w1s, a1s[k]);
                a0c[k] = fmaf(xvv, w0c, a0c[k]);
                a1c[k] = fmaf(xvv, w1c, a1c[k]);
                adw[k] = fmaf(dvv, wd,  adw[k]);
            }
        }
    }

    #pragma unroll
    for (int k = 0; k < 6; k++) {
        int i = ib + 4 * k;
        if (i < N_) {
            float4 hv; hv.x = a1s[k]; hv.y = a1c[k]; hv.z = adw[k]; hv.w = 0.f;
            *(float4*)&hh[(i * 64 + o) * 4] = hv;
        }
    }
    __syncthreads();   // also fences last dt reads before red-reuse

    float mxs[6], myc[6], mz[6];
    #pragma unroll
    for (int k = 0; k < 6; k++) { mxs[k] = myc[k] = mz[k] = 0.f; }

    for (int j = 0; j < N_; j++) {
        float4 h = *(const float4*)&hh[(j * 64 + o) * 4];
        #pragma unroll
        for (int k = 0; k < 6; k++) {
            int i  = ib + 4 * k;
            int ii = (i < N_) ? i : 0;
            float2 a2 = *(const float2*)&AA[((size_t)(ii * N_ + j) * 64 + o) * 2];
            float atv = attL[ii * N_ + j];
            mxs[k] = fmaf(a2.x, h.x, mxs[k]);
            myc[k] = fmaf(a2.y, h.y, myc[k]);
            mz[k]  = fmaf(atv,  h.z, mz[k]);
        }
    }

    float bd = bdis[o];
    float st0 = 0.f, st1 = 0.f, st2 = 0.f, st3 = 0.f, st4 = 0.f, st5 = 0.f;
    #pragma unroll
    for (int k = 0; k < 6; k++) {
        int i = ib + 4 * k;
        if (i < N_) {
            float2 ad = *(const float2*)&AA[((size_t)(i * 23) * 64 + o) * 2];  // diag
            float xsv = mxs[k] + ad.x * (a0s[k] - a1s[k]);
            float ycv = myc[k] + ad.y * (a0c[k] - a1c[k]);
            float zv  = mz[k] + bd;
            size_t oi = base + i * 64 + o;
            xs[oi] = f2bf(xsv); yc[oi] = f2bf(ycv); z[oi] = f2bf(zv);
            st0 += xsv; st1 += xsv * xsv;
            st2 += ycv; st3 += ycv * ycv;
            st4 += zv;  st5 += zv  * zv;
        }
    }

    red[(ib * 6 + 0) * 64 + o] = st0;
    red[(ib * 6 + 1) * 64 + o] = st1;
    red[(ib * 6 + 2) * 64 + o] = st2;
    red[(ib * 6 + 3) * 64 + o] = st3;
    red[(ib * 6 + 4) * 64 + o] = st4;
    red[(ib * 6 + 5) * 64 + o] = st5;
    __syncthreads();
    for (int qq = tid; qq < 384; qq += 256) {
        int q = qq >> 6, oo = qq & 63;
        part1[(size_t)bt * 384 + qq] =
            (red[q * 64 + oo] + red[(6 + q) * 64 + oo]) +
            (red[(12 + q) * 64 + oo] + red[(18 + q) * 64 + oo]);
    }
}

// ---------------------------------------------------------------------------
// Kernel 3: stage-A reduction: 3200 rows -> 100 rows (coalesced).
// ---------------------------------------------------------------------------
__global__ void reduce_stageA(const float* __restrict__ part1, float* __restrict__ partA) {
    const int g = blockIdx.x, tid = threadIdx.x;
    const float* p = part1 + (size_t)g * 32 * 384;
    float s0 = 0.f, s1 = 0.f;
    for (int r = 0; r < 32; r++) {
        s0 += p[r * 384 + tid];
        if (tid < 128) s1 += p[r * 384 + 256 + tid];
    }
    partA[(size_t)g * 384 + tid] = s0;
    if (tid < 128) partA[(size_t)g * 384 + 256 + tid] = s1;
}

// ---------------------------------------------------------------------------
// Kernel 4: final reduction + BN affine. Block b handles cols [b*128,b*128+128):
// sums (col<64) and sumsqs (col>=64); writes scale[b*128 + {0,64} + o].
// ---------------------------------------------------------------------------
__global__ void reduce_final(const float* __restrict__ part, int nrows, int rowlen,
                             const float* __restrict__ gammas, const float* __restrict__ betas,
                             int gbase, float* __restrict__ scale) {
    __shared__ float cs[256];
    const int b = blockIdx.x, tid = threadIdx.x;
    const int col  = b * 128 + (tid & 127);
    const int half = tid >> 7;
    float s = 0.f;
    for (int r = half; r < nrows; r += 2) s += part[(size_t)r * rowlen + col];
    cs[tid] = s;
    __syncthreads();
    if (tid < 128) cs[tid] = cs[tid] + cs[tid + 128];
    __syncthreads();
    if (tid < 64) {
        float S  = cs[tid];
        float SS = cs[64 + tid];
        const float invn = 1.f / (float)BTN;
        float mu   = S * invn;
        float var  = SS * invn - mu * mu;
        float rstd = rsqrtf(var + 1e-5f);
        float a = gammas[(gbase + b) * 64 + tid] * rstd;
        float c = betas[(gbase + b) * 64 + tid] - mu * a;
        scale[b * 128 + tid]      = a;
        scale[b * 128 + 64 + tid] = c;
    }
}

// ---------------------------------------------------------------------------
// Kernel 5: mix GEMM (v2): out2[r,o] = sum_f relu(bn(src_f[r])) * w[f,o]
// M=70400, N=64, K=192. 128-row tiles, 32-K chunks, thread = 8 rows x 4 cols.
// ---------------------------------------------------------------------------
__launch_bounds__(256)
__global__ void mix_pass(const bf16* __restrict__ xs, const bf16* __restrict__ yc,
                         const bf16* __restrict__ z, const float* __restrict__ scale1,
                         const float* __restrict__ cat_w,
                         bf16* __restrict__ out2, float* __restrict__ part2) {
    __shared__ float At[128 * 34];   // [r][kk], stride 34: 2-way max conflicts
    __shared__ float Bt[32 * 64];    // [kk][o]
    __shared__ float red[16 * 64];
    __shared__ float sL[384];

    const int tid = threadIdx.x;
    const int R0  = blockIdx.x * 128;
    const int tx  = tid & 15, ty = tid >> 4;

    for (int idx = tid; idx < 384; idx += 256) sL[idx] = scale1[idx];
    __syncthreads();

    float acc[8][4];
    #pragma unroll
    for (int rr = 0; rr < 8; rr++)
        #pragma unroll
        for (int s = 0; s < 4; s++) acc[rr][s] = 0.f;

    const bf16* srcs[3] = { xs, yc, z };

    #pragma unroll 1
    for (int q = 0; q < 6; q++) {
        const bf16* src = srcs[q >> 1];
        const int t3    = q >> 1;
        const int cbase = (q & 1) * 32;
        const int fbase = q * 32;

        {   // stage B chunk: Bt[kk][o] = cat_w[o*192 + fbase + kk]
            int o = tid & 63, g = tid >> 6;
            #pragma unroll
            for (int s = 0; s < 2; s++) {
                int f4 = g * 2 + s;   // 0..7
                float4 wv = *(const float4*)&cat_w[o * 192 + fbase + f4 * 4];
                Bt[(f4 * 4 + 0) * 64 + o] = wv.x;
                Bt[(f4 * 4 + 1) * 64 + o] = wv.y;
                Bt[(f4 * 4 + 2) * 64 + o] = wv.z;
                Bt[(f4 * 4 + 3) * 64 + o] = wv.w;
            }
        }
        {   // stage A chunk: BN+ReLU on the fly
            #pragma unroll
            for (int s = 0; s < 2; s++) {
                int seg = tid + 256 * s;          // 0..511
                int r = seg >> 2, cg = seg & 3;
                const bf16* sp = src + (size_t)(R0 + r) * 64 + cbase + cg * 8;
                uint4 u = *(const uint4*)sp;
                float v[8];
                unp(u.x, v[0], v[1]); unp(u.y, v[2], v[3]);
                unp(u.z, v[4], v[5]); unp(u.w, v[6], v[7]);
                int cb = cbase + cg * 8;
                #pragma unroll
                for (int e = 0; e < 8; e++) {
                    int c = cb + e;
                    v[e] = fmaxf(fmaf(v[e], sL[t3 * 128 + c], sL[t3 * 128 + 64 + c]), 0.f);
                }
                float* ap = &At[r * 34 + cg * 8];
                *(float2*)(ap + 0) = make_float2(v[0], v[1]);
                *(float2*)(ap + 2) = make_float2(v[2], v[3]);
                *(float2*)(ap + 4) = make_float2(v[4], v[5]);
                *(float2*)(ap + 6) = make_float2(v[6], v[7]);
            }
        }
        __syncthreads();

        for (int kk = 0; kk < 32; kk++) {
            float4 b = *(const float4*)&Bt[kk * 64 + tx * 4];
            #pragma unroll
            for (int rr = 0; rr < 8; rr++) {
                float a = At[(ty * 8 + rr) * 34 + kk];
                acc[rr][0] = fmaf(a, b.x, acc[rr][0]);
                acc[rr][1] = fmaf(a, b.y, acc[rr][1]);
                acc[rr][2] = fmaf(a, b.z, acc[rr][2]);
                acc[rr][3] = fmaf(a, b.w, acc[rr][3]);
            }
        }
        __syncthreads();
    }

    // epilogue: bf16 stores + per-column BN partials
    float csum[4] = {0.f, 0.f, 0.f, 0.f}, csq[4] = {0.f, 0.f, 0.f, 0.f};
    #pragma unroll
    for (int rr = 0; rr < 8; rr++) {
        int R = R0 + ty * 8 + rr;
        ushort4 uo;
        bf16 h0 = f2bf(acc[rr][0]); uo.x = *reinterpret_cast<unsigned short*>(&h0);
        bf16 h1 = f2bf(acc[rr][1]); uo.y = *reinterpret_cast<unsigned short*>(&h1);
        bf16 h2 = f2bf(acc[rr][2]); uo.z = *reinterpret_cast<unsigned short*>(&h2);
        bf16 h3 = f2bf(acc[rr][3]); uo.w = *reinterpret_cast<unsigned short*>(&h3);
        *reinterpret_cast<ushort4*>(out2 + (size_t)R * 64 + tx * 4) = uo;
        #pragma unroll
        for (int s = 0; s < 4; s++) {
            csum[s] += acc[rr][s];
            csq[s]  += acc[rr][s] * acc[rr][s];
        }
    }
    #pragma unroll
    for (int s = 0; s < 4; s++) red[ty * 64 + tx * 4 + s] = csum[s];
    __syncthreads();
    if (tid < 64) {
        float t = 0.f;
        #pragma unroll
        for (int y = 0; y < 16; y++) t += red[y * 64 + tid];
        part2[(size_t)blockIdx.x * 128 + tid] = t;
    }
    __syncthreads();
    #pragma unroll
    for (int s = 0; s < 4; s++) red[ty * 64 + tx * 4 + s] = csq[s];
    __syncthreads();
    if (tid < 64) {
        float t = 0.f;
        #pragma unroll
        for (int y = 0; y < 16; y++) t += red[y * 64 + tid];
        part2[(size_t)blockIdx.x * 128 + 64 + tid] = t;
    }
}

// ---------------------------------------------------------------------------
// Kernel 6: final BN + ReLU + f32 store (4 elems/thread).
// ---------------------------------------------------------------------------
__global__ void final_pass(const bf16* __restrict__ out2, const float* __restrict__ scale2,
                           float* __restrict__ out) {
    const int gid = blockIdx.x * 256 + threadIdx.x;
    const int idx = gid * 4;
    ushort4 u = reinterpret_cast<const ushort4*>(out2)[gid];
    const int o = idx & 63;
    float f0, f1, f2, f3;
    unp((unsigned)u.x | ((unsigned)u.y << 16), f0, f1);
    unp((unsigned)u.z | ((unsigned)u.w << 16), f2, f3);
    float4 r;
    r.x = fmaxf(fmaf(f0, scale2[o],     scale2[64 + o]),     0.f);
    r.y = fmaxf(fmaf(f1, scale2[o + 1], scale2[64 + o + 1]), 0.f);
    r.z = fmaxf(fmaf(f2, scale2[o + 2], scale2[64 + o + 2]), 0.f);
    r.w = fmaxf(fmaf(f3, scale2[o + 3], scale2[64 + o + 3]), 0.f);
    reinterpret_cast<float4*>(out)[gid] = r;
}

// ---------------------------------------------------------------------------
extern "C" void kernel_launch(void* const* d_in, const int* in_sizes, int n_in,
                              void* d_out, int out_size, void* d_ws, size_t ws_size,
                              hipStream_t stream) {
    const float* x      = (const float*)d_in[0];
    const float* W_sym  = (const float*)d_in[1];
    const float* e_sym  = (const float*)d_in[2];
    const float* W_con  = (const float*)d_in[3];
    const float* e_con  = (const float*)d_in[4];
    const float* W_dis  = (const float*)d_in[5];
    const float* att    = (const float*)d_in[6];
    const float* b_dis  = (const float*)d_in[7];
    const float* cat_w  = (const float*)d_in[8];
    const float* gammas = (const float*)d_in[9];
    const float* betas  = (const float*)d_in[10];
    const int* rows_sym = (const int*)d_in[11];
    const int* cols_sym = (const int*)d_in[12];
    const int* rows_con = (const int*)d_in[13];
    const int* cols_con = (const int*)d_in[14];
    const int nnz_s = in_sizes[2] / 64;
    const int nnz_c = in_sizes[4] / 64;

    char* p = (char*)d_ws;
    float* AA     = (float*)p; p += (size_t)NN * 64 * 2 * 4;
    float* part1  = (float*)p; p += (size_t)BT * 384 * 4;
    float* partA  = (float*)p; p += (size_t)100 * 384 * 4;
    float* part2  = (float*)p; p += (size_t)550 * 128 * 4;
    float* scale1 = (float*)p; p += 384 * 4;
    float* scale2 = (float*)p; p += 128 * 4;
    bf16*  xsb    = (bf16*)p;  p += (size_t)ELEMS * 2;
    bf16*  ycb    = (bf16*)p;  p += (size_t)ELEMS * 2;
    bf16*  zb     = (bf16*)p;  p += (size_t)ELEMS * 2;
    bf16*  out2   = (bf16*)p;  p += (size_t)ELEMS * 2;

    build_AA<<<11, 256, 0, stream>>>(e_sym, rows_sym, cols_sym, nnz_s,
                                     e_con, rows_con, cols_con, nnz_c, AA);
    main_pass<<<BT, 256, 0, stream>>>(x, W_sym, W_con, W_dis, att, b_dis, AA,
                                      xsb, ycb, zb, part1);
    reduce_stageA<<<100, 256, 0, stream>>>(part1, partA);
    reduce_final<<<3, 256, 0, stream>>>(partA, 100, 384, gammas, betas, 0, scale1);
    mix_pass<<<550, 256, 0, stream>>>(xsb, ycb, zb, scale1, cat_w, out2, part2);
    reduce_final<<<1, 256, 0, stream>>>(part2, 550, 128, gammas, betas, 3, scale2);
    final_pass<<<ELEMS / 1024, 256, 0, stream>>>(out2, scale2, (float*)d_out);
}

// Round 5
// 357.998 us; speedup vs baseline: 2.7843x; 1.0673x over previous
//
#include <hip/hip_runtime.h>
#include <hip/hip_bf16.h>

typedef __hip_bfloat16 bf16;
typedef __attribute__((ext_vector_type(8))) short bf16x8;
typedef __attribute__((ext_vector_type(4))) float f32x4;

#define BT    3200
#define N_    22
#define NO    1408           // N_*64
#define NN    484
#define BTN   70400
#define ELEMS 4505600        // BT*N_*64

static __device__ __forceinline__ float bf2f(bf16 v) { return __bfloat162float(v); }
static __device__ __forceinline__ bf16  f2bf(float v) { return __float2bfloat16(v); }
static __device__ __forceinline__ short fbf(float v) {
    bf16 h = __float2bfloat16(v);
    return *reinterpret_cast<short*>(&h);
}
static __device__ __forceinline__ void unp(unsigned u, float& lo, float& hi) {
    lo = __uint_as_float(u << 16);
    hi = __uint_as_float(u & 0xffff0000u);
}

// ---------------------------------------------------------------------------
// Kernel 1 (prep): blocks 0-10 build dense softmax AA[((i*22+j)*64+o)*2+t];
// blocks 11-26 pack W_{sym,con,dis} and cat_w into per-lane MFMA B-fragments
// (lane L of frag (ct,kc) holds B[k=kc*32+(L>>4)*8+j][n=ct_cols+(L&15)]).
// WB is packed but only CB is consumed this round (bisect: MFMA in mix only).
// ---------------------------------------------------------------------------
__global__ void prep_kernel(const float* __restrict__ e_s, const int* __restrict__ rs,
                            const int* __restrict__ cs, int nnz_s,
                            const float* __restrict__ e_c, const int* __restrict__ rc,
                            const int* __restrict__ cc, int nnz_c,
                            const float* __restrict__ Wsym, const float* __restrict__ Wcon,
                            const float* __restrict__ Wdis, const float* __restrict__ cat_w,
                            float* __restrict__ AA, short* __restrict__ WB,
                            short* __restrict__ CB) {
    const int tid = threadIdx.x;
    if (blockIdx.x < 11) {
        int id = blockIdx.x * 256 + tid;           // 0..2815
        if (id >= 2 * 64 * N_) return;
        int t   = id / (64 * N_);
        int rem = id % (64 * N_);
        int o   = rem / N_;
        int i   = rem % N_;
        const float* e    = t ? e_c : e_s;
        const int*   rows = t ? rc  : rs;
        const int*   cols = t ? cc  : cs;
        int          nnz  = t ? nnz_c : nnz_s;
        float row[N_];
        #pragma unroll
        for (int j = 0; j < N_; j++) row[j] = 0.f;
        float s = 0.f;
        for (int k = 0; k < nnz; k++) {
            if (rows[k] == i) {
                float v = expf(e[o * nnz + k]);
                row[cols[k]] = v;
                s += v;
            }
        }
        float inv = 1.f / s;
        for (int j = 0; j < N_; j++) AA[((size_t)(i * N_ + j) * 64 + o) * 2 + t] = row[j] * inv;
    } else {
        int pid = (blockIdx.x - 11) * 256 + tid;   // 0..4095
        if (pid < 2560) {
            int ct = pid >> 7, rem = pid & 127;
            int kc = rem >> 6, L = rem & 63;
            const float* Wsrc = (ct < 4)  ? Wsym :
                                (ct < 8)  ? Wsym + 4096 :
                                (ct < 12) ? Wcon :
                                (ct < 16) ? Wcon + 4096 : Wdis;
            int ncol  = (ct & 3) * 16 + (L & 15);
            int kbase = kc * 32 + (L >> 4) * 8;
            bf16x8 frag;
            #pragma unroll
            for (int j = 0; j < 8; j++) frag[j] = fbf(Wsrc[(kbase + j) * 64 + ncol]);
            ((bf16x8*)WB)[pid] = frag;
        } else {
            int gi = pid - 2560;
            int nt = gi / 384, rem = gi % 384;
            int kc = rem >> 6, L = rem & 63;
            int n = nt * 16 + (L & 15);
            int kbase = kc * 32 + (L >> 4) * 8;
            float4 w0 = *(const float4*)&cat_w[n * 192 + kbase];
            float4 w1 = *(const float4*)&cat_w[n * 192 + kbase + 4];
            bf16x8 frag;
            frag[0] = fbf(w0.x); frag[1] = fbf(w0.y); frag[2] = fbf(w0.z); frag[3] = fbf(w0.w);
            frag[4] = fbf(w1.x); frag[5] = fbf(w1.y); frag[6] = fbf(w1.z); frag[7] = fbf(w1.w);
            ((bf16x8*)CB)[gi] = frag;
        }
    }
}

// ---------------------------------------------------------------------------
// Kernel 2: per-(b,t) fused pass — R3 VALU version (known-good reference
// for the bisect; MFMA variant suspected buggy, reverted this round).
// ---------------------------------------------------------------------------
__launch_bounds__(256)
__global__ void main_pass(const float* __restrict__ x, const float* __restrict__ Wsym,
                          const float* __restrict__ Wcon, const float* __restrict__ Wdis,
                          const float* __restrict__ att, const float* __restrict__ bdis,
                          const float* __restrict__ AA,
                          bf16* __restrict__ xs, bf16* __restrict__ yc,
                          bf16* __restrict__ z, float* __restrict__ part1) {
    __shared__ float xt[NO];          // [i][c]
    __shared__ float dt[1536];        // [i][c]; tail reused as 'red' after matmul
    __shared__ float hh[24 * 64 * 4]; // [j][o]{h1s,h1c,hdw,pad}
    __shared__ float attL[NN];
    __shared__ float sS1[64], sS2[64];
    float* red = dt;                  // 24*64 = 1536 floats, reused post-matmul

    const int bt  = blockIdx.x;
    const int tid = threadIdx.x;
    const size_t base = (size_t)bt * NO;

    for (int idx = tid; idx < NO / 4; idx += 256)
        ((float4*)xt)[idx] = ((const float4*)(x + base))[idx];
    for (int idx = tid; idx < NN; idx += 256) attL[idx] = att[idx];
    __syncthreads();

    if (tid < 64) {
        float s = 0.f, s2 = 0.f;
        #pragma unroll
        for (int i = 0; i < N_; i++) { float v = xt[i * 64 + tid]; s += v; s2 += v * v; }
        sS1[tid] = s; sS2[tid] = s2;
    }
    __syncthreads();

    for (int idx = tid; idx < NO; idx += 256) {
        int c = idx & 63;
        float v  = xt[idx];
        float d2 = sS2[c] - 2.f * v * sS1[c] + (float)N_ * v * v;
        dt[idx] = sqrtf(fmaxf(d2, 0.f)) + 1e-8f;
    }
    __syncthreads();

    const int o  = tid & 63;
    const int ib = tid >> 6;    // wave-uniform

    float a0s[6], a1s[6], a0c[6], a1c[6], adw[6];
    #pragma unroll
    for (int k = 0; k < 6; k++) { a0s[k] = a1s[k] = a0c[k] = a1c[k] = adw[k] = 0.f; }

    for (int c4 = 0; c4 < 64; c4 += 4) {
        float4 xv[6], dv[6];
        #pragma unroll
        for (int k = 0; k < 6; k++) {
            int i  = ib + 4 * k;
            int ii = (i < N_) ? i : 0;
            xv[k] = *(const float4*)&xt[ii * 64 + c4];
            dv[k] = *(const float4*)&dt[ii * 64 + c4];
        }
        #pragma unroll
        for (int cc = 0; cc < 4; cc++) {
            int c = c4 + cc;
            float w0s = Wsym[c * 64 + o];
            float w1s = Wsym[4096 + c * 64 + o];
            float w0c = Wcon[c * 64 + o];
            float w1c = Wcon[4096 + c * 64 + o];
            float wd  = Wdis[c * 64 + o];
            #pragma unroll
            for (int k = 0; k < 6; k++) {
                float xvv = ((const float*)&xv[k])[cc];
                float dvv = ((const float*)&dv[k])[cc];
                a0s[k] = fmaf(xvv, w0s, a0s[k]);
                a1s[k] = fmaf(xvv, w1s, a1s[k]);
                a0c[k] = fmaf(xvv, w0c, a0c[k]);
                a1c[k] = fmaf(xvv, w1c, a1c[k]);
                adw[k] = fmaf(dvv, wd,  adw[k]);
            }
        }
    }

    #pragma unroll
    for (int k = 0; k < 6; k++) {
        int i = ib + 4 * k;
        if (i < N_) {
            float4 hv; hv.x = a1s[k]; hv.y = a1c[k]; hv.z = adw[k]; hv.w = 0.f;
            *(float4*)&hh[(i * 64 + o) * 4] = hv;
        }
    }
    __syncthreads();   // also fences last dt reads before red-reuse

    float mxs[6], myc[6], mz[6];
    #pragma unroll
    for (int k = 0; k < 6; k++) { mxs[k] = myc[k] = mz[k] = 0.f; }

    for (int j = 0; j < N_; j++) {
        float4 h = *(const float4*)&hh[(j * 64 + o) * 4];
        #pragma unroll
        for (int k = 0; k < 6; k++) {
            int i  = ib + 4 * k;
            int ii = (i < N_) ? i : 0;
            float2 a2 = *(const float2*)&AA[((size_t)(ii * N_ + j) * 64 + o) * 2];
            float atv = attL[ii * N_ + j];
            mxs[k] = fmaf(a2.x, h.x, mxs[k]);
            myc[k] = fmaf(a2.y, h.y, myc[k]);
            mz[k]  = fmaf(atv,  h.z, mz[k]);
        }
    }

    float bd = bdis[o];
    float st0 = 0.f, st1 = 0.f, st2 = 0.f, st3 = 0.f, st4 = 0.f, st5 = 0.f;
    #pragma unroll
    for (int k = 0; k < 6; k++) {
        int i = ib + 4 * k;
        if (i < N_) {
            float2 ad2 = *(const float2*)&AA[((size_t)(i * 23) * 64 + o) * 2];  // diag
            float xsv = mxs[k] + ad2.x * (a0s[k] - a1s[k]);
            float ycv = myc[k] + ad2.y * (a0c[k] - a1c[k]);
            float zv  = mz[k] + bd;
            size_t oi = base + i * 64 + o;
            xs[oi] = f2bf(xsv); yc[oi] = f2bf(ycv); z[oi] = f2bf(zv);
            st0 += xsv; st1 += xsv * xsv;
            st2 += ycv; st3 += ycv * ycv;
            st4 += zv;  st5 += zv  * zv;
        }
    }

    red[(ib * 6 + 0) * 64 + o] = st0;
    red[(ib * 6 + 1) * 64 + o] = st1;
    red[(ib * 6 + 2) * 64 + o] = st2;
    red[(ib * 6 + 3) * 64 + o] = st3;
    red[(ib * 6 + 4) * 64 + o] = st4;
    red[(ib * 6 + 5) * 64 + o] = st5;
    __syncthreads();
    for (int qq = tid; qq < 384; qq += 256) {
        int q = qq >> 6, oo = qq & 63;
        part1[(size_t)bt * 384 + qq] =
            (red[q * 64 + oo] + red[(6 + q) * 64 + oo]) +
            (red[(12 + q) * 64 + oo] + red[(18 + q) * 64 + oo]);
    }
}

// ---------------------------------------------------------------------------
// Kernel 3: stage-A reduction: 3200 rows -> 100 rows.
// ---------------------------------------------------------------------------
__global__ void reduce_stageA(const float* __restrict__ part1, float* __restrict__ partA) {
    const int g = blockIdx.x, tid = threadIdx.x;
    const float* p = part1 + (size_t)g * 32 * 384;
    float s0 = 0.f, s1 = 0.f;
    for (int r = 0; r < 32; r++) {
        s0 += p[r * 384 + tid];
        if (tid < 128) s1 += p[r * 384 + 256 + tid];
    }
    partA[(size_t)g * 384 + tid] = s0;
    if (tid < 128) partA[(size_t)g * 384 + 256 + tid] = s1;
}

// ---------------------------------------------------------------------------
// Kernel 4: final reduction + BN affine (a=g*rstd, c=beta-mu*a).
// ---------------------------------------------------------------------------
__global__ void reduce_final(const float* __restrict__ part, int nrows, int rowlen,
                             const float* __restrict__ gammas, const float* __restrict__ betas,
                             int gbase, float* __restrict__ scale) {
    __shared__ float cs[256];
    const int b = blockIdx.x, tid = threadIdx.x;
    const int col  = b * 128 + (tid & 127);
    const int half = tid >> 7;
    float s = 0.f;
    for (int r = half; r < nrows; r += 2) s += part[(size_t)r * rowlen + col];
    cs[tid] = s;
    __syncthreads();
    if (tid < 128) cs[tid] = cs[tid] + cs[tid + 128];
    __syncthreads();
    if (tid < 64) {
        float S  = cs[tid];
        float SS = cs[64 + tid];
        const float invn = 1.f / (float)BTN;
        float mu   = S * invn;
        float var  = SS * invn - mu * mu;
        float rstd = rsqrtf(var + 1e-5f);
        float a = gammas[(gbase + b) * 64 + tid] * rstd;
        float c = betas[(gbase + b) * 64 + tid] - mu * a;
        scale[b * 128 + tid]      = a;
        scale[b * 128 + 64 + tid] = c;
    }
}

// ---------------------------------------------------------------------------
// Kernel 5: mix GEMM (MFMA, under test): out2 = relu(bn(cat)) @ cat_w^T.
// M=70400, K=192, N=64. BN+ReLU fused into A-fragment construction in
// registers; B-fragments pre-packed (CB). No LDS staging in the K-loop.
// ---------------------------------------------------------------------------
__launch_bounds__(256)
__global__ void mix_pass(const bf16* __restrict__ xs, const bf16* __restrict__ yc,
                         const bf16* __restrict__ z, const float* __restrict__ scale1,
                         const short* __restrict__ CB,
                         bf16* __restrict__ out2, float* __restrict__ part2) {
    __shared__ float sL[384];
    __shared__ float red[512];

    const int tid = threadIdx.x;
    const int w = tid >> 6, L = tid & 63;
    const int lane16 = L & 15, quad = L >> 4;
    const int R0 = blockIdx.x * 128 + w * 32;

    for (int idx = tid; idx < 384; idx += 256) sL[idx] = scale1[idx];
    __syncthreads();

    const bf16* srcs[3] = { xs, yc, z };

    f32x4 acc[2][4];
    #pragma unroll
    for (int rt = 0; rt < 2; rt++)
        #pragma unroll
        for (int nt = 0; nt < 4; nt++)
            acc[rt][nt] = (f32x4){0.f, 0.f, 0.f, 0.f};

    #pragma unroll
    for (int kc = 0; kc < 6; kc++) {
        const int src = kc >> 1;
        const int c0  = (kc & 1) * 32 + quad * 8;
        bf16x8 av[2];
        #pragma unroll
        for (int rt = 0; rt < 2; rt++) {
            int row = R0 + rt * 16 + lane16;
            uint4 u = *(const uint4*)(srcs[src] + (size_t)row * 64 + c0);
            float v[8];
            unp(u.x, v[0], v[1]); unp(u.y, v[2], v[3]);
            unp(u.z, v[4], v[5]); unp(u.w, v[6], v[7]);
            #pragma unroll
            for (int e = 0; e < 8; e++) {
                float t = fmaxf(fmaf(v[e], sL[src * 128 + c0 + e],
                                     sL[src * 128 + 64 + c0 + e]), 0.f);
                av[rt][e] = fbf(t);
            }
        }
        #pragma unroll
        for (int nt = 0; nt < 4; nt++) {
            bf16x8 bw = ((const bf16x8*)CB)[(nt * 6 + kc) * 64 + L];
            acc[0][nt] = __builtin_amdgcn_mfma_f32_16x16x32_bf16(av[0], bw, acc[0][nt], 0, 0, 0);
            acc[1][nt] = __builtin_amdgcn_mfma_f32_16x16x32_bf16(av[1], bw, acc[1][nt], 0, 0, 0);
        }
    }

    // epilogue: stores + per-column BN partials (C layout col=lane&15, row=quad*4+r)
    float s[4]  = {0.f, 0.f, 0.f, 0.f};
    float s2[4] = {0.f, 0.f, 0.f, 0.f};
    #pragma unroll
    for (int rt = 0; rt < 2; rt++)
        #pragma unroll
        for (int nt = 0; nt < 4; nt++)
            #pragma unroll
            for (int r = 0; r < 4; r++) {
                int row = R0 + rt * 16 + quad * 4 + r;
                int col = nt * 16 + lane16;
                float v = acc[rt][nt][r];
                out2[(size_t)row * 64 + col] = f2bf(v);
                s[nt] += v; s2[nt] += v * v;
            }
    #pragma unroll
    for (int nt = 0; nt < 4; nt++) {
        s[nt]  += __shfl_xor(s[nt], 16);
        s[nt]  += __shfl_xor(s[nt], 32);
        s2[nt] += __shfl_xor(s2[nt], 16);
        s2[nt] += __shfl_xor(s2[nt], 32);
    }
    if (quad == 0) {
        #pragma unroll
        for (int nt = 0; nt < 4; nt++) {
            red[w * 64 + nt * 16 + lane16]       = s[nt];
            red[256 + w * 64 + nt * 16 + lane16] = s2[nt];
        }
    }
    __syncthreads();
    if (tid < 64) {
        float t = red[tid] + red[64 + tid] + red[128 + tid] + red[192 + tid];
        part2[(size_t)blockIdx.x * 128 + tid] = t;
    } else if (tid < 128) {
        int c = tid - 64;
        float t = red[256 + c] + red[320 + c] + red[384 + c] + red[448 + c];
        part2[(size_t)blockIdx.x * 128 + 64 + c] = t;
    }
}

// ---------------------------------------------------------------------------
// Kernel 6: final BN + ReLU + f32 store (4 elems/thread).
// ---------------------------------------------------------------------------
__global__ void final_pass(const bf16* __restrict__ out2, const float* __restrict__ scale2,
                           float* __restrict__ out) {
    const int gid = blockIdx.x * 256 + threadIdx.x;
    const int idx = gid * 4;
    ushort4 u = reinterpret_cast<const ushort4*>(out2)[gid];
    const int o = idx & 63;
    float f0, f1, f2, f3;
    unp((unsigned)u.x | ((unsigned)u.y << 16), f0, f1);
    unp((unsigned)u.z | ((unsigned)u.w << 16), f2, f3);
    float4 r;
    r.x = fmaxf(fmaf(f0, scale2[o],     scale2[64 + o]),     0.f);
    r.y = fmaxf(fmaf(f1, scale2[o + 1], scale2[64 + o + 1]), 0.f);
    r.z = fmaxf(fmaf(f2, scale2[o + 2], scale2[64 + o + 2]), 0.f);
    r.w = fmaxf(fmaf(f3, scale2[o + 3], scale2[64 + o + 3]), 0.f);
    reinterpret_cast<float4*>(out)[gid] = r;
}

// ---------------------------------------------------------------------------
extern "C" void kernel_launch(void* const* d_in, const int* in_sizes, int n_in,
                              void* d_out, int out_size, void* d_ws, size_t ws_size,
                              hipStream_t stream) {
    const float* x      = (const float*)d_in[0];
    const float* W_sym  = (const float*)d_in[1];
    const float* e_sym  = (const float*)d_in[2];
    const float* W_con  = (const float*)d_in[3];
    const float* e_con  = (const float*)d_in[4];
    const float* W_dis  = (const float*)d_in[5];
    const float* att    = (const float*)d_in[6];
    const float* b_dis  = (const float*)d_in[7];
    const float* cat_w  = (const float*)d_in[8];
    const float* gammas = (const float*)d_in[9];
    const float* betas  = (const float*)d_in[10];
    const int* rows_sym = (const int*)d_in[11];
    const int* cols_sym = (const int*)d_in[12];
    const int* rows_con = (const int*)d_in[13];
    const int* cols_con = (const int*)d_in[14];
    const int nnz_s = in_sizes[2] / 64;
    const int nnz_c = in_sizes[4] / 64;

    char* p = (char*)d_ws;
    float* AA     = (float*)p; p += (size_t)NN * 64 * 2 * 4;
    float* part1  = (float*)p; p += (size_t)BT * 384 * 4;
    float* partA  = (float*)p; p += (size_t)100 * 384 * 4;
    float* part2  = (float*)p; p += (size_t)550 * 128 * 4;
    float* scale1 = (float*)p; p += 384 * 4;
    float* scale2 = (float*)p; p += 128 * 4;
    short* WB     = (short*)p; p += (size_t)2560 * 8 * 2;
    short* CB     = (short*)p; p += (size_t)1536 * 8 * 2;
    bf16*  xsb    = (bf16*)p;  p += (size_t)ELEMS * 2;
    bf16*  ycb    = (bf16*)p;  p += (size_t)ELEMS * 2;
    bf16*  zb     = (bf16*)p;  p += (size_t)ELEMS * 2;
    bf16*  out2   = (bf16*)p;  p += (size_t)ELEMS * 2;

    prep_kernel<<<27, 256, 0, stream>>>(e_sym, rows_sym, cols_sym, nnz_s,
                                        e_con, rows_con, cols_con, nnz_c,
                                        W_sym, W_con, W_dis, cat_w, AA, WB, CB);
    main_pass<<<BT, 256, 0, stream>>>(x, W_sym, W_con, W_dis, att, b_dis, AA,
                                      xsb, ycb, zb, part1);
    reduce_stageA<<<100, 256, 0, stream>>>(part1, partA);
    reduce_final<<<3, 256, 0, stream>>>(partA, 100, 384, gammas, betas, 0, scale1);
    mix_pass<<<550, 256, 0, stream>>>(xsb, ycb, zb, scale1, CB, out2, part2);
    reduce_final<<<1, 256, 0, stream>>>(part2, 550, 128, gammas, betas, 3, scale2);
    final_pass<<<ELEMS / 1024, 256, 0, stream>>>(out2, scale2, (float*)d_out);
}

// Round 6
// 340.187 us; speedup vs baseline: 2.9301x; 1.0524x over previous
//
#include <hip/hip_runtime.h>
#include <hip/hip_bf16.h>

typedef __hip_bfloat16 bf16;
typedef __attribute__((ext_vector_type(8))) short bf16x8;
typedef __attribute__((ext_vector_type(4))) float f32x4;

#define BT    3200
#define N_    22
#define NO    1408           // N_*64
#define NN    484
#define BTN   70400
#define ELEMS 4505600        // BT*N_*64

static __device__ __forceinline__ bf16  f2bf(float v) { return __float2bfloat16(v); }
static __device__ __forceinline__ short fbf(float v) {
    bf16 h = __float2bfloat16(v);
    return *reinterpret_cast<short*>(&h);
}
static __device__ __forceinline__ float sbf(short s) {
    return __uint_as_float(((unsigned)(unsigned short)s) << 16);
}
static __device__ __forceinline__ void unp(unsigned u, float& lo, float& hi) {
    lo = __uint_as_float(u << 16);
    hi = __uint_as_float(u & 0xffff0000u);
}

// ---------------------------------------------------------------------------
// Kernel 1 (prep): blocks 0-10 build dense softmax AA[((i*22+j)*64+o)*2+t];
// blocks 11-16 pack cat_w into MFMA B-fragments CB (verified in R5).
// ---------------------------------------------------------------------------
__global__ void prep_kernel(const float* __restrict__ e_s, const int* __restrict__ rs,
                            const int* __restrict__ cs, int nnz_s,
                            const float* __restrict__ e_c, const int* __restrict__ rc,
                            const int* __restrict__ cc, int nnz_c,
                            const float* __restrict__ cat_w,
                            float* __restrict__ AA, short* __restrict__ CB) {
    const int tid = threadIdx.x;
    if (blockIdx.x < 11) {
        int id = blockIdx.x * 256 + tid;           // 0..2815
        if (id >= 2 * 64 * N_) return;
        int t   = id / (64 * N_);
        int rem = id % (64 * N_);
        int o   = rem / N_;
        int i   = rem % N_;
        const float* e    = t ? e_c : e_s;
        const int*   rows = t ? rc  : rs;
        const int*   cols = t ? cc  : cs;
        int          nnz  = t ? nnz_c : nnz_s;
        float row[N_];
        #pragma unroll
        for (int j = 0; j < N_; j++) row[j] = 0.f;
        float s = 0.f;
        for (int k = 0; k < nnz; k++) {
            if (rows[k] == i) {
                float v = expf(e[o * nnz + k]);
                row[cols[k]] = v;
                s += v;
            }
        }
        float inv = 1.f / s;
        for (int j = 0; j < N_; j++) AA[((size_t)(i * N_ + j) * 64 + o) * 2 + t] = row[j] * inv;
    } else {
        int gi = (blockIdx.x - 11) * 256 + tid;    // 0..1535
        if (gi >= 1536) return;
        int nt = gi / 384, rem = gi % 384;
        int kc = rem >> 6, L = rem & 63;
        int n = nt * 16 + (L & 15);
        int kbase = kc * 32 + (L >> 4) * 8;
        float4 w0 = *(const float4*)&cat_w[n * 192 + kbase];
        float4 w1 = *(const float4*)&cat_w[n * 192 + kbase + 4];
        bf16x8 frag;
        frag[0] = fbf(w0.x); frag[1] = fbf(w0.y); frag[2] = fbf(w0.z); frag[3] = fbf(w0.w);
        frag[4] = fbf(w1.x); frag[5] = fbf(w1.y); frag[6] = fbf(w1.z); frag[7] = fbf(w1.w);
        ((bf16x8*)CB)[gi] = frag;
    }
}

// ---------------------------------------------------------------------------
// Kernel 2: per-bt stats + cast: xb = bf16(x), db = bf16(dis closed-form).
// One wave per bt; thread = channel c (owns its column stats, no sharing).
// ---------------------------------------------------------------------------
__global__ void pre_pass(const float* __restrict__ x,
                         bf16* __restrict__ xb, bf16* __restrict__ db) {
    __shared__ float xt[NO];
    const int bt = blockIdx.x, tid = threadIdx.x;    // 64 threads
    const size_t base = (size_t)bt * NO;
    for (int idx = tid; idx < NO / 4; idx += 64)
        ((float4*)xt)[idx] = ((const float4*)(x + base))[idx];
    __syncthreads();
    float s = 0.f, s2 = 0.f;
    #pragma unroll
    for (int i = 0; i < N_; i++) { float v = xt[i * 64 + tid]; s += v; s2 += v * v; }
    #pragma unroll
    for (int i = 0; i < N_; i++) {
        float v  = xt[i * 64 + tid];
        float d2 = s2 - 2.f * v * s + (float)N_ * v * v;
        float d  = sqrtf(fmaxf(d2, 0.f)) + 1e-8f;
        xb[base + i * 64 + tid] = f2bf(v);
        db[base + i * 64 + tid] = f2bf(d);
    }
}

// ---------------------------------------------------------------------------
// Kernel 3: h GEMM — clone of the VERIFIED mix_pass MFMA skeleton.
// grid (550, 5): y picks {h0s,h1s,h0c,h1c,hdw} = {x@Ws0, x@Ws1, x@Wc0, x@Wc1,
// dis@Wd}. A = bf16 rows loaded directly as fragments; B built from W in LDS.
// ---------------------------------------------------------------------------
__launch_bounds__(256)
__global__ void h_gemm(const bf16* __restrict__ xb, const bf16* __restrict__ db,
                       const float* __restrict__ Wsym, const float* __restrict__ Wcon,
                       const float* __restrict__ Wdis, bf16* __restrict__ hbuf) {
    __shared__ float WL[4096];   // W[k][n], k=c 0..63, n=o 0..63
    const int tid = threadIdx.x;
    const int y = blockIdx.y;
    const float* Wsrc = (y == 0) ? Wsym :
                        (y == 1) ? Wsym + 4096 :
                        (y == 2) ? Wcon :
                        (y == 3) ? Wcon + 4096 : Wdis;
    const bf16* src = (y < 4) ? xb : db;

    for (int idx = tid; idx < 1024; idx += 256)
        ((float4*)WL)[idx] = ((const float4*)Wsrc)[idx];
    __syncthreads();

    const int w = tid >> 6, L = tid & 63;
    const int lane16 = L & 15, quad = L >> 4;
    const int R0 = blockIdx.x * 128 + w * 32;

    // B-fragments: lane L, reg j holds B[k = kc*32 + quad*8 + j][n = nt*16 + lane16]
    bf16x8 bfr[2][4];
    #pragma unroll
    for (int kc = 0; kc < 2; kc++)
        #pragma unroll
        for (int nt = 0; nt < 4; nt++) {
            int n  = nt * 16 + lane16;
            int kb = kc * 32 + quad * 8;
            #pragma unroll
            for (int j = 0; j < 8; j++) bfr[kc][nt][j] = fbf(WL[(kb + j) * 64 + n]);
        }

    f32x4 acc[2][4];
    #pragma unroll
    for (int rt = 0; rt < 2; rt++)
        #pragma unroll
        for (int nt = 0; nt < 4; nt++) acc[rt][nt] = (f32x4){0.f, 0.f, 0.f, 0.f};

    #pragma unroll
    for (int kc = 0; kc < 2; kc++) {
        bf16x8 av[2];
        #pragma unroll
        for (int rt = 0; rt < 2; rt++) {
            int row = R0 + rt * 16 + lane16;
            av[rt] = *(const bf16x8*)(src + (size_t)row * 64 + kc * 32 + quad * 8);
        }
        #pragma unroll
        for (int nt = 0; nt < 4; nt++) {
            acc[0][nt] = __builtin_amdgcn_mfma_f32_16x16x32_bf16(av[0], bfr[kc][nt], acc[0][nt], 0, 0, 0);
            acc[1][nt] = __builtin_amdgcn_mfma_f32_16x16x32_bf16(av[1], bfr[kc][nt], acc[1][nt], 0, 0, 0);
        }
    }

    bf16* out = hbuf + (size_t)y * ELEMS;
    #pragma unroll
    for (int rt = 0; rt < 2; rt++)
        #pragma unroll
        for (int nt = 0; nt < 4; nt++)
            #pragma unroll
            for (int r = 0; r < 4; r++) {
                int row = R0 + rt * 16 + quad * 4 + r;
                int col = nt * 16 + lane16;
                out[(size_t)row * 64 + col] = f2bf(acc[rt][nt][r]);
            }
}

// ---------------------------------------------------------------------------
// Kernel 4: per-bt mixer (VALU, verbatim R5 mixing code): stage 5 h-planes,
// transform to hh/hd, A/att mixing + diag correction, stores + BN partials.
// ---------------------------------------------------------------------------
__launch_bounds__(256)
__global__ void mixer(const bf16* __restrict__ hbuf, const float* __restrict__ AA,
                      const float* __restrict__ att, const float* __restrict__ bdis,
                      bf16* __restrict__ xs, bf16* __restrict__ yc,
                      bf16* __restrict__ z, float* __restrict__ part1) {
    __shared__ __align__(16) short raw[5 * NO];       // 14080 B; reused as red
    __shared__ __align__(16) float hh[NO * 4];        // [i*64+o]{h1s,h1c,hdw,pad}
    __shared__ __align__(8)  float hd[NO * 2];        // [i*64+o]{h0s-h1s,h0c-h1c}
    __shared__ float attL[NN];
    float* red = (float*)raw;                         // 1536 floats needed, fits

    const int bt  = blockIdx.x;
    const int tid = threadIdx.x;
    const size_t base = (size_t)bt * NO;
    const int w = tid >> 6, L = tid & 63;

    for (int idx = tid; idx < 880; idx += 256) {      // 5 planes x 176 uint4
        int t = idx / 176, rem = idx - t * 176;
        ((uint4*)raw)[idx] = ((const uint4*)(hbuf + (size_t)t * ELEMS + base))[rem];
    }
    for (int idx = tid; idx < NN; idx += 256) attL[idx] = att[idx];
    __syncthreads();

    for (int idx = tid; idx < NO; idx += 256) {
        float h0s = sbf(raw[idx]);
        float h1s = sbf(raw[NO + idx]);
        float h0c = sbf(raw[2 * NO + idx]);
        float h1c = sbf(raw[3 * NO + idx]);
        float hw  = sbf(raw[4 * NO + idx]);
        hh[idx * 4 + 0] = h1s; hh[idx * 4 + 1] = h1c;
        hh[idx * 4 + 2] = hw;  hh[idx * 4 + 3] = 0.f;
        hd[idx * 2 + 0] = h0s - h1s;
        hd[idx * 2 + 1] = h0c - h1c;
    }
    __syncthreads();

    float mxs[6], myc[6], mz[6];
    #pragma unroll
    for (int k = 0; k < 6; k++) { mxs[k] = myc[k] = mz[k] = 0.f; }

    for (int j = 0; j < N_; j++) {
        float4 h = *(const float4*)&hh[(j * 64 + L) * 4];
        #pragma unroll
        for (int k = 0; k < 6; k++) {
            int i  = w + 4 * k;
            int ii = (i < N_) ? i : 0;
            float2 a2 = *(const float2*)&AA[((size_t)(ii * N_ + j) * 64 + L) * 2];
            float atv = attL[ii * N_ + j];
            mxs[k] = fmaf(a2.x, h.x, mxs[k]);
            myc[k] = fmaf(a2.y, h.y, myc[k]);
            mz[k]  = fmaf(atv,  h.z, mz[k]);
        }
    }

    float bd = bdis[L];
    float st0 = 0.f, st1 = 0.f, st2 = 0.f, st3 = 0.f, st4 = 0.f, st5 = 0.f;
    #pragma unroll
    for (int k = 0; k < 6; k++) {
        int i = w + 4 * k;
        if (i < N_) {
            float2 ad2 = *(const float2*)&AA[((size_t)(i * 23) * 64 + L) * 2];  // diag
            float2 dv  = *(const float2*)&hd[(i * 64 + L) * 2];
            float xsv = mxs[k] + ad2.x * dv.x;
            float ycv = myc[k] + ad2.y * dv.y;
            float zv  = mz[k] + bd;
            size_t oi = base + i * 64 + L;
            xs[oi] = f2bf(xsv); yc[oi] = f2bf(ycv); z[oi] = f2bf(zv);
            st0 += xsv; st1 += xsv * xsv;
            st2 += ycv; st3 += ycv * ycv;
            st4 += zv;  st5 += zv  * zv;
        }
    }

    red[(w * 6 + 0) * 64 + L] = st0;
    red[(w * 6 + 1) * 64 + L] = st1;
    red[(w * 6 + 2) * 64 + L] = st2;
    red[(w * 6 + 3) * 64 + L] = st3;
    red[(w * 6 + 4) * 64 + L] = st4;
    red[(w * 6 + 5) * 64 + L] = st5;
    __syncthreads();
    for (int qq = tid; qq < 384; qq += 256) {
        int q = qq >> 6, oo = qq & 63;
        part1[(size_t)bt * 384 + qq] =
            (red[q * 64 + oo] + red[(6 + q) * 64 + oo]) +
            (red[(12 + q) * 64 + oo] + red[(18 + q) * 64 + oo]);
    }
}

// ---------------------------------------------------------------------------
// Kernel 5: stage-A reduction: 3200 rows -> 100 rows.
// ---------------------------------------------------------------------------
__global__ void reduce_stageA(const float* __restrict__ part1, float* __restrict__ partA) {
    const int g = blockIdx.x, tid = threadIdx.x;
    const float* p = part1 + (size_t)g * 32 * 384;
    float s0 = 0.f, s1 = 0.f;
    for (int r = 0; r < 32; r++) {
        s0 += p[r * 384 + tid];
        if (tid < 128) s1 += p[r * 384 + 256 + tid];
    }
    partA[(size_t)g * 384 + tid] = s0;
    if (tid < 128) partA[(size_t)g * 384 + 256 + tid] = s1;
}

// ---------------------------------------------------------------------------
// Kernel 6: final reduction + BN affine (a=g*rstd, c=beta-mu*a).
// ---------------------------------------------------------------------------
__global__ void reduce_final(const float* __restrict__ part, int nrows, int rowlen,
                             const float* __restrict__ gammas, const float* __restrict__ betas,
                             int gbase, float* __restrict__ scale) {
    __shared__ float cs[256];
    const int b = blockIdx.x, tid = threadIdx.x;
    const int col  = b * 128 + (tid & 127);
    const int half = tid >> 7;
    float s = 0.f;
    for (int r = half; r < nrows; r += 2) s += part[(size_t)r * rowlen + col];
    cs[tid] = s;
    __syncthreads();
    if (tid < 128) cs[tid] = cs[tid] + cs[tid + 128];
    __syncthreads();
    if (tid < 64) {
        float S  = cs[tid];
        float SS = cs[64 + tid];
        const float invn = 1.f / (float)BTN;
        float mu   = S * invn;
        float var  = SS * invn - mu * mu;
        float rstd = rsqrtf(var + 1e-5f);
        float a = gammas[(gbase + b) * 64 + tid] * rstd;
        float c = betas[(gbase + b) * 64 + tid] - mu * a;
        scale[b * 128 + tid]      = a;
        scale[b * 128 + 64 + tid] = c;
    }
}

// ---------------------------------------------------------------------------
// Kernel 7: mix GEMM (MFMA, verified R5): out2 = relu(bn(cat)) @ cat_w^T.
// ---------------------------------------------------------------------------
__launch_bounds__(256)
__global__ void mix_pass(const bf16* __restrict__ xs, const bf16* __restrict__ yc,
                         const bf16* __restrict__ z, const float* __restrict__ scale1,
                         const short* __restrict__ CB,
                         bf16* __restrict__ out2, float* __restrict__ part2) {
    __shared__ float sL[384];
    __shared__ float red[512];

    const int tid = threadIdx.x;
    const int w = tid >> 6, L = tid & 63;
    const int lane16 = L & 15, quad = L >> 4;
    const int R0 = blockIdx.x * 128 + w * 32;

    for (int idx = tid; idx < 384; idx += 256) sL[idx] = scale1[idx];
    __syncthreads();

    const bf16* srcs[3] = { xs, yc, z };

    f32x4 acc[2][4];
    #pragma unroll
    for (int rt = 0; rt < 2; rt++)
        #pragma unroll
        for (int nt = 0; nt < 4; nt++)
            acc[rt][nt] = (f32x4){0.f, 0.f, 0.f, 0.f};

    #pragma unroll
    for (int kc = 0; kc < 6; kc++) {
        const int src = kc >> 1;
        const int c0  = (kc & 1) * 32 + quad * 8;
        bf16x8 av[2];
        #pragma unroll
        for (int rt = 0; rt < 2; rt++) {
            int row = R0 + rt * 16 + lane16;
            uint4 u = *(const uint4*)(srcs[src] + (size_t)row * 64 + c0);
            float v[8];
            unp(u.x, v[0], v[1]); unp(u.y, v[2], v[3]);
            unp(u.z, v[4], v[5]); unp(u.w, v[6], v[7]);
            #pragma unroll
            for (int e = 0; e < 8; e++) {
                float t = fmaxf(fmaf(v[e], sL[src * 128 + c0 + e],
                                     sL[src * 128 + 64 + c0 + e]), 0.f);
                av[rt][e] = fbf(t);
            }
        }
        #pragma unroll
        for (int nt = 0; nt < 4; nt++) {
            bf16x8 bw = ((const bf16x8*)CB)[(nt * 6 + kc) * 64 + L];
            acc[0][nt] = __builtin_amdgcn_mfma_f32_16x16x32_bf16(av[0], bw, acc[0][nt], 0, 0, 0);
            acc[1][nt] = __builtin_amdgcn_mfma_f32_16x16x32_bf16(av[1], bw, acc[1][nt], 0, 0, 0);
        }
    }

    float s[4]  = {0.f, 0.f, 0.f, 0.f};
    float s2[4] = {0.f, 0.f, 0.f, 0.f};
    #pragma unroll
    for (int rt = 0; rt < 2; rt++)
        #pragma unroll
        for (int nt = 0; nt < 4; nt++)
            #pragma unroll
            for (int r = 0; r < 4; r++) {
                int row = R0 + rt * 16 + quad * 4 + r;
                int col = nt * 16 + lane16;
                float v = acc[rt][nt][r];
                out2[(size_t)row * 64 + col] = f2bf(v);
                s[nt] += v; s2[nt] += v * v;
            }
    #pragma unroll
    for (int nt = 0; nt < 4; nt++) {
        s[nt]  += __shfl_xor(s[nt], 16);
        s[nt]  += __shfl_xor(s[nt], 32);
        s2[nt] += __shfl_xor(s2[nt], 16);
        s2[nt] += __shfl_xor(s2[nt], 32);
    }
    if (quad == 0) {
        #pragma unroll
        for (int nt = 0; nt < 4; nt++) {
            red[w * 64 + nt * 16 + lane16]       = s[nt];
            red[256 + w * 64 + nt * 16 + lane16] = s2[nt];
        }
    }
    __syncthreads();
    if (tid < 64) {
        float t = red[tid] + red[64 + tid] + red[128 + tid] + red[192 + tid];
        part2[(size_t)blockIdx.x * 128 + tid] = t;
    } else if (tid < 128) {
        int c = tid - 64;
        float t = red[256 + c] + red[320 + c] + red[384 + c] + red[448 + c];
        part2[(size_t)blockIdx.x * 128 + 64 + c] = t;
    }
}

// ---------------------------------------------------------------------------
// Kernel 8: final BN + ReLU + f32 store (4 elems/thread).
// ---------------------------------------------------------------------------
__global__ void final_pass(const bf16* __restrict__ out2, const float* __restrict__ scale2,
                           float* __restrict__ out) {
    const int gid = blockIdx.x * 256 + threadIdx.x;
    const int idx = gid * 4;
    ushort4 u = reinterpret_cast<const ushort4*>(out2)[gid];
    const int o = idx & 63;
    float f0, f1, f2, f3;
    unp((unsigned)u.x | ((unsigned)u.y << 16), f0, f1);
    unp((unsigned)u.z | ((unsigned)u.w << 16), f2, f3);
    float4 r;
    r.x = fmaxf(fmaf(f0, scale2[o],     scale2[64 + o]),     0.f);
    r.y = fmaxf(fmaf(f1, scale2[o + 1], scale2[64 + o + 1]), 0.f);
    r.z = fmaxf(fmaf(f2, scale2[o + 2], scale2[64 + o + 2]), 0.f);
    r.w = fmaxf(fmaf(f3, scale2[o + 3], scale2[64 + o + 3]), 0.f);
    reinterpret_cast<float4*>(out)[gid] = r;
}

// ---------------------------------------------------------------------------
extern "C" void kernel_launch(void* const* d_in, const int* in_sizes, int n_in,
                              void* d_out, int out_size, void* d_ws, size_t ws_size,
                              hipStream_t stream) {
    const float* x      = (const float*)d_in[0];
    const float* W_sym  = (const float*)d_in[1];
    const float* e_sym  = (const float*)d_in[2];
    const float* W_con  = (const float*)d_in[3];
    const float* e_con  = (const float*)d_in[4];
    const float* W_dis  = (const float*)d_in[5];
    const float* att    = (const float*)d_in[6];
    const float* b_dis  = (const float*)d_in[7];
    const float* cat_w  = (const float*)d_in[8];
    const float* gammas = (const float*)d_in[9];
    const float* betas  = (const float*)d_in[10];
    const int* rows_sym = (const int*)d_in[11];
    const int* cols_sym = (const int*)d_in[12];
    const int* rows_con = (const int*)d_in[13];
    const int* cols_con = (const int*)d_in[14];
    const int nnz_s = in_sizes[2] / 64;
    const int nnz_c = in_sizes[4] / 64;

    // Workspace carve. out2 aliases the xb/db region (xb/db dead after h_gemm,
    // out2 first written by mix_pass — strictly later on the same stream).
    char* p = (char*)d_ws;
    float* AA     = (float*)p; p += (size_t)NN * 64 * 2 * 4;   // 247808
    float* part1  = (float*)p; p += (size_t)BT * 384 * 4;      // 4915200
    float* partA  = (float*)p; p += (size_t)100 * 384 * 4;     // 153600
    float* part2  = (float*)p; p += (size_t)550 * 128 * 4;     // 281600
    float* scale1 = (float*)p; p += 384 * 4;
    float* scale2 = (float*)p; p += 128 * 4;
    short* CB     = (short*)p; p += (size_t)1536 * 8 * 2;      // 24576
    bf16*  xb     = (bf16*)p;  p += (size_t)ELEMS * 2;         // 9 MB
    bf16*  db     = (bf16*)p;  p += (size_t)ELEMS * 2;         // 9 MB
    bf16*  xsb    = (bf16*)p;  p += (size_t)ELEMS * 2;
    bf16*  ycb    = (bf16*)p;  p += (size_t)ELEMS * 2;
    bf16*  zb     = (bf16*)p;  p += (size_t)ELEMS * 2;
    bf16*  hbuf   = (bf16*)p;  p += (size_t)ELEMS * 5 * 2;     // 45 MB
    bf16*  out2   = xb;                                        // alias (see above)

    prep_kernel<<<17, 256, 0, stream>>>(e_sym, rows_sym, cols_sym, nnz_s,
                                        e_con, rows_con, cols_con, nnz_c,
                                        cat_w, AA, CB);
    pre_pass<<<BT, 64, 0, stream>>>(x, xb, db);
    h_gemm<<<dim3(550, 5), 256, 0, stream>>>(xb, db, W_sym, W_con, W_dis, hbuf);
    mixer<<<BT, 256, 0, stream>>>(hbuf, AA, att, b_dis, xsb, ycb, zb, part1);
    reduce_stageA<<<100, 256, 0, stream>>>(part1, partA);
    reduce_final<<<3, 256, 0, stream>>>(partA, 100, 384, gammas, betas, 0, scale1);
    mix_pass<<<550, 256, 0, stream>>>(xsb, ycb, zb, scale1, CB, out2, part2);
    reduce_final<<<1, 256, 0, stream>>>(part2, 550, 128, gammas, betas, 3, scale2);
    final_pass<<<ELEMS / 1024, 256, 0, stream>>>(out2, scale2, (float*)d_out);
}

// Round 7
// 314.571 us; speedup vs baseline: 3.1687x; 1.0814x over previous
//
#include <hip/hip_runtime.h>
#include <hip/hip_bf16.h>

typedef __hip_bfloat16 bf16;
typedef __attribute__((ext_vector_type(8))) short bf16x8;
typedef __attribute__((ext_vector_type(4))) float f32x4;

#define BT    3200
#define N_    22
#define NO    1408           // N_*64
#define NN    484
#define BTN   70400
#define ELEMS 4505600        // BT*N_*64

static __device__ __forceinline__ bf16  f2bf(float v) { return __float2bfloat16(v); }
static __device__ __forceinline__ short fbf(float v) {
    bf16 h = __float2bfloat16(v);
    return *reinterpret_cast<short*>(&h);
}
static __device__ __forceinline__ void unp(unsigned u, float& lo, float& hi) {
    lo = __uint_as_float(u << 16);
    hi = __uint_as_float(u & 0xffff0000u);
}

// ---------------------------------------------------------------------------
// Kernel 1 (prep): blocks 0-10 build softmax adjacency as packed bf16 pairs
// AAb[((i*22+j)*64+o)*2 + t] (t=0 lo-short = As, t=1 hi-short = Ac; two 2B
// stores into the same 4B word by different threads — disjoint bytes, safe).
// blocks 11-16 pack cat_w into MFMA B-fragments CB (verified R5).
// ---------------------------------------------------------------------------
__global__ void prep_kernel(const float* __restrict__ e_s, const int* __restrict__ rs,
                            const int* __restrict__ cs, int nnz_s,
                            const float* __restrict__ e_c, const int* __restrict__ rc,
                            const int* __restrict__ cc, int nnz_c,
                            const float* __restrict__ cat_w,
                            short* __restrict__ AAb, short* __restrict__ CB) {
    const int tid = threadIdx.x;
    if (blockIdx.x < 11) {
        int id = blockIdx.x * 256 + tid;           // 0..2815
        if (id >= 2 * 64 * N_) return;
        int t   = id / (64 * N_);
        int rem = id % (64 * N_);
        int o   = rem / N_;
        int i   = rem % N_;
        const float* e    = t ? e_c : e_s;
        const int*   rows = t ? rc  : rs;
        const int*   cols = t ? cc  : cs;
        int          nnz  = t ? nnz_c : nnz_s;
        float row[N_];
        #pragma unroll
        for (int j = 0; j < N_; j++) row[j] = 0.f;
        float s = 0.f;
        for (int k = 0; k < nnz; k++) {
            if (rows[k] == i) {
                float v = expf(e[o * nnz + k]);
                row[cols[k]] = v;
                s += v;
            }
        }
        float inv = 1.f / s;
        for (int j = 0; j < N_; j++)
            AAb[((size_t)(i * N_ + j) * 64 + o) * 2 + t] = fbf(row[j] * inv);
    } else {
        int gi = (blockIdx.x - 11) * 256 + tid;    // 0..1535
        if (gi >= 1536) return;
        int nt = gi / 384, rem = gi % 384;
        int kc = rem >> 6, L = rem & 63;
        int n = nt * 16 + (L & 15);
        int kbase = kc * 32 + (L >> 4) * 8;
        float4 w0 = *(const float4*)&cat_w[n * 192 + kbase];
        float4 w1 = *(const float4*)&cat_w[n * 192 + kbase + 4];
        bf16x8 frag;
        frag[0] = fbf(w0.x); frag[1] = fbf(w0.y); frag[2] = fbf(w0.z); frag[3] = fbf(w0.w);
        frag[4] = fbf(w1.x); frag[5] = fbf(w1.y); frag[6] = fbf(w1.z); frag[7] = fbf(w1.w);
        ((bf16x8*)CB)[gi] = frag;
    }
}

// ---------------------------------------------------------------------------
// Kernel 2: per-bt stats + cast (verified R6, unchanged).
// ---------------------------------------------------------------------------
__global__ void pre_pass(const float* __restrict__ x,
                         bf16* __restrict__ xb, bf16* __restrict__ db) {
    __shared__ float xt[NO];
    const int bt = blockIdx.x, tid = threadIdx.x;    // 64 threads
    const size_t base = (size_t)bt * NO;
    for (int idx = tid; idx < NO / 4; idx += 64)
        ((float4*)xt)[idx] = ((const float4*)(x + base))[idx];
    __syncthreads();
    float s = 0.f, s2 = 0.f;
    #pragma unroll
    for (int i = 0; i < N_; i++) { float v = xt[i * 64 + tid]; s += v; s2 += v * v; }
    #pragma unroll
    for (int i = 0; i < N_; i++) {
        float v  = xt[i * 64 + tid];
        float d2 = s2 - 2.f * v * s + (float)N_ * v * v;
        float d  = sqrtf(fmaxf(d2, 0.f)) + 1e-8f;
        xb[base + i * 64 + tid] = f2bf(v);
        db[base + i * 64 + tid] = f2bf(d);
    }
}

// ---------------------------------------------------------------------------
// Kernel 3: h GEMM v2. grid (550, 3). Each block computes a plane PAIR from
// one A-stream:
//   y=0: xb @ {Ws0, Ws1} -> planes {1:h1s wait see below}
//   plane map in hbuf: 0:h1s 1:(h0s-h1s) 2:h1c 3:(h0c-h1c) 4:hdw
// A = verified direct-uint4-global pattern; B = bf16 WT[n][k] LDS transpose
// read as b128 fragments; C-layout epilogue verified (R5/R6).
// ---------------------------------------------------------------------------
__launch_bounds__(256)
__global__ void h_gemm(const bf16* __restrict__ xb, const bf16* __restrict__ db,
                       const float* __restrict__ Wsym, const float* __restrict__ Wcon,
                       const float* __restrict__ Wdis, bf16* __restrict__ hbuf) {
    __shared__ __align__(16) short WT[2 * 4608];   // [p][n][72] bf16, 18.4 KB
    const int tid = threadIdx.x;
    const int y = blockIdx.y;
    const float* Wp0 = (y == 0) ? Wsym        : (y == 1) ? Wcon        : Wdis;
    const float* Wp1 = (y == 0) ? Wsym + 4096 : (y == 1) ? Wcon + 4096 : Wdis;
    const bf16*  src = (y < 2) ? xb : db;

    for (int idx = tid; idx < 4096; idx += 256) {
        int k = idx >> 6, n = idx & 63;
        WT[n * 72 + k]        = fbf(Wp0[idx]);
        WT[4608 + n * 72 + k] = fbf(Wp1[idx]);
    }
    __syncthreads();

    const int w = tid >> 6, L = tid & 63;
    const int lane16 = L & 15, quad = L >> 4;
    const int R0 = blockIdx.x * 128 + w * 32;

    // B-frags: frag[p][kc][nt] reg j = B[k=kc*32+quad*8+j][n=nt*16+lane16]
    bf16x8 bfr[2][2][4];
    #pragma unroll
    for (int p = 0; p < 2; p++)
        #pragma unroll
        for (int kc = 0; kc < 2; kc++)
            #pragma unroll
            for (int nt = 0; nt < 4; nt++)
                bfr[p][kc][nt] = *(const bf16x8*)
                    &WT[p * 4608 + (nt * 16 + lane16) * 72 + kc * 32 + quad * 8];

    f32x4 acc[2][2][4];   // [p][rt][nt]
    #pragma unroll
    for (int p = 0; p < 2; p++)
        #pragma unroll
        for (int rt = 0; rt < 2; rt++)
            #pragma unroll
            for (int nt = 0; nt < 4; nt++) acc[p][rt][nt] = (f32x4){0.f, 0.f, 0.f, 0.f};

    #pragma unroll
    for (int kc = 0; kc < 2; kc++) {
        bf16x8 av[2];
        #pragma unroll
        for (int rt = 0; rt < 2; rt++) {
            int row = R0 + rt * 16 + lane16;
            av[rt] = *(const bf16x8*)(src + (size_t)row * 64 + kc * 32 + quad * 8);
        }
        #pragma unroll
        for (int p = 0; p < 2; p++)
            #pragma unroll
            for (int nt = 0; nt < 4; nt++) {
                acc[p][0][nt] = __builtin_amdgcn_mfma_f32_16x16x32_bf16(av[0], bfr[p][kc][nt], acc[p][0][nt], 0, 0, 0);
                acc[p][1][nt] = __builtin_amdgcn_mfma_f32_16x16x32_bf16(av[1], bfr[p][kc][nt], acc[p][1][nt], 0, 0, 0);
            }
    }

    // epilogue (verified C layout: row=quad*4+r, col=lane16 within tile)
    bf16* out0 = hbuf + (size_t)((y == 0) ? 0 : (y == 1) ? 2 : 4) * ELEMS;
    bf16* outD = hbuf + (size_t)((y == 0) ? 1 : 3) * ELEMS;   // y<2 only
    #pragma unroll
    for (int rt = 0; rt < 2; rt++)
        #pragma unroll
        for (int nt = 0; nt < 4; nt++)
            #pragma unroll
            for (int r = 0; r < 4; r++) {
                size_t idx = (size_t)(R0 + rt * 16 + quad * 4 + r) * 64 + nt * 16 + lane16;
                float h0v = acc[0][rt][nt][r];   // W plane 0
                float h1v = acc[1][rt][nt][r];   // W plane 1
                if (y < 2) {
                    out0[idx] = f2bf(h1v);
                    outD[idx] = f2bf(h0v - h1v);  // diff in f32, then round
                } else {
                    out0[idx] = f2bf(h0v);        // hdw (plane 0 = Wdis)
                }
            }
}

// ---------------------------------------------------------------------------
// Kernel 4: per-bt mixer v2. Planes pre-diffed; hh/hd kept as packed bf16 in
// LDS (pure repack, lossless); AAb read as packed bf16 pairs (half traffic).
// Mixing math identical to verified R5/R6 code.
// ---------------------------------------------------------------------------
__launch_bounds__(256)
__global__ void mixer(const bf16* __restrict__ hbuf, const short* __restrict__ AAb,
                      const float* __restrict__ att, const float* __restrict__ bdis,
                      bf16* __restrict__ xs, bf16* __restrict__ yc,
                      bf16* __restrict__ z, float* __restrict__ part1) {
    __shared__ __align__(16) short raw[5 * NO];    // 14 KB; reused as red (6 KB)
    __shared__ __align__(8)  ushort hhb[NO * 4];   // {h1s,h1c,hdw,0} per (i,o), 11.3 KB
    __shared__ __align__(4)  unsigned hdb[NO];     // {ds|dc<<16} per (i,o), 5.6 KB
    __shared__ float attL[NN];
    float* red = (float*)raw;

    const int bt  = blockIdx.x;
    const int tid = threadIdx.x;
    const size_t base = (size_t)bt * NO;
    const int w = tid >> 6, L = tid & 63;

    for (int idx = tid; idx < 880; idx += 256) {   // 5 planes x 176 uint4
        int t = idx / 176, rem = idx - t * 176;
        ((uint4*)raw)[idx] = ((const uint4*)(hbuf + (size_t)t * ELEMS + base))[rem];
    }
    for (int idx = tid; idx < NN; idx += 256) attL[idx] = att[idx];
    __syncthreads();

    // repack (planes: 0:h1s 1:ds 2:h1c 3:dc 4:hdw) — pure bf16 copies
    for (int idx = tid; idx < NO; idx += 256) {
        hhb[idx * 4 + 0] = (ushort)raw[idx];
        hhb[idx * 4 + 1] = (ushort)raw[2 * NO + idx];
        hhb[idx * 4 + 2] = (ushort)raw[4 * NO + idx];
        hhb[idx * 4 + 3] = 0;
        hdb[idx] = (unsigned)(ushort)raw[NO + idx] |
                   ((unsigned)(ushort)raw[3 * NO + idx] << 16);
    }
    __syncthreads();

    float mxs[6], myc[6], mz[6];
    #pragma unroll
    for (int k = 0; k < 6; k++) { mxs[k] = myc[k] = mz[k] = 0.f; }

    const unsigned* AAu = (const unsigned*)AAb;
    for (int j = 0; j < N_; j++) {
        uint2 hv = *(const uint2*)&hhb[(j * 64 + L) * 4];
        float h1s, h1c, hw, dum;
        unp(hv.x, h1s, h1c); unp(hv.y, hw, dum);
        #pragma unroll
        for (int k = 0; k < 6; k++) {
            int i  = w + 4 * k;
            int ii = (i < N_) ? i : 0;
            unsigned a = AAu[(size_t)(ii * N_ + j) * 64 + L];
            float as, ac; unp(a, as, ac);
            float atv = attL[ii * N_ + j];
            mxs[k] = fmaf(as,  h1s, mxs[k]);
            myc[k] = fmaf(ac,  h1c, myc[k]);
            mz[k]  = fmaf(atv, hw,  mz[k]);
        }
    }

    float bd = bdis[L];
    float st0 = 0.f, st1 = 0.f, st2 = 0.f, st3 = 0.f, st4 = 0.f, st5 = 0.f;
    #pragma unroll
    for (int k = 0; k < 6; k++) {
        int i = w + 4 * k;
        if (i < N_) {
            unsigned ad = AAu[(size_t)(i * 23) * 64 + L];   // diag coeffs
            float asd, acd; unp(ad, asd, acd);
            float dsv, dcv; unp(hdb[i * 64 + L], dsv, dcv);
            float xsv = mxs[k] + asd * dsv;
            float ycv = myc[k] + acd * dcv;
            float zv  = mz[k] + bd;
            size_t oi = base + i * 64 + L;
            xs[oi] = f2bf(xsv); yc[oi] = f2bf(ycv); z[oi] = f2bf(zv);
            st0 += xsv; st1 += xsv * xsv;
            st2 += ycv; st3 += ycv * ycv;
            st4 += zv;  st5 += zv  * zv;
        }
    }

    red[(w * 6 + 0) * 64 + L] = st0;
    red[(w * 6 + 1) * 64 + L] = st1;
    red[(w * 6 + 2) * 64 + L] = st2;
    red[(w * 6 + 3) * 64 + L] = st3;
    red[(w * 6 + 4) * 64 + L] = st4;
    red[(w * 6 + 5) * 64 + L] = st5;
    __syncthreads();
    for (int qq = tid; qq < 384; qq += 256) {
        int q = qq >> 6, oo = qq & 63;
        part1[(size_t)bt * 384 + qq] =
            (red[q * 64 + oo] + red[(6 + q) * 64 + oo]) +
            (red[(12 + q) * 64 + oo] + red[(18 + q) * 64 + oo]);
    }
}

// ---------------------------------------------------------------------------
// Kernel 5: stage-A reduction: 3200 rows -> 100 rows.
// ---------------------------------------------------------------------------
__global__ void reduce_stageA(const float* __restrict__ part1, float* __restrict__ partA) {
    const int g = blockIdx.x, tid = threadIdx.x;
    const float* p = part1 + (size_t)g * 32 * 384;
    float s0 = 0.f, s1 = 0.f;
    for (int r = 0; r < 32; r++) {
        s0 += p[r * 384 + tid];
        if (tid < 128) s1 += p[r * 384 + 256 + tid];
    }
    partA[(size_t)g * 384 + tid] = s0;
    if (tid < 128) partA[(size_t)g * 384 + 256 + tid] = s1;
}

// ---------------------------------------------------------------------------
// Kernel 6: final reduction + BN affine (a=g*rstd, c=beta-mu*a).
// ---------------------------------------------------------------------------
__global__ void reduce_final(const float* __restrict__ part, int nrows, int rowlen,
                             const float* __restrict__ gammas, const float* __restrict__ betas,
                             int gbase, float* __restrict__ scale) {
    __shared__ float cs[256];
    const int b = blockIdx.x, tid = threadIdx.x;
    const int col  = b * 128 + (tid & 127);
    const int half = tid >> 7;
    float s = 0.f;
    for (int r = half; r < nrows; r += 2) s += part[(size_t)r * rowlen + col];
    cs[tid] = s;
    __syncthreads();
    if (tid < 128) cs[tid] = cs[tid] + cs[tid + 128];
    __syncthreads();
    if (tid < 64) {
        float S  = cs[tid];
        float SS = cs[64 + tid];
        const float invn = 1.f / (float)BTN;
        float mu   = S * invn;
        float var  = SS * invn - mu * mu;
        float rstd = rsqrtf(var + 1e-5f);
        float a = gammas[(gbase + b) * 64 + tid] * rstd;
        float c = betas[(gbase + b) * 64 + tid] - mu * a;
        scale[b * 128 + tid]      = a;
        scale[b * 128 + 64 + tid] = c;
    }
}

// ---------------------------------------------------------------------------
// Kernel 7: mix GEMM (MFMA, verified R5/R6 — unchanged).
// ---------------------------------------------------------------------------
__launch_bounds__(256)
__global__ void mix_pass(const bf16* __restrict__ xs, const bf16* __restrict__ yc,
                         const bf16* __restrict__ z, const float* __restrict__ scale1,
                         const short* __restrict__ CB,
                         bf16* __restrict__ out2, float* __restrict__ part2) {
    __shared__ float sL[384];
    __shared__ float red[512];

    const int tid = threadIdx.x;
    const int w = tid >> 6, L = tid & 63;
    const int lane16 = L & 15, quad = L >> 4;
    const int R0 = blockIdx.x * 128 + w * 32;

    for (int idx = tid; idx < 384; idx += 256) sL[idx] = scale1[idx];
    __syncthreads();

    const bf16* srcs[3] = { xs, yc, z };

    f32x4 acc[2][4];
    #pragma unroll
    for (int rt = 0; rt < 2; rt++)
        #pragma unroll
        for (int nt = 0; nt < 4; nt++)
            acc[rt][nt] = (f32x4){0.f, 0.f, 0.f, 0.f};

    #pragma unroll
    for (int kc = 0; kc < 6; kc++) {
        const int src = kc >> 1;
        const int c0  = (kc & 1) * 32 + quad * 8;
        bf16x8 av[2];
        #pragma unroll
        for (int rt = 0; rt < 2; rt++) {
            int row = R0 + rt * 16 + lane16;
            uint4 u = *(const uint4*)(srcs[src] + (size_t)row * 64 + c0);
            float v[8];
            unp(u.x, v[0], v[1]); unp(u.y, v[2], v[3]);
            unp(u.z, v[4], v[5]); unp(u.w, v[6], v[7]);
            #pragma unroll
            for (int e = 0; e < 8; e++) {
                float t = fmaxf(fmaf(v[e], sL[src * 128 + c0 + e],
                                     sL[src * 128 + 64 + c0 + e]), 0.f);
                av[rt][e] = fbf(t);
            }
        }
        #pragma unroll
        for (int nt = 0; nt < 4; nt++) {
            bf16x8 bw = ((const bf16x8*)CB)[(nt * 6 + kc) * 64 + L];
            acc[0][nt] = __builtin_amdgcn_mfma_f32_16x16x32_bf16(av[0], bw, acc[0][nt], 0, 0, 0);
            acc[1][nt] = __builtin_amdgcn_mfma_f32_16x16x32_bf16(av[1], bw, acc[1][nt], 0, 0, 0);
        }
    }

    float s[4]  = {0.f, 0.f, 0.f, 0.f};
    float s2[4] = {0.f, 0.f, 0.f, 0.f};
    #pragma unroll
    for (int rt = 0; rt < 2; rt++)
        #pragma unroll
        for (int nt = 0; nt < 4; nt++)
            #pragma unroll
            for (int r = 0; r < 4; r++) {
                int row = R0 + rt * 16 + quad * 4 + r;
                int col = nt * 16 + lane16;
                float v = acc[rt][nt][r];
                out2[(size_t)row * 64 + col] = f2bf(v);
                s[nt] += v; s2[nt] += v * v;
            }
    #pragma unroll
    for (int nt = 0; nt < 4; nt++) {
        s[nt]  += __shfl_xor(s[nt], 16);
        s[nt]  += __shfl_xor(s[nt], 32);
        s2[nt] += __shfl_xor(s2[nt], 16);
        s2[nt] += __shfl_xor(s2[nt], 32);
    }
    if (quad == 0) {
        #pragma unroll
        for (int nt = 0; nt < 4; nt++) {
            red[w * 64 + nt * 16 + lane16]       = s[nt];
            red[256 + w * 64 + nt * 16 + lane16] = s2[nt];
        }
    }
    __syncthreads();
    if (tid < 64) {
        float t = red[tid] + red[64 + tid] + red[128 + tid] + red[192 + tid];
        part2[(size_t)blockIdx.x * 128 + tid] = t;
    } else if (tid < 128) {
        int c = tid - 64;
        float t = red[256 + c] + red[320 + c] + red[384 + c] + red[448 + c];
        part2[(size_t)blockIdx.x * 128 + 64 + c] = t;
    }
}

// ---------------------------------------------------------------------------
// Kernel 8: final BN + ReLU + f32 store (4 elems/thread).
// ---------------------------------------------------------------------------
__global__ void final_pass(const bf16* __restrict__ out2, const float* __restrict__ scale2,
                           float* __restrict__ out) {
    const int gid = blockIdx.x * 256 + threadIdx.x;
    const int idx = gid * 4;
    ushort4 u = reinterpret_cast<const ushort4*>(out2)[gid];
    const int o = idx & 63;
    float f0, f1, f2, f3;
    unp((unsigned)u.x | ((unsigned)u.y << 16), f0, f1);
    unp((unsigned)u.z | ((unsigned)u.w << 16), f2, f3);
    float4 r;
    r.x = fmaxf(fmaf(f0, scale2[o],     scale2[64 + o]),     0.f);
    r.y = fmaxf(fmaf(f1, scale2[o + 1], scale2[64 + o + 1]), 0.f);
    r.z = fmaxf(fmaf(f2, scale2[o + 2], scale2[64 + o + 2]), 0.f);
    r.w = fmaxf(fmaf(f3, scale2[o + 3], scale2[64 + o + 3]), 0.f);
    reinterpret_cast<float4*>(out)[gid] = r;
}

// ---------------------------------------------------------------------------
extern "C" void kernel_launch(void* const* d_in, const int* in_sizes, int n_in,
                              void* d_out, int out_size, void* d_ws, size_t ws_size,
                              hipStream_t stream) {
    const float* x      = (const float*)d_in[0];
    const float* W_sym  = (const float*)d_in[1];
    const float* e_sym  = (const float*)d_in[2];
    const float* W_con  = (const float*)d_in[3];
    const float* e_con  = (const float*)d_in[4];
    const float* W_dis  = (const float*)d_in[5];
    const float* att    = (const float*)d_in[6];
    const float* b_dis  = (const float*)d_in[7];
    const float* cat_w  = (const float*)d_in[8];
    const float* gammas = (const float*)d_in[9];
    const float* betas  = (const float*)d_in[10];
    const int* rows_sym = (const int*)d_in[11];
    const int* cols_sym = (const int*)d_in[12];
    const int* rows_con = (const int*)d_in[13];
    const int* cols_con = (const int*)d_in[14];
    const int nnz_s = in_sizes[2] / 64;
    const int nnz_c = in_sizes[4] / 64;

    // Workspace carve. out2 aliases xb (dead after h_gemm; out2 written later).
    char* p = (char*)d_ws;
    short* AAb    = (short*)p; p += (size_t)NN * 64 * 2 * 2;   // 124 KB (16B-mult)
    float* part1  = (float*)p; p += (size_t)BT * 384 * 4;
    float* partA  = (float*)p; p += (size_t)100 * 384 * 4;
    float* part2  = (float*)p; p += (size_t)550 * 128 * 4;
    float* scale1 = (float*)p; p += 384 * 4;
    float* scale2 = (float*)p; p += 128 * 4;
    short* CB     = (short*)p; p += (size_t)1536 * 8 * 2;
    bf16*  xb     = (bf16*)p;  p += (size_t)ELEMS * 2;
    bf16*  db     = (bf16*)p;  p += (size_t)ELEMS * 2;
    bf16*  xsb    = (bf16*)p;  p += (size_t)ELEMS * 2;
    bf16*  ycb    = (bf16*)p;  p += (size_t)ELEMS * 2;
    bf16*  zb     = (bf16*)p;  p += (size_t)ELEMS * 2;
    bf16*  hbuf   = (bf16*)p;  p += (size_t)ELEMS * 5 * 2;
    bf16*  out2   = xb;

    prep_kernel<<<17, 256, 0, stream>>>(e_sym, rows_sym, cols_sym, nnz_s,
                                        e_con, rows_con, cols_con, nnz_c,
                                        cat_w, AAb, CB);
    pre_pass<<<BT, 64, 0, stream>>>(x, xb, db);
    h_gemm<<<dim3(550, 3), 256, 0, stream>>>(xb, db, W_sym, W_con, W_dis, hbuf);
    mixer<<<BT, 256, 0, stream>>>(hbuf, AAb, att, b_dis, xsb, ycb, zb, part1);
    reduce_stageA<<<100, 256, 0, stream>>>(part1, partA);
    reduce_final<<<3, 256, 0, stream>>>(partA, 100, 384, gammas, betas, 0, scale1);
    mix_pass<<<550, 256, 0, stream>>>(xsb, ycb, zb, scale1, CB, out2, part2);
    reduce_final<<<1, 256, 0, stream>>>(part2, 550, 128, gammas, betas, 3, scale2);
    final_pass<<<ELEMS / 1024, 256, 0, stream>>>(out2, scale2, (float*)d_out);
}

// Round 8
// 292.504 us; speedup vs baseline: 3.4078x; 1.0754x over previous
//
#include <hip/hip_runtime.h>
#include <hip/hip_bf16.h>

typedef __hip_bfloat16 bf16;
typedef __attribute__((ext_vector_type(8))) short bf16x8;
typedef __attribute__((ext_vector_type(4))) float f32x4;

#define BT    3200
#define N_    22
#define NO    1408           // N_*64
#define NN    484
#define BTN   70400
#define ELEMS 4505600        // BT*N_*64

static __device__ __forceinline__ bf16  f2bf(float v) { return __float2bfloat16(v); }
static __device__ __forceinline__ short fbf(float v) {
    bf16 h = __float2bfloat16(v);
    return *reinterpret_cast<short*>(&h);
}
static __device__ __forceinline__ void unp(unsigned u, float& lo, float& hi) {
    lo = __uint_as_float(u << 16);
    hi = __uint_as_float(u & 0xffff0000u);
}

// ---------------------------------------------------------------------------
// Kernel 1 (prep): blocks 0-10 build softmax adjacency as packed bf16 pairs
// AAb[((i*22+j)*64+o)*2 + t]; blocks 11-16 pack cat_w into MFMA B-fragments.
// (verified R5-R7)
// ---------------------------------------------------------------------------
__global__ void prep_kernel(const float* __restrict__ e_s, const int* __restrict__ rs,
                            const int* __restrict__ cs, int nnz_s,
                            const float* __restrict__ e_c, const int* __restrict__ rc,
                            const int* __restrict__ cc, int nnz_c,
                            const float* __restrict__ cat_w,
                            short* __restrict__ AAb, short* __restrict__ CB) {
    const int tid = threadIdx.x;
    if (blockIdx.x < 11) {
        int id = blockIdx.x * 256 + tid;           // 0..2815
        if (id >= 2 * 64 * N_) return;
        int t   = id / (64 * N_);
        int rem = id % (64 * N_);
        int o   = rem / N_;
        int i   = rem % N_;
        const float* e    = t ? e_c : e_s;
        const int*   rows = t ? rc  : rs;
        const int*   cols = t ? cc  : cs;
        int          nnz  = t ? nnz_c : nnz_s;
        float row[N_];
        #pragma unroll
        for (int j = 0; j < N_; j++) row[j] = 0.f;
        float s = 0.f;
        for (int k = 0; k < nnz; k++) {
            if (rows[k] == i) {
                float v = expf(e[o * nnz + k]);
                row[cols[k]] = v;
                s += v;
            }
        }
        float inv = 1.f / s;
        for (int j = 0; j < N_; j++)
            AAb[((size_t)(i * N_ + j) * 64 + o) * 2 + t] = fbf(row[j] * inv);
    } else {
        int gi = (blockIdx.x - 11) * 256 + tid;    // 0..1535
        if (gi >= 1536) return;
        int nt = gi / 384, rem = gi % 384;
        int kc = rem >> 6, L = rem & 63;
        int n = nt * 16 + (L & 15);
        int kbase = kc * 32 + (L >> 4) * 8;
        float4 w0 = *(const float4*)&cat_w[n * 192 + kbase];
        float4 w1 = *(const float4*)&cat_w[n * 192 + kbase + 4];
        bf16x8 frag;
        frag[0] = fbf(w0.x); frag[1] = fbf(w0.y); frag[2] = fbf(w0.z); frag[3] = fbf(w0.w);
        frag[4] = fbf(w1.x); frag[5] = fbf(w1.y); frag[6] = fbf(w1.z); frag[7] = fbf(w1.w);
        ((bf16x8*)CB)[gi] = frag;
    }
}

// ---------------------------------------------------------------------------
// Kernel 2: per-bt stats + cast (verified R6/R7, unchanged).
// ---------------------------------------------------------------------------
__global__ void pre_pass(const float* __restrict__ x,
                         bf16* __restrict__ xb, bf16* __restrict__ db) {
    __shared__ float xt[NO];
    const int bt = blockIdx.x, tid = threadIdx.x;    // 64 threads
    const size_t base = (size_t)bt * NO;
    for (int idx = tid; idx < NO / 4; idx += 64)
        ((float4*)xt)[idx] = ((const float4*)(x + base))[idx];
    __syncthreads();
    float s = 0.f, s2 = 0.f;
    #pragma unroll
    for (int i = 0; i < N_; i++) { float v = xt[i * 64 + tid]; s += v; s2 += v * v; }
    #pragma unroll
    for (int i = 0; i < N_; i++) {
        float v  = xt[i * 64 + tid];
        float d2 = s2 - 2.f * v * s + (float)N_ * v * v;
        float d  = sqrtf(fmaxf(d2, 0.f)) + 1e-8f;
        xb[base + i * 64 + tid] = f2bf(v);
        db[base + i * 64 + tid] = f2bf(d);
    }
}

// ---------------------------------------------------------------------------
// Kernel 3: h GEMM (verified R7, unchanged). grid (550, 3), plane pairs.
// plane map in hbuf: 0:h1s 1:(h0s-h1s) 2:h1c 3:(h0c-h1c) 4:hdw
// ---------------------------------------------------------------------------
__launch_bounds__(256)
__global__ void h_gemm(const bf16* __restrict__ xb, const bf16* __restrict__ db,
                       const float* __restrict__ Wsym, const float* __restrict__ Wcon,
                       const float* __restrict__ Wdis, bf16* __restrict__ hbuf) {
    __shared__ __align__(16) short WT[2 * 4608];   // [p][n][72] bf16
    const int tid = threadIdx.x;
    const int y = blockIdx.y;
    const float* Wp0 = (y == 0) ? Wsym        : (y == 1) ? Wcon        : Wdis;
    const float* Wp1 = (y == 0) ? Wsym + 4096 : (y == 1) ? Wcon + 4096 : Wdis;
    const bf16*  src = (y < 2) ? xb : db;

    for (int idx = tid; idx < 4096; idx += 256) {
        int k = idx >> 6, n = idx & 63;
        WT[n * 72 + k]        = fbf(Wp0[idx]);
        WT[4608 + n * 72 + k] = fbf(Wp1[idx]);
    }
    __syncthreads();

    const int w = tid >> 6, L = tid & 63;
    const int lane16 = L & 15, quad = L >> 4;
    const int R0 = blockIdx.x * 128 + w * 32;

    bf16x8 bfr[2][2][4];
    #pragma unroll
    for (int p = 0; p < 2; p++)
        #pragma unroll
        for (int kc = 0; kc < 2; kc++)
            #pragma unroll
            for (int nt = 0; nt < 4; nt++)
                bfr[p][kc][nt] = *(const bf16x8*)
                    &WT[p * 4608 + (nt * 16 + lane16) * 72 + kc * 32 + quad * 8];

    f32x4 acc[2][2][4];   // [p][rt][nt]
    #pragma unroll
    for (int p = 0; p < 2; p++)
        #pragma unroll
        for (int rt = 0; rt < 2; rt++)
            #pragma unroll
            for (int nt = 0; nt < 4; nt++) acc[p][rt][nt] = (f32x4){0.f, 0.f, 0.f, 0.f};

    #pragma unroll
    for (int kc = 0; kc < 2; kc++) {
        bf16x8 av[2];
        #pragma unroll
        for (int rt = 0; rt < 2; rt++) {
            int row = R0 + rt * 16 + lane16;
            av[rt] = *(const bf16x8*)(src + (size_t)row * 64 + kc * 32 + quad * 8);
        }
        #pragma unroll
        for (int p = 0; p < 2; p++)
            #pragma unroll
            for (int nt = 0; nt < 4; nt++) {
                acc[p][0][nt] = __builtin_amdgcn_mfma_f32_16x16x32_bf16(av[0], bfr[p][kc][nt], acc[p][0][nt], 0, 0, 0);
                acc[p][1][nt] = __builtin_amdgcn_mfma_f32_16x16x32_bf16(av[1], bfr[p][kc][nt], acc[p][1][nt], 0, 0, 0);
            }
    }

    bf16* out0 = hbuf + (size_t)((y == 0) ? 0 : (y == 1) ? 2 : 4) * ELEMS;
    bf16* outD = hbuf + (size_t)((y == 0) ? 1 : 3) * ELEMS;   // y<2 only
    #pragma unroll
    for (int rt = 0; rt < 2; rt++)
        #pragma unroll
        for (int nt = 0; nt < 4; nt++)
            #pragma unroll
            for (int r = 0; r < 4; r++) {
                size_t idx = (size_t)(R0 + rt * 16 + quad * 4 + r) * 64 + nt * 16 + lane16;
                float h0v = acc[0][rt][nt][r];
                float h1v = acc[1][rt][nt][r];
                if (y < 2) {
                    out0[idx] = f2bf(h1v);
                    outD[idx] = f2bf(h0v - h1v);
                } else {
                    out0[idx] = f2bf(h0v);
                }
            }
}

// ---------------------------------------------------------------------------
// Kernel 4: per-bt mixer (verified R7 math); BN partials now go straight to
// device-scope atomic accumulators stats1[384] (one atomicAdd per value per
// block) instead of the part1 spill + starved reduction tree.
// ---------------------------------------------------------------------------
__launch_bounds__(256)
__global__ void mixer(const bf16* __restrict__ hbuf, const short* __restrict__ AAb,
                      const float* __restrict__ att, const float* __restrict__ bdis,
                      bf16* __restrict__ xs, bf16* __restrict__ yc,
                      bf16* __restrict__ z, float* __restrict__ stats1) {
    __shared__ __align__(16) short raw[5 * NO];    // reused as red
    __shared__ __align__(8)  ushort hhb[NO * 4];
    __shared__ __align__(4)  unsigned hdb[NO];
    __shared__ float attL[NN];
    float* red = (float*)raw;

    const int bt  = blockIdx.x;
    const int tid = threadIdx.x;
    const size_t base = (size_t)bt * NO;
    const int w = tid >> 6, L = tid & 63;

    for (int idx = tid; idx < 880; idx += 256) {   // 5 planes x 176 uint4
        int t = idx / 176, rem = idx - t * 176;
        ((uint4*)raw)[idx] = ((const uint4*)(hbuf + (size_t)t * ELEMS + base))[rem];
    }
    for (int idx = tid; idx < NN; idx += 256) attL[idx] = att[idx];
    __syncthreads();

    for (int idx = tid; idx < NO; idx += 256) {
        hhb[idx * 4 + 0] = (ushort)raw[idx];
        hhb[idx * 4 + 1] = (ushort)raw[2 * NO + idx];
        hhb[idx * 4 + 2] = (ushort)raw[4 * NO + idx];
        hhb[idx * 4 + 3] = 0;
        hdb[idx] = (unsigned)(ushort)raw[NO + idx] |
                   ((unsigned)(ushort)raw[3 * NO + idx] << 16);
    }
    __syncthreads();

    float mxs[6], myc[6], mz[6];
    #pragma unroll
    for (int k = 0; k < 6; k++) { mxs[k] = myc[k] = mz[k] = 0.f; }

    const unsigned* AAu = (const unsigned*)AAb;
    for (int j = 0; j < N_; j++) {
        uint2 hv = *(const uint2*)&hhb[(j * 64 + L) * 4];
        float h1s, h1c, hw, dum;
        unp(hv.x, h1s, h1c); unp(hv.y, hw, dum);
        #pragma unroll
        for (int k = 0; k < 6; k++) {
            int i  = w + 4 * k;
            int ii = (i < N_) ? i : 0;
            unsigned a = AAu[(size_t)(ii * N_ + j) * 64 + L];
            float as, ac; unp(a, as, ac);
            float atv = attL[ii * N_ + j];
            mxs[k] = fmaf(as,  h1s, mxs[k]);
            myc[k] = fmaf(ac,  h1c, myc[k]);
            mz[k]  = fmaf(atv, hw,  mz[k]);
        }
    }

    float bd = bdis[L];
    float st0 = 0.f, st1 = 0.f, st2 = 0.f, st3 = 0.f, st4 = 0.f, st5 = 0.f;
    #pragma unroll
    for (int k = 0; k < 6; k++) {
        int i = w + 4 * k;
        if (i < N_) {
            unsigned ad = AAu[(size_t)(i * 23) * 64 + L];
            float asd, acd; unp(ad, asd, acd);
            float dsv, dcv; unp(hdb[i * 64 + L], dsv, dcv);
            float xsv = mxs[k] + asd * dsv;
            float ycv = myc[k] + acd * dcv;
            float zv  = mz[k] + bd;
            size_t oi = base + i * 64 + L;
            xs[oi] = f2bf(xsv); yc[oi] = f2bf(ycv); z[oi] = f2bf(zv);
            st0 += xsv; st1 += xsv * xsv;
            st2 += ycv; st3 += ycv * ycv;
            st4 += zv;  st5 += zv  * zv;
        }
    }

    red[(w * 6 + 0) * 64 + L] = st0;
    red[(w * 6 + 1) * 64 + L] = st1;
    red[(w * 6 + 2) * 64 + L] = st2;
    red[(w * 6 + 3) * 64 + L] = st3;
    red[(w * 6 + 4) * 64 + L] = st4;
    red[(w * 6 + 5) * 64 + L] = st5;
    __syncthreads();
    for (int qq = tid; qq < 384; qq += 256) {
        int q = qq >> 6, oo = qq & 63;
        float v = (red[q * 64 + oo] + red[(6 + q) * 64 + oo]) +
                  (red[(12 + q) * 64 + oo] + red[(18 + q) * 64 + oo]);
        atomicAdd(&stats1[qq], v);
    }
}

// ---------------------------------------------------------------------------
// Kernel 5: BN affine from atomic stats. stats[(2t)*64+o]=sum,
// stats[(2t+1)*64+o]=sumsq; writes scale[t*128+{0,64}+o]. 1 block.
// ---------------------------------------------------------------------------
__global__ void scale_from_stats(const float* __restrict__ stats,
                                 const float* __restrict__ gammas,
                                 const float* __restrict__ betas,
                                 int nch, int gbase, float* __restrict__ scale) {
    int tid = threadIdx.x;
    if (tid >= nch * 64) return;
    int t = tid >> 6, o = tid & 63;
    float S  = stats[(2 * t) * 64 + o];
    float SS = stats[(2 * t + 1) * 64 + o];
    const float invn = 1.f / (float)BTN;
    float mu   = S * invn;
    float var  = SS * invn - mu * mu;
    float rstd = rsqrtf(var + 1e-5f);
    float a = gammas[(gbase + t) * 64 + o] * rstd;
    float c = betas[(gbase + t) * 64 + o] - mu * a;
    scale[t * 128 + o]      = a;
    scale[t * 128 + 64 + o] = c;
}

// ---------------------------------------------------------------------------
// Kernel 6: mix GEMM (verified R5-R7); partials -> atomic stats2[128]
// (stats2[o]=sum, stats2[64+o]=sumsq).
// ---------------------------------------------------------------------------
__launch_bounds__(256)
__global__ void mix_pass(const bf16* __restrict__ xs, const bf16* __restrict__ yc,
                         const bf16* __restrict__ z, const float* __restrict__ scale1,
                         const short* __restrict__ CB,
                         bf16* __restrict__ out2, float* __restrict__ stats2) {
    __shared__ float sL[384];
    __shared__ float red[512];

    const int tid = threadIdx.x;
    const int w = tid >> 6, L = tid & 63;
    const int lane16 = L & 15, quad = L >> 4;
    const int R0 = blockIdx.x * 128 + w * 32;

    for (int idx = tid; idx < 384; idx += 256) sL[idx] = scale1[idx];
    __syncthreads();

    const bf16* srcs[3] = { xs, yc, z };

    f32x4 acc[2][4];
    #pragma unroll
    for (int rt = 0; rt < 2; rt++)
        #pragma unroll
        for (int nt = 0; nt < 4; nt++)
            acc[rt][nt] = (f32x4){0.f, 0.f, 0.f, 0.f};

    #pragma unroll
    for (int kc = 0; kc < 6; kc++) {
        const int src = kc >> 1;
        const int c0  = (kc & 1) * 32 + quad * 8;
        bf16x8 av[2];
        #pragma unroll
        for (int rt = 0; rt < 2; rt++) {
            int row = R0 + rt * 16 + lane16;
            uint4 u = *(const uint4*)(srcs[src] + (size_t)row * 64 + c0);
            float v[8];
            unp(u.x, v[0], v[1]); unp(u.y, v[2], v[3]);
            unp(u.z, v[4], v[5]); unp(u.w, v[6], v[7]);
            #pragma unroll
            for (int e = 0; e < 8; e++) {
                float t = fmaxf(fmaf(v[e], sL[src * 128 + c0 + e],
                                     sL[src * 128 + 64 + c0 + e]), 0.f);
                av[rt][e] = fbf(t);
            }
        }
        #pragma unroll
        for (int nt = 0; nt < 4; nt++) {
            bf16x8 bw = ((const bf16x8*)CB)[(nt * 6 + kc) * 64 + L];
            acc[0][nt] = __builtin_amdgcn_mfma_f32_16x16x32_bf16(av[0], bw, acc[0][nt], 0, 0, 0);
            acc[1][nt] = __builtin_amdgcn_mfma_f32_16x16x32_bf16(av[1], bw, acc[1][nt], 0, 0, 0);
        }
    }

    float s[4]  = {0.f, 0.f, 0.f, 0.f};
    float s2[4] = {0.f, 0.f, 0.f, 0.f};
    #pragma unroll
    for (int rt = 0; rt < 2; rt++)
        #pragma unroll
        for (int nt = 0; nt < 4; nt++)
            #pragma unroll
            for (int r = 0; r < 4; r++) {
                int row = R0 + rt * 16 + quad * 4 + r;
                int col = nt * 16 + lane16;
                float v = acc[rt][nt][r];
                out2[(size_t)row * 64 + col] = f2bf(v);
                s[nt] += v; s2[nt] += v * v;
            }
    #pragma unroll
    for (int nt = 0; nt < 4; nt++) {
        s[nt]  += __shfl_xor(s[nt], 16);
        s[nt]  += __shfl_xor(s[nt], 32);
        s2[nt] += __shfl_xor(s2[nt], 16);
        s2[nt] += __shfl_xor(s2[nt], 32);
    }
    if (quad == 0) {
        #pragma unroll
        for (int nt = 0; nt < 4; nt++) {
            red[w * 64 + nt * 16 + lane16]       = s[nt];
            red[256 + w * 64 + nt * 16 + lane16] = s2[nt];
        }
    }
    __syncthreads();
    if (tid < 64) {
        float t = red[tid] + red[64 + tid] + red[128 + tid] + red[192 + tid];
        atomicAdd(&stats2[tid], t);
    } else if (tid < 128) {
        int c = tid - 64;
        float t = red[256 + c] + red[320 + c] + red[384 + c] + red[448 + c];
        atomicAdd(&stats2[64 + c], t);
    }
}

// ---------------------------------------------------------------------------
// Kernel 7: final BN + ReLU + f32 store (verified, unchanged).
// ---------------------------------------------------------------------------
__global__ void final_pass(const bf16* __restrict__ out2, const float* __restrict__ scale2,
                           float* __restrict__ out) {
    const int gid = blockIdx.x * 256 + threadIdx.x;
    const int idx = gid * 4;
    ushort4 u = reinterpret_cast<const ushort4*>(out2)[gid];
    const int o = idx & 63;
    float f0, f1, f2, f3;
    unp((unsigned)u.x | ((unsigned)u.y << 16), f0, f1);
    unp((unsigned)u.z | ((unsigned)u.w << 16), f2, f3);
    float4 r;
    r.x = fmaxf(fmaf(f0, scale2[o],     scale2[64 + o]),     0.f);
    r.y = fmaxf(fmaf(f1, scale2[o + 1], scale2[64 + o + 1]), 0.f);
    r.z = fmaxf(fmaf(f2, scale2[o + 2], scale2[64 + o + 2]), 0.f);
    r.w = fmaxf(fmaf(f3, scale2[o + 3], scale2[64 + o + 3]), 0.f);
    reinterpret_cast<float4*>(out)[gid] = r;
}

// ---------------------------------------------------------------------------
extern "C" void kernel_launch(void* const* d_in, const int* in_sizes, int n_in,
                              void* d_out, int out_size, void* d_ws, size_t ws_size,
                              hipStream_t stream) {
    const float* x      = (const float*)d_in[0];
    const float* W_sym  = (const float*)d_in[1];
    const float* e_sym  = (const float*)d_in[2];
    const float* W_con  = (const float*)d_in[3];
    const float* e_con  = (const float*)d_in[4];
    const float* W_dis  = (const float*)d_in[5];
    const float* att    = (const float*)d_in[6];
    const float* b_dis  = (const float*)d_in[7];
    const float* cat_w  = (const float*)d_in[8];
    const float* gammas = (const float*)d_in[9];
    const float* betas  = (const float*)d_in[10];
    const int* rows_sym = (const int*)d_in[11];
    const int* cols_sym = (const int*)d_in[12];
    const int* rows_con = (const int*)d_in[13];
    const int* cols_con = (const int*)d_in[14];
    const int nnz_s = in_sizes[2] / 64;
    const int nnz_c = in_sizes[4] / 64;

    // Workspace carve. out2 aliases xb (dead after h_gemm; out2 written later).
    char* p = (char*)d_ws;
    float* stats  = (float*)p; p += 512 * 4;                   // stats1[384] + stats2[128]
    float* scale1 = (float*)p; p += 384 * 4;
    float* scale2 = (float*)p; p += 128 * 4;
    short* AAb    = (short*)p; p += (size_t)NN * 64 * 2 * 2;
    short* CB     = (short*)p; p += (size_t)1536 * 8 * 2;
    bf16*  xb     = (bf16*)p;  p += (size_t)ELEMS * 2;
    bf16*  db     = (bf16*)p;  p += (size_t)ELEMS * 2;
    bf16*  xsb    = (bf16*)p;  p += (size_t)ELEMS * 2;
    bf16*  ycb    = (bf16*)p;  p += (size_t)ELEMS * 2;
    bf16*  zb     = (bf16*)p;  p += (size_t)ELEMS * 2;
    bf16*  hbuf   = (bf16*)p;  p += (size_t)ELEMS * 5 * 2;
    bf16*  out2   = xb;
    float* stats1 = stats;
    float* stats2 = stats + 384;

    hipMemsetAsync(stats, 0, 512 * 4, stream);
    prep_kernel<<<17, 256, 0, stream>>>(e_sym, rows_sym, cols_sym, nnz_s,
                                        e_con, rows_con, cols_con, nnz_c,
                                        cat_w, AAb, CB);
    pre_pass<<<BT, 64, 0, stream>>>(x, xb, db);
    h_gemm<<<dim3(550, 3), 256, 0, stream>>>(xb, db, W_sym, W_con, W_dis, hbuf);
    mixer<<<BT, 256, 0, stream>>>(hbuf, AAb, att, b_dis, xsb, ycb, zb, stats1);
    scale_from_stats<<<1, 192, 0, stream>>>(stats1, gammas, betas, 3, 0, scale1);
    mix_pass<<<550, 256, 0, stream>>>(xsb, ycb, zb, scale1, CB, out2, stats2);
    scale_from_stats<<<1, 64, 0, stream>>>(stats2, gammas, betas, 1, 3, scale2);
    final_pass<<<ELEMS / 1024, 256, 0, stream>>>(out2, scale2, (float*)d_out);
}

// Round 9
// 259.535 us; speedup vs baseline: 3.8407x; 1.1270x over previous
//
#include <hip/hip_runtime.h>
#include <hip/hip_bf16.h>

typedef __hip_bfloat16 bf16;
typedef __attribute__((ext_vector_type(8))) short bf16x8;
typedef __attribute__((ext_vector_type(4))) float f32x4;

#define BT    3200
#define N_    22
#define NO    1408           // N_*64
#define NN    484
#define BTN   70400
#define ELEMS 4505600        // BT*N_*64

static __device__ __forceinline__ bf16  f2bf(float v) { return __float2bfloat16(v); }
static __device__ __forceinline__ short fbf(float v) {
    bf16 h = __float2bfloat16(v);
    return *reinterpret_cast<short*>(&h);
}
static __device__ __forceinline__ float sbf(short s) {
    return __uint_as_float(((unsigned)(unsigned short)s) << 16);
}
static __device__ __forceinline__ void unp(unsigned u, float& lo, float& hi) {
    lo = __uint_as_float(u << 16);
    hi = __uint_as_float(u & 0xffff0000u);
}

// ---------------------------------------------------------------------------
// Kernel 1 (prep): blocks 0-10 build softmax adjacency as packed bf16 pairs
// AAb[((i*22+j)*64+o)*2 + t]; blocks 11-16 pack cat_w into MFMA B-fragments.
// (verified R5-R8)
// ---------------------------------------------------------------------------
__global__ void prep_kernel(const float* __restrict__ e_s, const int* __restrict__ rs,
                            const int* __restrict__ cs, int nnz_s,
                            const float* __restrict__ e_c, const int* __restrict__ rc,
                            const int* __restrict__ cc, int nnz_c,
                            const float* __restrict__ cat_w,
                            short* __restrict__ AAb, short* __restrict__ CB) {
    const int tid = threadIdx.x;
    if (blockIdx.x < 11) {
        int id = blockIdx.x * 256 + tid;           // 0..2815
        if (id >= 2 * 64 * N_) return;
        int t   = id / (64 * N_);
        int rem = id % (64 * N_);
        int o   = rem / N_;
        int i   = rem % N_;
        const float* e    = t ? e_c : e_s;
        const int*   rows = t ? rc  : rs;
        const int*   cols = t ? cc  : cs;
        int          nnz  = t ? nnz_c : nnz_s;
        float row[N_];
        #pragma unroll
        for (int j = 0; j < N_; j++) row[j] = 0.f;
        float s = 0.f;
        for (int k = 0; k < nnz; k++) {
            if (rows[k] == i) {
                float v = expf(e[o * nnz + k]);
                row[cols[k]] = v;
                s += v;
            }
        }
        float inv = 1.f / s;
        for (int j = 0; j < N_; j++)
            AAb[((size_t)(i * N_ + j) * 64 + o) * 2 + t] = fbf(row[j] * inv);
    } else {
        int gi = (blockIdx.x - 11) * 256 + tid;    // 0..1535
        if (gi >= 1536) return;
        int nt = gi / 384, rem = gi % 384;
        int kc = rem >> 6, L = rem & 63;
        int n = nt * 16 + (L & 15);
        int kbase = kc * 32 + (L >> 4) * 8;
        float4 w0 = *(const float4*)&cat_w[n * 192 + kbase];
        float4 w1 = *(const float4*)&cat_w[n * 192 + kbase + 4];
        bf16x8 frag;
        frag[0] = fbf(w0.x); frag[1] = fbf(w0.y); frag[2] = fbf(w0.z); frag[3] = fbf(w0.w);
        frag[4] = fbf(w1.x); frag[5] = fbf(w1.y); frag[6] = fbf(w1.z); frag[7] = fbf(w1.w);
        ((bf16x8*)CB)[gi] = frag;
    }
}

// ---------------------------------------------------------------------------
// Kernel 2: per-bt stats + cast (verified R6-R8, unchanged).
// ---------------------------------------------------------------------------
__global__ void pre_pass(const float* __restrict__ x,
                         bf16* __restrict__ xb, bf16* __restrict__ db) {
    __shared__ float xt[NO];
    const int bt = blockIdx.x, tid = threadIdx.x;    // 64 threads
    const size_t base = (size_t)bt * NO;
    for (int idx = tid; idx < NO / 4; idx += 64)
        ((float4*)xt)[idx] = ((const float4*)(x + base))[idx];
    __syncthreads();
    float s = 0.f, s2 = 0.f;
    #pragma unroll
    for (int i = 0; i < N_; i++) { float v = xt[i * 64 + tid]; s += v; s2 += v * v; }
    #pragma unroll
    for (int i = 0; i < N_; i++) {
        float v  = xt[i * 64 + tid];
        float d2 = s2 - 2.f * v * s + (float)N_ * v * v;
        float d  = sqrtf(fmaxf(d2, 0.f)) + 1e-8f;
        xb[base + i * 64 + tid] = f2bf(v);
        db[base + i * 64 + tid] = f2bf(d);
    }
}

// ---------------------------------------------------------------------------
// Kernel 3: h GEMM (verified R7/R8 compute; epilogue now packs plane pairs).
// Output planes: P01[idx] = {h1s | (h0s-h1s)<<16}  (y=0, uint)
//                P23[idx] = {h1c | (h0c-h1c)<<16}  (y=1, uint)
//                P4 [idx] = hdw                    (y=2, bf16)
// ---------------------------------------------------------------------------
__launch_bounds__(256)
__global__ void h_gemm(const bf16* __restrict__ xb, const bf16* __restrict__ db,
                       const float* __restrict__ Wsym, const float* __restrict__ Wcon,
                       const float* __restrict__ Wdis,
                       unsigned* __restrict__ P01, unsigned* __restrict__ P23,
                       short* __restrict__ P4) {
    __shared__ __align__(16) short WT[2 * 4608];   // [p][n][72] bf16
    const int tid = threadIdx.x;
    const int y = blockIdx.y;
    const float* Wp0 = (y == 0) ? Wsym        : (y == 1) ? Wcon        : Wdis;
    const float* Wp1 = (y == 0) ? Wsym + 4096 : (y == 1) ? Wcon + 4096 : Wdis;
    const bf16*  src = (y < 2) ? xb : db;

    for (int idx = tid; idx < 4096; idx += 256) {
        int k = idx >> 6, n = idx & 63;
        WT[n * 72 + k]        = fbf(Wp0[idx]);
        WT[4608 + n * 72 + k] = fbf(Wp1[idx]);
    }
    __syncthreads();

    const int w = tid >> 6, L = tid & 63;
    const int lane16 = L & 15, quad = L >> 4;
    const int R0 = blockIdx.x * 128 + w * 32;

    bf16x8 bfr[2][2][4];
    #pragma unroll
    for (int p = 0; p < 2; p++)
        #pragma unroll
        for (int kc = 0; kc < 2; kc++)
            #pragma unroll
            for (int nt = 0; nt < 4; nt++)
                bfr[p][kc][nt] = *(const bf16x8*)
                    &WT[p * 4608 + (nt * 16 + lane16) * 72 + kc * 32 + quad * 8];

    f32x4 acc[2][2][4];   // [p][rt][nt]
    #pragma unroll
    for (int p = 0; p < 2; p++)
        #pragma unroll
        for (int rt = 0; rt < 2; rt++)
            #pragma unroll
            for (int nt = 0; nt < 4; nt++) acc[p][rt][nt] = (f32x4){0.f, 0.f, 0.f, 0.f};

    #pragma unroll
    for (int kc = 0; kc < 2; kc++) {
        bf16x8 av[2];
        #pragma unroll
        for (int rt = 0; rt < 2; rt++) {
            int row = R0 + rt * 16 + lane16;
            av[rt] = *(const bf16x8*)(src + (size_t)row * 64 + kc * 32 + quad * 8);
        }
        #pragma unroll
        for (int p = 0; p < 2; p++)
            #pragma unroll
            for (int nt = 0; nt < 4; nt++) {
                acc[p][0][nt] = __builtin_amdgcn_mfma_f32_16x16x32_bf16(av[0], bfr[p][kc][nt], acc[p][0][nt], 0, 0, 0);
                acc[p][1][nt] = __builtin_amdgcn_mfma_f32_16x16x32_bf16(av[1], bfr[p][kc][nt], acc[p][1][nt], 0, 0, 0);
            }
    }

    unsigned* Pu = (y == 0) ? P01 : P23;
    #pragma unroll
    for (int rt = 0; rt < 2; rt++)
        #pragma unroll
        for (int nt = 0; nt < 4; nt++)
            #pragma unroll
            for (int r = 0; r < 4; r++) {
                size_t idx = (size_t)(R0 + rt * 16 + quad * 4 + r) * 64 + nt * 16 + lane16;
                float h0v = acc[0][rt][nt][r];
                float h1v = acc[1][rt][nt][r];
                if (y < 2) {
                    Pu[idx] = (unsigned)(unsigned short)fbf(h1v) |
                              ((unsigned)(unsigned short)fbf(h0v - h1v) << 16);
                } else {
                    P4[idx] = fbf(h0v);
                }
            }
}

// ---------------------------------------------------------------------------
// Kernel 4: per-bt mixer v3. Packed planes land in LDS directly (no repack):
// pp[0..NO) = {h1s|ds<<16}, pp[NO..2NO) = {h1c|dc<<16}, p2 = hw (bf16).
// LDS ~16 KB -> high occupancy. BN partials -> 8-way-sharded atomic stats.
// Mixing math identical to verified R7/R8.
// ---------------------------------------------------------------------------
__launch_bounds__(256)
__global__ void mixer(const unsigned* __restrict__ P01, const unsigned* __restrict__ P23,
                      const short* __restrict__ P4, const short* __restrict__ AAb,
                      const float* __restrict__ att, const float* __restrict__ bdis,
                      bf16* __restrict__ xs, bf16* __restrict__ yc,
                      bf16* __restrict__ z, float* __restrict__ stats1) {
    __shared__ __align__(16) unsigned pp[2 * NO];  // 11.3 KB; reused as red (6 KB)
    __shared__ __align__(16) short p2[NO];         // 2.8 KB
    __shared__ float attL[NN];                     // 1.9 KB
    float* red = (float*)pp;

    const int bt  = blockIdx.x;
    const int tid = threadIdx.x;
    const size_t base = (size_t)bt * NO;
    const int w = tid >> 6, L = tid & 63;

    for (int idx = tid; idx < 880; idx += 256) {
        if (idx < 352)      ((uint4*)pp)[idx]              = ((const uint4*)(P01 + base))[idx];
        else if (idx < 704) ((uint4*)(pp + NO))[idx - 352] = ((const uint4*)(P23 + base))[idx - 352];
        else                ((uint4*)p2)[idx - 704]        = ((const uint4*)(P4 + base))[idx - 704];
    }
    for (int idx = tid; idx < NN; idx += 256) attL[idx] = att[idx];
    __syncthreads();

    float mxs[6], myc[6], mz[6];
    #pragma unroll
    for (int k = 0; k < 6; k++) { mxs[k] = myc[k] = mz[k] = 0.f; }

    const unsigned* AAu = (const unsigned*)AAb;
    for (int j = 0; j < N_; j++) {
        unsigned u0 = pp[j * 64 + L];
        unsigned u1 = pp[NO + j * 64 + L];
        float h1s, h1c, dum;
        unp(u0, h1s, dum);
        unp(u1, h1c, dum);
        float hw = sbf(p2[j * 64 + L]);
        #pragma unroll
        for (int k = 0; k < 6; k++) {
            int i  = w + 4 * k;
            int ii = (i < N_) ? i : 0;
            unsigned a = AAu[(size_t)(ii * N_ + j) * 64 + L];
            float as, ac; unp(a, as, ac);
            float atv = attL[ii * N_ + j];
            mxs[k] = fmaf(as,  h1s, mxs[k]);
            myc[k] = fmaf(ac,  h1c, myc[k]);
            mz[k]  = fmaf(atv, hw,  mz[k]);
        }
    }

    float bd = bdis[L];
    float st0 = 0.f, st1 = 0.f, st2 = 0.f, st3 = 0.f, st4 = 0.f, st5 = 0.f;
    #pragma unroll
    for (int k = 0; k < 6; k++) {
        int i = w + 4 * k;
        if (i < N_) {
            unsigned ad = AAu[(size_t)(i * 23) * 64 + L];
            float asd, acd; unp(ad, asd, acd);
            float dum, dsv, dcv;
            unp(pp[i * 64 + L], dum, dsv);        // hi half = ds
            unp(pp[NO + i * 64 + L], dum, dcv);   // hi half = dc
            float xsv = mxs[k] + asd * dsv;
            float ycv = myc[k] + acd * dcv;
            float zv  = mz[k] + bd;
            size_t oi = base + i * 64 + L;
            xs[oi] = f2bf(xsv); yc[oi] = f2bf(ycv); z[oi] = f2bf(zv);
            st0 += xsv; st1 += xsv * xsv;
            st2 += ycv; st3 += ycv * ycv;
            st4 += zv;  st5 += zv  * zv;
        }
    }

    __syncthreads();                // all pp reads done; reuse as red
    red[(w * 6 + 0) * 64 + L] = st0;
    red[(w * 6 + 1) * 64 + L] = st1;
    red[(w * 6 + 2) * 64 + L] = st2;
    red[(w * 6 + 3) * 64 + L] = st3;
    red[(w * 6 + 4) * 64 + L] = st4;
    red[(w * 6 + 5) * 64 + L] = st5;
    __syncthreads();
    float* myStats = stats1 + (size_t)(bt & 7) * 384;   // 8-way shard
    for (int qq = tid; qq < 384; qq += 256) {
        int q = qq >> 6, oo = qq & 63;
        float v = (red[q * 64 + oo] + red[(6 + q) * 64 + oo]) +
                  (red[(12 + q) * 64 + oo] + red[(18 + q) * 64 + oo]);
        atomicAdd(&myStats[qq], v);
    }
}

// ---------------------------------------------------------------------------
// Kernel 5: BN affine from (sharded) atomic stats.
// stats layout per shard: [(2t)*64+o]=sum, [(2t+1)*64+o]=sumsq.
// ---------------------------------------------------------------------------
__global__ void scale_from_stats(const float* __restrict__ stats,
                                 const float* __restrict__ gammas,
                                 const float* __restrict__ betas,
                                 int nch, int gbase, int nshard, int sstride,
                                 float* __restrict__ scale) {
    int tid = threadIdx.x;
    if (tid >= nch * 64) return;
    int t = tid >> 6, o = tid & 63;
    float S = 0.f, SS = 0.f;
    for (int s = 0; s < nshard; s++) {
        S  += stats[s * sstride + (2 * t) * 64 + o];
        SS += stats[s * sstride + (2 * t + 1) * 64 + o];
    }
    const float invn = 1.f / (float)BTN;
    float mu   = S * invn;
    float var  = SS * invn - mu * mu;
    float rstd = rsqrtf(var + 1e-5f);
    float a = gammas[(gbase + t) * 64 + o] * rstd;
    float c = betas[(gbase + t) * 64 + o] - mu * a;
    scale[t * 128 + o]      = a;
    scale[t * 128 + 64 + o] = c;
}

// ---------------------------------------------------------------------------
// Kernel 6: mix GEMM (verified R5-R8); partials -> atomic stats2[128]
// (550 adds/address — low contention, unsharded).
// ---------------------------------------------------------------------------
__launch_bounds__(256)
__global__ void mix_pass(const bf16* __restrict__ xs, const bf16* __restrict__ yc,
                         const bf16* __restrict__ z, const float* __restrict__ scale1,
                         const short* __restrict__ CB,
                         bf16* __restrict__ out2, float* __restrict__ stats2) {
    __shared__ float sL[384];
    __shared__ float red[512];

    const int tid = threadIdx.x;
    const int w = tid >> 6, L = tid & 63;
    const int lane16 = L & 15, quad = L >> 4;
    const int R0 = blockIdx.x * 128 + w * 32;

    for (int idx = tid; idx < 384; idx += 256) sL[idx] = scale1[idx];
    __syncthreads();

    const bf16* srcs[3] = { xs, yc, z };

    f32x4 acc[2][4];
    #pragma unroll
    for (int rt = 0; rt < 2; rt++)
        #pragma unroll
        for (int nt = 0; nt < 4; nt++)
            acc[rt][nt] = (f32x4){0.f, 0.f, 0.f, 0.f};

    #pragma unroll
    for (int kc = 0; kc < 6; kc++) {
        const int src = kc >> 1;
        const int c0  = (kc & 1) * 32 + quad * 8;
        bf16x8 av[2];
        #pragma unroll
        for (int rt = 0; rt < 2; rt++) {
            int row = R0 + rt * 16 + lane16;
            uint4 u = *(const uint4*)(srcs[src] + (size_t)row * 64 + c0);
            float v[8];
            unp(u.x, v[0], v[1]); unp(u.y, v[2], v[3]);
            unp(u.z, v[4], v[5]); unp(u.w, v[6], v[7]);
            #pragma unroll
            for (int e = 0; e < 8; e++) {
                float t = fmaxf(fmaf(v[e], sL[src * 128 + c0 + e],
                                     sL[src * 128 + 64 + c0 + e]), 0.f);
                av[rt][e] = fbf(t);
            }
        }
        #pragma unroll
        for (int nt = 0; nt < 4; nt++) {
            bf16x8 bw = ((const bf16x8*)CB)[(nt * 6 + kc) * 64 + L];
            acc[0][nt] = __builtin_amdgcn_mfma_f32_16x16x32_bf16(av[0], bw, acc[0][nt], 0, 0, 0);
            acc[1][nt] = __builtin_amdgcn_mfma_f32_16x16x32_bf16(av[1], bw, acc[1][nt], 0, 0, 0);
        }
    }

    float s[4]  = {0.f, 0.f, 0.f, 0.f};
    float s2[4] = {0.f, 0.f, 0.f, 0.f};
    #pragma unroll
    for (int rt = 0; rt < 2; rt++)
        #pragma unroll
        for (int nt = 0; nt < 4; nt++)
            #pragma unroll
            for (int r = 0; r < 4; r++) {
                int row = R0 + rt * 16 + quad * 4 + r;
                int col = nt * 16 + lane16;
                float v = acc[rt][nt][r];
                out2[(size_t)row * 64 + col] = f2bf(v);
                s[nt] += v; s2[nt] += v * v;
            }
    #pragma unroll
    for (int nt = 0; nt < 4; nt++) {
        s[nt]  += __shfl_xor(s[nt], 16);
        s[nt]  += __shfl_xor(s[nt], 32);
        s2[nt] += __shfl_xor(s2[nt], 16);
        s2[nt] += __shfl_xor(s2[nt], 32);
    }
    if (quad == 0) {
        #pragma unroll
        for (int nt = 0; nt < 4; nt++) {
            red[w * 64 + nt * 16 + lane16]       = s[nt];
            red[256 + w * 64 + nt * 16 + lane16] = s2[nt];
        }
    }
    __syncthreads();
    if (tid < 64) {
        float t = red[tid] + red[64 + tid] + red[128 + tid] + red[192 + tid];
        atomicAdd(&stats2[tid], t);
    } else if (tid < 128) {
        int c = tid - 64;
        float t = red[256 + c] + red[320 + c] + red[384 + c] + red[448 + c];
        atomicAdd(&stats2[64 + c], t);
    }
}

// ---------------------------------------------------------------------------
// Kernel 7: final BN + ReLU + f32 store (verified, unchanged).
// ---------------------------------------------------------------------------
__global__ void final_pass(const bf16* __restrict__ out2, const float* __restrict__ scale2,
                           float* __restrict__ out) {
    const int gid = blockIdx.x * 256 + threadIdx.x;
    const int idx = gid * 4;
    ushort4 u = reinterpret_cast<const ushort4*>(out2)[gid];
    const int o = idx & 63;
    float f0, f1, f2, f3;
    unp((unsigned)u.x | ((unsigned)u.y << 16), f0, f1);
    unp((unsigned)u.z | ((unsigned)u.w << 16), f2, f3);
    float4 r;
    r.x = fmaxf(fmaf(f0, scale2[o],     scale2[64 + o]),     0.f);
    r.y = fmaxf(fmaf(f1, scale2[o + 1], scale2[64 + o + 1]), 0.f);
    r.z = fmaxf(fmaf(f2, scale2[o + 2], scale2[64 + o + 2]), 0.f);
    r.w = fmaxf(fmaf(f3, scale2[o + 3], scale2[64 + o + 3]), 0.f);
    reinterpret_cast<float4*>(out)[gid] = r;
}

// ---------------------------------------------------------------------------
extern "C" void kernel_launch(void* const* d_in, const int* in_sizes, int n_in,
                              void* d_out, int out_size, void* d_ws, size_t ws_size,
                              hipStream_t stream) {
    const float* x      = (const float*)d_in[0];
    const float* W_sym  = (const float*)d_in[1];
    const float* e_sym  = (const float*)d_in[2];
    const float* W_con  = (const float*)d_in[3];
    const float* e_con  = (const float*)d_in[4];
    const float* W_dis  = (const float*)d_in[5];
    const float* att    = (const float*)d_in[6];
    const float* b_dis  = (const float*)d_in[7];
    const float* cat_w  = (const float*)d_in[8];
    const float* gammas = (const float*)d_in[9];
    const float* betas  = (const float*)d_in[10];
    const int* rows_sym = (const int*)d_in[11];
    const int* cols_sym = (const int*)d_in[12];
    const int* rows_con = (const int*)d_in[13];
    const int* cols_con = (const int*)d_in[14];
    const int nnz_s = in_sizes[2] / 64;
    const int nnz_c = in_sizes[4] / 64;

    // Workspace carve. out2 aliases xb (dead after h_gemm; out2 written later).
    char* p = (char*)d_ws;
    float* stats  = (float*)p; p += (8 * 384 + 128) * 4;       // stats1 shards + stats2
    float* scale1 = (float*)p; p += 384 * 4;
    float* scale2 = (float*)p; p += 128 * 4;
    short* AAb    = (short*)p; p += (size_t)NN * 64 * 2 * 2;
    short* CB     = (short*)p; p += (size_t)1536 * 8 * 2;
    bf16*  xb     = (bf16*)p;  p += (size_t)ELEMS * 2;
    bf16*  db     = (bf16*)p;  p += (size_t)ELEMS * 2;
    bf16*  xsb    = (bf16*)p;  p += (size_t)ELEMS * 2;
    bf16*  ycb    = (bf16*)p;  p += (size_t)ELEMS * 2;
    bf16*  zb     = (bf16*)p;  p += (size_t)ELEMS * 2;
    unsigned* P01 = (unsigned*)p; p += (size_t)ELEMS * 4;      // {h1s|ds}
    unsigned* P23 = (unsigned*)p; p += (size_t)ELEMS * 4;      // {h1c|dc}
    short*    P4  = (short*)p;    p += (size_t)ELEMS * 2;      // hdw
    bf16*  out2   = xb;
    float* stats1 = stats;
    float* stats2 = stats + 8 * 384;

    hipMemsetAsync(stats, 0, (8 * 384 + 128) * 4, stream);
    prep_kernel<<<17, 256, 0, stream>>>(e_sym, rows_sym, cols_sym, nnz_s,
                                        e_con, rows_con, cols_con, nnz_c,
                                        cat_w, AAb, CB);
    pre_pass<<<BT, 64, 0, stream>>>(x, xb, db);
    h_gemm<<<dim3(550, 3), 256, 0, stream>>>(xb, db, W_sym, W_con, W_dis, P01, P23, P4);
    mixer<<<BT, 256, 0, stream>>>(P01, P23, P4, AAb, att, b_dis, xsb, ycb, zb, stats1);
    scale_from_stats<<<1, 192, 0, stream>>>(stats1, gammas, betas, 3, 0, 8, 384, scale1);
    mix_pass<<<550, 256, 0, stream>>>(xsb, ycb, zb, scale1, CB, out2, stats2);
    scale_from_stats<<<1, 64, 0, stream>>>(stats2, gammas, betas, 1, 3, 1, 0, scale2);
    final_pass<<<ELEMS / 1024, 256, 0, stream>>>(out2, scale2, (float*)d_out);
}

// Round 10
// 244.536 us; speedup vs baseline: 4.0763x; 1.0613x over previous
//
#include <hip/hip_runtime.h>
#include <hip/hip_bf16.h>

typedef __hip_bfloat16 bf16;
typedef __attribute__((ext_vector_type(8))) short bf16x8;
typedef __attribute__((ext_vector_type(4))) float f32x4;

#define BT    3200
#define N_    22
#define NO    1408           // N_*64
#define NN    484
#define BTN   70400
#define ELEMS 4505600        // BT*N_*64

static __device__ __forceinline__ bf16  f2bf(float v) { return __float2bfloat16(v); }
static __device__ __forceinline__ short fbf(float v) {
    bf16 h = __float2bfloat16(v);
    return *reinterpret_cast<short*>(&h);
}
static __device__ __forceinline__ float sbf(short s) {
    return __uint_as_float(((unsigned)(unsigned short)s) << 16);
}
static __device__ __forceinline__ void unp(unsigned u, float& lo, float& hi) {
    lo = __uint_as_float(u << 16);
    hi = __uint_as_float(u & 0xffff0000u);
}

// ---------------------------------------------------------------------------
// Kernel 1 (prep): blocks 0-10 AAb softmax pairs (verified R5-R9);
// blocks 11-16 CB cat_w fragments (verified R5-R9);
// blocks 17-26 WB: 5 W planes {sym0,sym1,con0,con1,dis} packed as MFMA
// B-fragments WB[((p*2+kc)*4+nt)*64+L] — same mapping as CB / h_gemm's
// verified in-LDS build: frag[j] = W_p[k=kc*32+quad*8+j][n=nt*16+lane16].
// ---------------------------------------------------------------------------
__global__ void prep_kernel(const float* __restrict__ e_s, const int* __restrict__ rs,
                            const int* __restrict__ cs, int nnz_s,
                            const float* __restrict__ e_c, const int* __restrict__ rc,
                            const int* __restrict__ cc, int nnz_c,
                            const float* __restrict__ cat_w,
                            const float* __restrict__ Wsym, const float* __restrict__ Wcon,
                            const float* __restrict__ Wdis,
                            short* __restrict__ AAb, short* __restrict__ CB,
                            short* __restrict__ WB) {
    const int tid = threadIdx.x;
    if (blockIdx.x < 11) {
        int id = blockIdx.x * 256 + tid;           // 0..2815
        if (id >= 2 * 64 * N_) return;
        int t   = id / (64 * N_);
        int rem = id % (64 * N_);
        int o   = rem / N_;
        int i   = rem % N_;
        const float* e    = t ? e_c : e_s;
        const int*   rows = t ? rc  : rs;
        const int*   cols = t ? cc  : cs;
        int          nnz  = t ? nnz_c : nnz_s;
        float row[N_];
        #pragma unroll
        for (int j = 0; j < N_; j++) row[j] = 0.f;
        float s = 0.f;
        for (int k = 0; k < nnz; k++) {
            if (rows[k] == i) {
                float v = expf(e[o * nnz + k]);
                row[cols[k]] = v;
                s += v;
            }
        }
        float inv = 1.f / s;
        for (int j = 0; j < N_; j++)
            AAb[((size_t)(i * N_ + j) * 64 + o) * 2 + t] = fbf(row[j] * inv);
    } else if (blockIdx.x < 17) {
        int gi = (blockIdx.x - 11) * 256 + tid;    // 0..1535
        if (gi >= 1536) return;
        int nt = gi / 384, rem = gi % 384;
        int kc = rem >> 6, L = rem & 63;
        int n = nt * 16 + (L & 15);
        int kbase = kc * 32 + (L >> 4) * 8;
        float4 w0 = *(const float4*)&cat_w[n * 192 + kbase];
        float4 w1 = *(const float4*)&cat_w[n * 192 + kbase + 4];
        bf16x8 frag;
        frag[0] = fbf(w0.x); frag[1] = fbf(w0.y); frag[2] = fbf(w0.z); frag[3] = fbf(w0.w);
        frag[4] = fbf(w1.x); frag[5] = fbf(w1.y); frag[6] = fbf(w1.z); frag[7] = fbf(w1.w);
        ((bf16x8*)CB)[gi] = frag;
    } else {
        int gi = (blockIdx.x - 17) * 256 + tid;    // 0..2559
        if (gi >= 2560) return;
        int L = gi & 63;
        int q = gi >> 6;          // 0..39
        int nt = q & 3;
        int pk = q >> 2;          // 0..9
        int kc = pk & 1;
        int p  = pk >> 1;         // 0..4
        const float* Wsrc = (p == 0) ? Wsym :
                            (p == 1) ? Wsym + 4096 :
                            (p == 2) ? Wcon :
                            (p == 3) ? Wcon + 4096 : Wdis;
        int n  = nt * 16 + (L & 15);
        int kb = kc * 32 + (L >> 4) * 8;
        bf16x8 frag;
        #pragma unroll
        for (int j = 0; j < 8; j++) frag[j] = fbf(Wsrc[(kb + j) * 64 + n]);
        ((bf16x8*)WB)[gi] = frag;
    }
}

// ---------------------------------------------------------------------------
// Kernel 2: stats + cast, 4 bt per 256-thread block (wave w = bt-sub).
// ---------------------------------------------------------------------------
__launch_bounds__(256)
__global__ void pre_pass(const float* __restrict__ x,
                         bf16* __restrict__ xb, bf16* __restrict__ db) {
    __shared__ float xt[4 * NO];
    const int tid = threadIdx.x;
    const int w = tid >> 6, L = tid & 63;
    const size_t base = (size_t)blockIdx.x * 4 * NO;
    for (int idx = tid; idx < NO; idx += 256)       // 4*NO/4 float4
        ((float4*)xt)[idx] = ((const float4*)(x + base))[idx];
    __syncthreads();
    const float* xw = xt + w * NO;
    float s = 0.f, s2 = 0.f;
    #pragma unroll
    for (int i = 0; i < N_; i++) { float v = xw[i * 64 + L]; s += v; s2 += v * v; }
    const size_t wb = base + (size_t)w * NO;
    #pragma unroll
    for (int i = 0; i < N_; i++) {
        float v  = xw[i * 64 + L];
        float d2 = s2 - 2.f * v * s + (float)N_ * v * v;
        float d  = sqrtf(fmaxf(d2, 0.f)) + 1e-8f;
        xb[wb + i * 64 + L] = f2bf(v);
        db[wb + i * 64 + L] = f2bf(d);
    }
}

// ---------------------------------------------------------------------------
// Kernel 3: h GEMM v3 — LDS-free. grid (550, 2).
// y=0: xb @ {sym0,sym1,con0,con1} -> P01 {h1s|ds<<16}, P23 {h1c|dc<<16}
// y=1: db @ dis -> P4 (bf16)
// A-frags: direct global uint4 (verified); B-frags: WB global (CB pattern).
// ---------------------------------------------------------------------------
__launch_bounds__(256)
__global__ void h_gemm(const bf16* __restrict__ xb, const bf16* __restrict__ db,
                       const short* __restrict__ WB,
                       unsigned* __restrict__ P01, unsigned* __restrict__ P23,
                       short* __restrict__ P4) {
    const int tid = threadIdx.x;
    const int w = tid >> 6, L = tid & 63;
    const int lane16 = L & 15, quad = L >> 4;
    const int R0 = blockIdx.x * 128 + w * 32;
    const bf16x8* WBf = (const bf16x8*)WB;

    if (blockIdx.y == 0) {
        f32x4 acc[4][2][4];   // [p][rt][nt]
        #pragma unroll
        for (int p = 0; p < 4; p++)
            #pragma unroll
            for (int rt = 0; rt < 2; rt++)
                #pragma unroll
                for (int nt = 0; nt < 4; nt++) acc[p][rt][nt] = (f32x4){0.f, 0.f, 0.f, 0.f};

        #pragma unroll
        for (int kc = 0; kc < 2; kc++) {
            bf16x8 av[2];
            #pragma unroll
            for (int rt = 0; rt < 2; rt++) {
                int row = R0 + rt * 16 + lane16;
                av[rt] = *(const bf16x8*)(xb + (size_t)row * 64 + kc * 32 + quad * 8);
            }
            #pragma unroll
            for (int p = 0; p < 4; p++)
                #pragma unroll
                for (int nt = 0; nt < 4; nt++) {
                    bf16x8 bw = WBf[((p * 2 + kc) * 4 + nt) * 64 + L];
                    acc[p][0][nt] = __builtin_amdgcn_mfma_f32_16x16x32_bf16(av[0], bw, acc[p][0][nt], 0, 0, 0);
                    acc[p][1][nt] = __builtin_amdgcn_mfma_f32_16x16x32_bf16(av[1], bw, acc[p][1][nt], 0, 0, 0);
                }
        }

        #pragma unroll
        for (int rt = 0; rt < 2; rt++)
            #pragma unroll
            for (int nt = 0; nt < 4; nt++)
                #pragma unroll
                for (int r = 0; r < 4; r++) {
                    size_t idx = (size_t)(R0 + rt * 16 + quad * 4 + r) * 64 + nt * 16 + lane16;
                    float h0s = acc[0][rt][nt][r], h1s = acc[1][rt][nt][r];
                    float h0c = acc[2][rt][nt][r], h1c = acc[3][rt][nt][r];
                    P01[idx] = (unsigned)(unsigned short)fbf(h1s) |
                               ((unsigned)(unsigned short)fbf(h0s - h1s) << 16);
                    P23[idx] = (unsigned)(unsigned short)fbf(h1c) |
                               ((unsigned)(unsigned short)fbf(h0c - h1c) << 16);
                }
    } else {
        f32x4 acc[2][4];
        #pragma unroll
        for (int rt = 0; rt < 2; rt++)
            #pragma unroll
            for (int nt = 0; nt < 4; nt++) acc[rt][nt] = (f32x4){0.f, 0.f, 0.f, 0.f};

        #pragma unroll
        for (int kc = 0; kc < 2; kc++) {
            bf16x8 av[2];
            #pragma unroll
            for (int rt = 0; rt < 2; rt++) {
                int row = R0 + rt * 16 + lane16;
                av[rt] = *(const bf16x8*)(db + (size_t)row * 64 + kc * 32 + quad * 8);
            }
            #pragma unroll
            for (int nt = 0; nt < 4; nt++) {
                bf16x8 bw = WBf[((4 * 2 + kc) * 4 + nt) * 64 + L];
                acc[0][nt] = __builtin_amdgcn_mfma_f32_16x16x32_bf16(av[0], bw, acc[0][nt], 0, 0, 0);
                acc[1][nt] = __builtin_amdgcn_mfma_f32_16x16x32_bf16(av[1], bw, acc[1][nt], 0, 0, 0);
            }
        }
        #pragma unroll
        for (int rt = 0; rt < 2; rt++)
            #pragma unroll
            for (int nt = 0; nt < 4; nt++)
                #pragma unroll
                for (int r = 0; r < 4; r++) {
                    size_t idx = (size_t)(R0 + rt * 16 + quad * 4 + r) * 64 + nt * 16 + lane16;
                    P4[idx] = fbf(acc[rt][nt][r]);
                }
    }
}

// ---------------------------------------------------------------------------
// Kernel 4: mixer v4 — 2 bt per block (1600 blocks). Each AA load feeds both
// bts' FMAs; AA L2 traffic halves. Math identical to verified R8/R9.
// ---------------------------------------------------------------------------
__launch_bounds__(256)
__global__ void mixer(const unsigned* __restrict__ P01, const unsigned* __restrict__ P23,
                      const short* __restrict__ P4, const short* __restrict__ AAb,
                      const float* __restrict__ att, const float* __restrict__ bdis,
                      bf16* __restrict__ xs, bf16* __restrict__ yc,
                      bf16* __restrict__ z, float* __restrict__ stats1) {
    __shared__ __align__(16) unsigned pp0[2 * NO];  // P01, both bts; reused as red
    __shared__ __align__(16) unsigned pp1[2 * NO];  // P23
    __shared__ __align__(16) short p2[2 * NO];      // P4
    __shared__ float attL[NN];
    float* red = (float*)pp0;

    const int g   = blockIdx.x;
    const int tid = threadIdx.x;
    const size_t base = (size_t)g * 2 * NO;
    const int w = tid >> 6, L = tid & 63;

    for (int idx = tid; idx < 1760; idx += 256) {
        if (idx < 704)       ((uint4*)pp0)[idx]        = ((const uint4*)(P01 + base))[idx];
        else if (idx < 1408) ((uint4*)pp1)[idx - 704]  = ((const uint4*)(P23 + base))[idx - 704];
        else                 ((uint4*)p2)[idx - 1408]  = ((const uint4*)(P4 + base))[idx - 1408];
    }
    for (int idx = tid; idx < NN; idx += 256) attL[idx] = att[idx];
    __syncthreads();

    float mxs[2][6], myc[2][6], mz[2][6];
    #pragma unroll
    for (int b = 0; b < 2; b++)
        #pragma unroll
        for (int k = 0; k < 6; k++) { mxs[b][k] = myc[b][k] = mz[b][k] = 0.f; }

    const unsigned* AAu = (const unsigned*)AAb;
    for (int j = 0; j < N_; j++) {
        float h1s[2], h1c[2], hw[2], dum;
        #pragma unroll
        for (int b = 0; b < 2; b++) {
            unp(pp0[b * NO + j * 64 + L], h1s[b], dum);
            unp(pp1[b * NO + j * 64 + L], h1c[b], dum);
            hw[b] = sbf(p2[b * NO + j * 64 + L]);
        }
        #pragma unroll
        for (int k = 0; k < 6; k++) {
            int i  = w + 4 * k;
            int ii = (i < N_) ? i : 0;
            unsigned a = AAu[(size_t)(ii * N_ + j) * 64 + L];
            float as, ac; unp(a, as, ac);
            float atv = attL[ii * N_ + j];
            #pragma unroll
            for (int b = 0; b < 2; b++) {
                mxs[b][k] = fmaf(as,  h1s[b], mxs[b][k]);
                myc[b][k] = fmaf(ac,  h1c[b], myc[b][k]);
                mz[b][k]  = fmaf(atv, hw[b],  mz[b][k]);
            }
        }
    }

    float bd = bdis[L];
    float st0 = 0.f, st1 = 0.f, st2 = 0.f, st3 = 0.f, st4 = 0.f, st5 = 0.f;
    #pragma unroll
    for (int k = 0; k < 6; k++) {
        int i = w + 4 * k;
        if (i < N_) {
            unsigned ad = AAu[(size_t)(i * 23) * 64 + L];
            float asd, acd; unp(ad, asd, acd);
            #pragma unroll
            for (int b = 0; b < 2; b++) {
                float dum, dsv, dcv;
                unp(pp0[b * NO + i * 64 + L], dum, dsv);
                unp(pp1[b * NO + i * 64 + L], dum, dcv);
                float xsv = mxs[b][k] + asd * dsv;
                float ycv = myc[b][k] + acd * dcv;
                float zv  = mz[b][k] + bd;
                size_t oi = base + b * NO + i * 64 + L;
                xs[oi] = f2bf(xsv); yc[oi] = f2bf(ycv); z[oi] = f2bf(zv);
                st0 += xsv; st1 += xsv * xsv;
                st2 += ycv; st3 += ycv * ycv;
                st4 += zv;  st5 += zv  * zv;
            }
        }
    }

    __syncthreads();                // all pp0 reads done; reuse as red
    red[(w * 6 + 0) * 64 + L] = st0;
    red[(w * 6 + 1) * 64 + L] = st1;
    red[(w * 6 + 2) * 64 + L] = st2;
    red[(w * 6 + 3) * 64 + L] = st3;
    red[(w * 6 + 4) * 64 + L] = st4;
    red[(w * 6 + 5) * 64 + L] = st5;
    __syncthreads();
    float* myStats = stats1 + (size_t)(g & 7) * 384;   // 8-way shard
    for (int qq = tid; qq < 384; qq += 256) {
        int q = qq >> 6, oo = qq & 63;
        float v = (red[q * 64 + oo] + red[(6 + q) * 64 + oo]) +
                  (red[(12 + q) * 64 + oo] + red[(18 + q) * 64 + oo]);
        atomicAdd(&myStats[qq], v);
    }
}

// ---------------------------------------------------------------------------
// Kernel 5: BN affine from (sharded) atomic stats (verified R9).
// ---------------------------------------------------------------------------
__global__ void scale_from_stats(const float* __restrict__ stats,
                                 const float* __restrict__ gammas,
                                 const float* __restrict__ betas,
                                 int nch, int gbase, int nshard, int sstride,
                                 float* __restrict__ scale) {
    int tid = threadIdx.x;
    if (tid >= nch * 64) return;
    int t = tid >> 6, o = tid & 63;
    float S = 0.f, SS = 0.f;
    for (int s = 0; s < nshard; s++) {
        S  += stats[s * sstride + (2 * t) * 64 + o];
        SS += stats[s * sstride + (2 * t + 1) * 64 + o];
    }
    const float invn = 1.f / (float)BTN;
    float mu   = S * invn;
    float var  = SS * invn - mu * mu;
    float rstd = rsqrtf(var + 1e-5f);
    float a = gammas[(gbase + t) * 64 + o] * rstd;
    float c = betas[(gbase + t) * 64 + o] - mu * a;
    scale[t * 128 + o]      = a;
    scale[t * 128 + 64 + o] = c;
}

// ---------------------------------------------------------------------------
// Kernel 6: mix GEMM (verified R5-R9, unchanged).
// ---------------------------------------------------------------------------
__launch_bounds__(256)
__global__ void mix_pass(const bf16* __restrict__ xs, const bf16* __restrict__ yc,
                         const bf16* __restrict__ z, const float* __restrict__ scale1,
                         const short* __restrict__ CB,
                         bf16* __restrict__ out2, float* __restrict__ stats2) {
    __shared__ float sL[384];
    __shared__ float red[512];

    const int tid = threadIdx.x;
    const int w = tid >> 6, L = tid & 63;
    const int lane16 = L & 15, quad = L >> 4;
    const int R0 = blockIdx.x * 128 + w * 32;

    for (int idx = tid; idx < 384; idx += 256) sL[idx] = scale1[idx];
    __syncthreads();

    const bf16* srcs[3] = { xs, yc, z };

    f32x4 acc[2][4];
    #pragma unroll
    for (int rt = 0; rt < 2; rt++)
        #pragma unroll
        for (int nt = 0; nt < 4; nt++)
            acc[rt][nt] = (f32x4){0.f, 0.f, 0.f, 0.f};

    #pragma unroll
    for (int kc = 0; kc < 6; kc++) {
        const int src = kc >> 1;
        const int c0  = (kc & 1) * 32 + quad * 8;
        bf16x8 av[2];
        #pragma unroll
        for (int rt = 0; rt < 2; rt++) {
            int row = R0 + rt * 16 + lane16;
            uint4 u = *(const uint4*)(srcs[src] + (size_t)row * 64 + c0);
            float v[8];
            unp(u.x, v[0], v[1]); unp(u.y, v[2], v[3]);
            unp(u.z, v[4], v[5]); unp(u.w, v[6], v[7]);
            #pragma unroll
            for (int e = 0; e < 8; e++) {
                float t = fmaxf(fmaf(v[e], sL[src * 128 + c0 + e],
                                     sL[src * 128 + 64 + c0 + e]), 0.f);
                av[rt][e] = fbf(t);
            }
        }
        #pragma unroll
        for (int nt = 0; nt < 4; nt++) {
            bf16x8 bw = ((const bf16x8*)CB)[(nt * 6 + kc) * 64 + L];
            acc[0][nt] = __builtin_amdgcn_mfma_f32_16x16x32_bf16(av[0], bw, acc[0][nt], 0, 0, 0);
            acc[1][nt] = __builtin_amdgcn_mfma_f32_16x16x32_bf16(av[1], bw, acc[1][nt], 0, 0, 0);
        }
    }

    float s[4]  = {0.f, 0.f, 0.f, 0.f};
    float s2[4] = {0.f, 0.f, 0.f, 0.f};
    #pragma unroll
    for (int rt = 0; rt < 2; rt++)
        #pragma unroll
        for (int nt = 0; nt < 4; nt++)
            #pragma unroll
            for (int r = 0; r < 4; r++) {
                int row = R0 + rt * 16 + quad * 4 + r;
                int col = nt * 16 + lane16;
                float v = acc[rt][nt][r];
                out2[(size_t)row * 64 + col] = f2bf(v);
                s[nt] += v; s2[nt] += v * v;
            }
    #pragma unroll
    for (int nt = 0; nt < 4; nt++) {
        s[nt]  += __shfl_xor(s[nt], 16);
        s[nt]  += __shfl_xor(s[nt], 32);
        s2[nt] += __shfl_xor(s2[nt], 16);
        s2[nt] += __shfl_xor(s2[nt], 32);
    }
    if (quad == 0) {
        #pragma unroll
        for (int nt = 0; nt < 4; nt++) {
            red[w * 64 + nt * 16 + lane16]       = s[nt];
            red[256 + w * 64 + nt * 16 + lane16] = s2[nt];
        }
    }
    __syncthreads();
    if (tid < 64) {
        float t = red[tid] + red[64 + tid] + red[128 + tid] + red[192 + tid];
        atomicAdd(&stats2[tid], t);
    } else if (tid < 128) {
        int c = tid - 64;
        float t = red[256 + c] + red[320 + c] + red[384 + c] + red[448 + c];
        atomicAdd(&stats2[64 + c], t);
    }
}

// ---------------------------------------------------------------------------
// Kernel 7: final BN + ReLU + f32 store (verified, unchanged).
// ---------------------------------------------------------------------------
__global__ void final_pass(const bf16* __restrict__ out2, const float* __restrict__ scale2,
                           float* __restrict__ out) {
    const int gid = blockIdx.x * 256 + threadIdx.x;
    const int idx = gid * 4;
    ushort4 u = reinterpret_cast<const ushort4*>(out2)[gid];
    const int o = idx & 63;
    float f0, f1, f2, f3;
    unp((unsigned)u.x | ((unsigned)u.y << 16), f0, f1);
    unp((unsigned)u.z | ((unsigned)u.w << 16), f2, f3);
    float4 r;
    r.x = fmaxf(fmaf(f0, scale2[o],     scale2[64 + o]),     0.f);
    r.y = fmaxf(fmaf(f1, scale2[o + 1], scale2[64 + o + 1]), 0.f);
    r.z = fmaxf(fmaf(f2, scale2[o + 2], scale2[64 + o + 2]), 0.f);
    r.w = fmaxf(fmaf(f3, scale2[o + 3], scale2[64 + o + 3]), 0.f);
    reinterpret_cast<float4*>(out)[gid] = r;
}

// ---------------------------------------------------------------------------
extern "C" void kernel_launch(void* const* d_in, const int* in_sizes, int n_in,
                              void* d_out, int out_size, void* d_ws, size_t ws_size,
                              hipStream_t stream) {
    const float* x      = (const float*)d_in[0];
    const float* W_sym  = (const float*)d_in[1];
    const float* e_sym  = (const float*)d_in[2];
    const float* W_con  = (const float*)d_in[3];
    const float* e_con  = (const float*)d_in[4];
    const float* W_dis  = (const float*)d_in[5];
    const float* att    = (const float*)d_in[6];
    const float* b_dis  = (const float*)d_in[7];
    const float* cat_w  = (const float*)d_in[8];
    const float* gammas = (const float*)d_in[9];
    const float* betas  = (const float*)d_in[10];
    const int* rows_sym = (const int*)d_in[11];
    const int* cols_sym = (const int*)d_in[12];
    const int* rows_con = (const int*)d_in[13];
    const int* cols_con = (const int*)d_in[14];
    const int nnz_s = in_sizes[2] / 64;
    const int nnz_c = in_sizes[4] / 64;

    // Workspace carve. out2 aliases xb (dead after h_gemm; out2 written later).
    char* p = (char*)d_ws;
    float* stats  = (float*)p; p += (8 * 384 + 128) * 4;       // stats1 shards + stats2
    float* scale1 = (float*)p; p += 384 * 4;
    float* scale2 = (float*)p; p += 128 * 4;
    short* AAb    = (short*)p; p += (size_t)NN * 64 * 2 * 2;
    short* CB     = (short*)p; p += (size_t)1536 * 8 * 2;
    short* WB     = (short*)p; p += (size_t)2560 * 8 * 2;
    bf16*  xb     = (bf16*)p;  p += (size_t)ELEMS * 2;
    bf16*  db     = (bf16*)p;  p += (size_t)ELEMS * 2;
    bf16*  xsb    = (bf16*)p;  p += (size_t)ELEMS * 2;
    bf16*  ycb    = (bf16*)p;  p += (size_t)ELEMS * 2;
    bf16*  zb     = (bf16*)p;  p += (size_t)ELEMS * 2;
    unsigned* P01 = (unsigned*)p; p += (size_t)ELEMS * 4;      // {h1s|ds}
    unsigned* P23 = (unsigned*)p; p += (size_t)ELEMS * 4;      // {h1c|dc}
    short*    P4  = (short*)p;    p += (size_t)ELEMS * 2;      // hdw
    bf16*  out2   = xb;
    float* stats1 = stats;
    float* stats2 = stats + 8 * 384;

    hipMemsetAsync(stats, 0, (8 * 384 + 128) * 4, stream);
    prep_kernel<<<27, 256, 0, stream>>>(e_sym, rows_sym, cols_sym, nnz_s,
                                        e_con, rows_con, cols_con, nnz_c,
                                        cat_w, W_sym, W_con, W_dis, AAb, CB, WB);
    pre_pass<<<800, 256, 0, stream>>>(x, xb, db);
    h_gemm<<<dim3(550, 2), 256, 0, stream>>>(xb, db, WB, P01, P23, P4);
    mixer<<<1600, 256, 0, stream>>>(P01, P23, P4, AAb, att, b_dis, xsb, ycb, zb, stats1);
    scale_from_stats<<<1, 192, 0, stream>>>(stats1, gammas, betas, 3, 0, 8, 384, scale1);
    mix_pass<<<550, 256, 0, stream>>>(xsb, ycb, zb, scale1, CB, out2, stats2);
    scale_from_stats<<<1, 64, 0, stream>>>(stats2, gammas, betas, 1, 3, 1, 0, scale2);
    final_pass<<<ELEMS / 1024, 256, 0, stream>>>(out2, scale2, (float*)d_out);
}

// Round 11
// 239.775 us; speedup vs baseline: 4.1572x; 1.0199x over previous
//
#include <hip/hip_runtime.h>
#include <hip/hip_bf16.h>

typedef __hip_bfloat16 bf16;
typedef __attribute__((ext_vector_type(8))) short bf16x8;
typedef __attribute__((ext_vector_type(4))) float f32x4;

#define BT    3200
#define N_    22
#define NO    1408           // N_*64
#define NN    484
#define BTN   70400
#define ELEMS 4505600        // BT*N_*64

static __device__ __forceinline__ bf16  f2bf(float v) { return __float2bfloat16(v); }
static __device__ __forceinline__ short fbf(float v) {
    bf16 h = __float2bfloat16(v);
    return *reinterpret_cast<short*>(&h);
}
static __device__ __forceinline__ float sbf(short s) {
    return __uint_as_float(((unsigned)(unsigned short)s) << 16);
}
static __device__ __forceinline__ void unp(unsigned u, float& lo, float& hi) {
    lo = __uint_as_float(u << 16);
    hi = __uint_as_float(u & 0xffff0000u);
}

// ---------------------------------------------------------------------------
// Kernel 1 (prep): blocks 0-10 AAb softmax pairs — v2: NO local row[] array
// (R10's dynamically-indexed row[22] spilled to scratch -> 58 us at 0.3%
// occupancy). Two register-only passes over the nnz list; zeros come from
// the hipMemsetAsync background. blocks 11-16 CB (verified R5-R10);
// blocks 17-26 WB (verified R10).
// ---------------------------------------------------------------------------
__global__ void prep_kernel(const float* __restrict__ e_s, const int* __restrict__ rs,
                            const int* __restrict__ cs, int nnz_s,
                            const float* __restrict__ e_c, const int* __restrict__ rc,
                            const int* __restrict__ cc, int nnz_c,
                            const float* __restrict__ cat_w,
                            const float* __restrict__ Wsym, const float* __restrict__ Wcon,
                            const float* __restrict__ Wdis,
                            short* __restrict__ AAb, short* __restrict__ CB,
                            short* __restrict__ WB) {
    const int tid = threadIdx.x;
    if (blockIdx.x < 11) {
        int id = blockIdx.x * 256 + tid;           // 0..2815
        if (id >= 2 * 64 * N_) return;
        int t   = id / (64 * N_);
        int rem = id % (64 * N_);
        int o   = rem / N_;
        int i   = rem % N_;
        const float* e    = t ? e_c : e_s;
        const int*   rows = t ? rc  : rs;
        const int*   cols = t ? cc  : cs;
        int          nnz  = t ? nnz_c : nnz_s;
        float s = 0.f;
        for (int k = 0; k < nnz; k++)
            if (rows[k] == i) s += expf(e[o * nnz + k]);
        float inv = 1.f / s;
        for (int k = 0; k < nnz; k++)
            if (rows[k] == i)
                AAb[((size_t)(i * N_ + cols[k]) * 64 + o) * 2 + t] =
                    fbf(expf(e[o * nnz + k]) * inv);
    } else if (blockIdx.x < 17) {
        int gi = (blockIdx.x - 11) * 256 + tid;    // 0..1535
        if (gi >= 1536) return;
        int nt = gi / 384, rem = gi % 384;
        int kc = rem >> 6, L = rem & 63;
        int n = nt * 16 + (L & 15);
        int kbase = kc * 32 + (L >> 4) * 8;
        float4 w0 = *(const float4*)&cat_w[n * 192 + kbase];
        float4 w1 = *(const float4*)&cat_w[n * 192 + kbase + 4];
        bf16x8 frag;
        frag[0] = fbf(w0.x); frag[1] = fbf(w0.y); frag[2] = fbf(w0.z); frag[3] = fbf(w0.w);
        frag[4] = fbf(w1.x); frag[5] = fbf(w1.y); frag[6] = fbf(w1.z); frag[7] = fbf(w1.w);
        ((bf16x8*)CB)[gi] = frag;
    } else {
        int gi = (blockIdx.x - 17) * 256 + tid;    // 0..2559
        if (gi >= 2560) return;
        int L = gi & 63;
        int q = gi >> 6;          // 0..39
        int nt = q & 3;
        int pk = q >> 2;          // 0..9
        int kc = pk & 1;
        int p  = pk >> 1;         // 0..4
        const float* Wsrc = (p == 0) ? Wsym :
                            (p == 1) ? Wsym + 4096 :
                            (p == 2) ? Wcon :
                            (p == 3) ? Wcon + 4096 : Wdis;
        int n  = nt * 16 + (L & 15);
        int kb = kc * 32 + (L >> 4) * 8;
        bf16x8 frag;
        #pragma unroll
        for (int j = 0; j < 8; j++) frag[j] = fbf(Wsrc[(kb + j) * 64 + n]);
        ((bf16x8*)WB)[gi] = frag;
    }
}

// ---------------------------------------------------------------------------
// Kernel 2: stats + cast, 4 bt per 256-thread block (verified R10).
// ---------------------------------------------------------------------------
__launch_bounds__(256)
__global__ void pre_pass(const float* __restrict__ x,
                         bf16* __restrict__ xb, bf16* __restrict__ db) {
    __shared__ float xt[4 * NO];
    const int tid = threadIdx.x;
    const int w = tid >> 6, L = tid & 63;
    const size_t base = (size_t)blockIdx.x * 4 * NO;
    for (int idx = tid; idx < NO; idx += 256)       // 4*NO/4 float4
        ((float4*)xt)[idx] = ((const float4*)(x + base))[idx];
    __syncthreads();
    const float* xw = xt + w * NO;
    float s = 0.f, s2 = 0.f;
    #pragma unroll
    for (int i = 0; i < N_; i++) { float v = xw[i * 64 + L]; s += v; s2 += v * v; }
    const size_t wb = base + (size_t)w * NO;
    #pragma unroll
    for (int i = 0; i < N_; i++) {
        float v  = xw[i * 64 + L];
        float d2 = s2 - 2.f * v * s + (float)N_ * v * v;
        float d  = sqrtf(fmaxf(d2, 0.f)) + 1e-8f;
        xb[wb + i * 64 + L] = f2bf(v);
        db[wb + i * 64 + L] = f2bf(d);
    }
}

// ---------------------------------------------------------------------------
// Kernel 3: h GEMM v3 — LDS-free (verified R10). grid (550, 2).
// y=0: xb @ {sym0,sym1,con0,con1} -> P01 {h1s|ds<<16}, P23 {h1c|dc<<16}
// y=1: db @ dis -> P4 (bf16)
// ---------------------------------------------------------------------------
__launch_bounds__(256)
__global__ void h_gemm(const bf16* __restrict__ xb, const bf16* __restrict__ db,
                       const short* __restrict__ WB,
                       unsigned* __restrict__ P01, unsigned* __restrict__ P23,
                       short* __restrict__ P4) {
    const int tid = threadIdx.x;
    const int w = tid >> 6, L = tid & 63;
    const int lane16 = L & 15, quad = L >> 4;
    const int R0 = blockIdx.x * 128 + w * 32;
    const bf16x8* WBf = (const bf16x8*)WB;

    if (blockIdx.y == 0) {
        f32x4 acc[4][2][4];   // [p][rt][nt]
        #pragma unroll
        for (int p = 0; p < 4; p++)
            #pragma unroll
            for (int rt = 0; rt < 2; rt++)
                #pragma unroll
                for (int nt = 0; nt < 4; nt++) acc[p][rt][nt] = (f32x4){0.f, 0.f, 0.f, 0.f};

        #pragma unroll
        for (int kc = 0; kc < 2; kc++) {
            bf16x8 av[2];
            #pragma unroll
            for (int rt = 0; rt < 2; rt++) {
                int row = R0 + rt * 16 + lane16;
                av[rt] = *(const bf16x8*)(xb + (size_t)row * 64 + kc * 32 + quad * 8);
            }
            #pragma unroll
            for (int p = 0; p < 4; p++)
                #pragma unroll
                for (int nt = 0; nt < 4; nt++) {
                    bf16x8 bw = WBf[((p * 2 + kc) * 4 + nt) * 64 + L];
                    acc[p][0][nt] = __builtin_amdgcn_mfma_f32_16x16x32_bf16(av[0], bw, acc[p][0][nt], 0, 0, 0);
                    acc[p][1][nt] = __builtin_amdgcn_mfma_f32_16x16x32_bf16(av[1], bw, acc[p][1][nt], 0, 0, 0);
                }
        }

        #pragma unroll
        for (int rt = 0; rt < 2; rt++)
            #pragma unroll
            for (int nt = 0; nt < 4; nt++)
                #pragma unroll
                for (int r = 0; r < 4; r++) {
                    size_t idx = (size_t)(R0 + rt * 16 + quad * 4 + r) * 64 + nt * 16 + lane16;
                    float h0s = acc[0][rt][nt][r], h1s = acc[1][rt][nt][r];
                    float h0c = acc[2][rt][nt][r], h1c = acc[3][rt][nt][r];
                    P01[idx] = (unsigned)(unsigned short)fbf(h1s) |
                               ((unsigned)(unsigned short)fbf(h0s - h1s) << 16);
                    P23[idx] = (unsigned)(unsigned short)fbf(h1c) |
                               ((unsigned)(unsigned short)fbf(h0c - h1c) << 16);
                }
    } else {
        f32x4 acc[2][4];
        #pragma unroll
        for (int rt = 0; rt < 2; rt++)
            #pragma unroll
            for (int nt = 0; nt < 4; nt++) acc[rt][nt] = (f32x4){0.f, 0.f, 0.f, 0.f};

        #pragma unroll
        for (int kc = 0; kc < 2; kc++) {
            bf16x8 av[2];
            #pragma unroll
            for (int rt = 0; rt < 2; rt++) {
                int row = R0 + rt * 16 + lane16;
                av[rt] = *(const bf16x8*)(db + (size_t)row * 64 + kc * 32 + quad * 8);
            }
            #pragma unroll
            for (int nt = 0; nt < 4; nt++) {
                bf16x8 bw = WBf[((4 * 2 + kc) * 4 + nt) * 64 + L];
                acc[0][nt] = __builtin_amdgcn_mfma_f32_16x16x32_bf16(av[0], bw, acc[0][nt], 0, 0, 0);
                acc[1][nt] = __builtin_amdgcn_mfma_f32_16x16x32_bf16(av[1], bw, acc[1][nt], 0, 0, 0);
            }
        }
        #pragma unroll
        for (int rt = 0; rt < 2; rt++)
            #pragma unroll
            for (int nt = 0; nt < 4; nt++)
                #pragma unroll
                for (int r = 0; r < 4; r++) {
                    size_t idx = (size_t)(R0 + rt * 16 + quad * 4 + r) * 64 + nt * 16 + lane16;
                    P4[idx] = fbf(acc[rt][nt][r]);
                }
    }
}

// ---------------------------------------------------------------------------
// Kernel 4: mixer v4 — 2 bt per block (verified R10).
// ---------------------------------------------------------------------------
__launch_bounds__(256)
__global__ void mixer(const unsigned* __restrict__ P01, const unsigned* __restrict__ P23,
                      const short* __restrict__ P4, const short* __restrict__ AAb,
                      const float* __restrict__ att, const float* __restrict__ bdis,
                      bf16* __restrict__ xs, bf16* __restrict__ yc,
                      bf16* __restrict__ z, float* __restrict__ stats1) {
    __shared__ __align__(16) unsigned pp0[2 * NO];  // P01, both bts; reused as red
    __shared__ __align__(16) unsigned pp1[2 * NO];  // P23
    __shared__ __align__(16) short p2[2 * NO];      // P4
    __shared__ float attL[NN];
    float* red = (float*)pp0;

    const int g   = blockIdx.x;
    const int tid = threadIdx.x;
    const size_t base = (size_t)g * 2 * NO;
    const int w = tid >> 6, L = tid & 63;

    for (int idx = tid; idx < 1760; idx += 256) {
        if (idx < 704)       ((uint4*)pp0)[idx]        = ((const uint4*)(P01 + base))[idx];
        else if (idx < 1408) ((uint4*)pp1)[idx - 704]  = ((const uint4*)(P23 + base))[idx - 704];
        else                 ((uint4*)p2)[idx - 1408]  = ((const uint4*)(P4 + base))[idx - 1408];
    }
    for (int idx = tid; idx < NN; idx += 256) attL[idx] = att[idx];
    __syncthreads();

    float mxs[2][6], myc[2][6], mz[2][6];
    #pragma unroll
    for (int b = 0; b < 2; b++)
        #pragma unroll
        for (int k = 0; k < 6; k++) { mxs[b][k] = myc[b][k] = mz[b][k] = 0.f; }

    const unsigned* AAu = (const unsigned*)AAb;
    for (int j = 0; j < N_; j++) {
        float h1s[2], h1c[2], hw[2], dum;
        #pragma unroll
        for (int b = 0; b < 2; b++) {
            unp(pp0[b * NO + j * 64 + L], h1s[b], dum);
            unp(pp1[b * NO + j * 64 + L], h1c[b], dum);
            hw[b] = sbf(p2[b * NO + j * 64 + L]);
        }
        #pragma unroll
        for (int k = 0; k < 6; k++) {
            int i  = w + 4 * k;
            int ii = (i < N_) ? i : 0;
            unsigned a = AAu[(size_t)(ii * N_ + j) * 64 + L];
            float as, ac; unp(a, as, ac);
            float atv = attL[ii * N_ + j];
            #pragma unroll
            for (int b = 0; b < 2; b++) {
                mxs[b][k] = fmaf(as,  h1s[b], mxs[b][k]);
                myc[b][k] = fmaf(ac,  h1c[b], myc[b][k]);
                mz[b][k]  = fmaf(atv, hw[b],  mz[b][k]);
            }
        }
    }

    float bd = bdis[L];
    float st0 = 0.f, st1 = 0.f, st2 = 0.f, st3 = 0.f, st4 = 0.f, st5 = 0.f;
    #pragma unroll
    for (int k = 0; k < 6; k++) {
        int i = w + 4 * k;
        if (i < N_) {
            unsigned ad = AAu[(size_t)(i * 23) * 64 + L];
            float asd, acd; unp(ad, asd, acd);
            #pragma unroll
            for (int b = 0; b < 2; b++) {
                float dum, dsv, dcv;
                unp(pp0[b * NO + i * 64 + L], dum, dsv);
                unp(pp1[b * NO + i * 64 + L], dum, dcv);
                float xsv = mxs[b][k] + asd * dsv;
                float ycv = myc[b][k] + acd * dcv;
                float zv  = mz[b][k] + bd;
                size_t oi = base + b * NO + i * 64 + L;
                xs[oi] = f2bf(xsv); yc[oi] = f2bf(ycv); z[oi] = f2bf(zv);
                st0 += xsv; st1 += xsv * xsv;
                st2 += ycv; st3 += ycv * ycv;
                st4 += zv;  st5 += zv  * zv;
            }
        }
    }

    __syncthreads();                // all pp0 reads done; reuse as red
    red[(w * 6 + 0) * 64 + L] = st0;
    red[(w * 6 + 1) * 64 + L] = st1;
    red[(w * 6 + 2) * 64 + L] = st2;
    red[(w * 6 + 3) * 64 + L] = st3;
    red[(w * 6 + 4) * 64 + L] = st4;
    red[(w * 6 + 5) * 64 + L] = st5;
    __syncthreads();
    float* myStats = stats1 + (size_t)(g & 7) * 384;   // 8-way shard
    for (int qq = tid; qq < 384; qq += 256) {
        int q = qq >> 6, oo = qq & 63;
        float v = (red[q * 64 + oo] + red[(6 + q) * 64 + oo]) +
                  (red[(12 + q) * 64 + oo] + red[(18 + q) * 64 + oo]);
        atomicAdd(&myStats[qq], v);
    }
}

// ---------------------------------------------------------------------------
// Kernel 5: BN affine from (sharded) atomic stats (verified R9/R10).
// ---------------------------------------------------------------------------
__global__ void scale_from_stats(const float* __restrict__ stats,
                                 const float* __restrict__ gammas,
                                 const float* __restrict__ betas,
                                 int nch, int gbase, int nshard, int sstride,
                                 float* __restrict__ scale) {
    int tid = threadIdx.x;
    if (tid >= nch * 64) return;
    int t = tid >> 6, o = tid & 63;
    float S = 0.f, SS = 0.f;
    for (int s = 0; s < nshard; s++) {
        S  += stats[s * sstride + (2 * t) * 64 + o];
        SS += stats[s * sstride + (2 * t + 1) * 64 + o];
    }
    const float invn = 1.f / (float)BTN;
    float mu   = S * invn;
    float var  = SS * invn - mu * mu;
    float rstd = rsqrtf(var + 1e-5f);
    float a = gammas[(gbase + t) * 64 + o] * rstd;
    float c = betas[(gbase + t) * 64 + o] - mu * a;
    scale[t * 128 + o]      = a;
    scale[t * 128 + 64 + o] = c;
}

// ---------------------------------------------------------------------------
// Kernel 6: mix GEMM (verified R5-R10, unchanged).
// ---------------------------------------------------------------------------
__launch_bounds__(256)
__global__ void mix_pass(const bf16* __restrict__ xs, const bf16* __restrict__ yc,
                         const bf16* __restrict__ z, const float* __restrict__ scale1,
                         const short* __restrict__ CB,
                         bf16* __restrict__ out2, float* __restrict__ stats2) {
    __shared__ float sL[384];
    __shared__ float red[512];

    const int tid = threadIdx.x;
    const int w = tid >> 6, L = tid & 63;
    const int lane16 = L & 15, quad = L >> 4;
    const int R0 = blockIdx.x * 128 + w * 32;

    for (int idx = tid; idx < 384; idx += 256) sL[idx] = scale1[idx];
    __syncthreads();

    const bf16* srcs[3] = { xs, yc, z };

    f32x4 acc[2][4];
    #pragma unroll
    for (int rt = 0; rt < 2; rt++)
        #pragma unroll
        for (int nt = 0; nt < 4; nt++)
            acc[rt][nt] = (f32x4){0.f, 0.f, 0.f, 0.f};

    #pragma unroll
    for (int kc = 0; kc < 6; kc++) {
        const int src = kc >> 1;
        const int c0  = (kc & 1) * 32 + quad * 8;
        bf16x8 av[2];
        #pragma unroll
        for (int rt = 0; rt < 2; rt++) {
            int row = R0 + rt * 16 + lane16;
            uint4 u = *(const uint4*)(srcs[src] + (size_t)row * 64 + c0);
            float v[8];
            unp(u.x, v[0], v[1]); unp(u.y, v[2], v[3]);
            unp(u.z, v[4], v[5]); unp(u.w, v[6], v[7]);
            #pragma unroll
            for (int e = 0; e < 8; e++) {
                float t = fmaxf(fmaf(v[e], sL[src * 128 + c0 + e],
                                     sL[src * 128 + 64 + c0 + e]), 0.f);
                av[rt][e] = fbf(t);
            }
        }
        #pragma unroll
        for (int nt = 0; nt < 4; nt++) {
            bf16x8 bw = ((const bf16x8*)CB)[(nt * 6 + kc) * 64 + L];
            acc[0][nt] = __builtin_amdgcn_mfma_f32_16x16x32_bf16(av[0], bw, acc[0][nt], 0, 0, 0);
            acc[1][nt] = __builtin_amdgcn_mfma_f32_16x16x32_bf16(av[1], bw, acc[1][nt], 0, 0, 0);
        }
    }

    float s[4]  = {0.f, 0.f, 0.f, 0.f};
    float s2[4] = {0.f, 0.f, 0.f, 0.f};
    #pragma unroll
    for (int rt = 0; rt < 2; rt++)
        #pragma unroll
        for (int nt = 0; nt < 4; nt++)
            #pragma unroll
            for (int r = 0; r < 4; r++) {
                int row = R0 + rt * 16 + quad * 4 + r;
                int col = nt * 16 + lane16;
                float v = acc[rt][nt][r];
                out2[(size_t)row * 64 + col] = f2bf(v);
                s[nt] += v; s2[nt] += v * v;
            }
    #pragma unroll
    for (int nt = 0; nt < 4; nt++) {
        s[nt]  += __shfl_xor(s[nt], 16);
        s[nt]  += __shfl_xor(s[nt], 32);
        s2[nt] += __shfl_xor(s2[nt], 16);
        s2[nt] += __shfl_xor(s2[nt], 32);
    }
    if (quad == 0) {
        #pragma unroll
        for (int nt = 0; nt < 4; nt++) {
            red[w * 64 + nt * 16 + lane16]       = s[nt];
            red[256 + w * 64 + nt * 16 + lane16] = s2[nt];
        }
    }
    __syncthreads();
    if (tid < 64) {
        float t = red[tid] + red[64 + tid] + red[128 + tid] + red[192 + tid];
        atomicAdd(&stats2[tid], t);
    } else if (tid < 128) {
        int c = tid - 64;
        float t = red[256 + c] + red[320 + c] + red[384 + c] + red[448 + c];
        atomicAdd(&stats2[64 + c], t);
    }
}

// ---------------------------------------------------------------------------
// Kernel 7: final BN + ReLU + f32 store (verified, unchanged).
// ---------------------------------------------------------------------------
__global__ void final_pass(const bf16* __restrict__ out2, const float* __restrict__ scale2,
                           float* __restrict__ out) {
    const int gid = blockIdx.x * 256 + threadIdx.x;
    const int idx = gid * 4;
    ushort4 u = reinterpret_cast<const ushort4*>(out2)[gid];
    const int o = idx & 63;
    float f0, f1, f2, f3;
    unp((unsigned)u.x | ((unsigned)u.y << 16), f0, f1);
    unp((unsigned)u.z | ((unsigned)u.w << 16), f2, f3);
    float4 r;
    r.x = fmaxf(fmaf(f0, scale2[o],     scale2[64 + o]),     0.f);
    r.y = fmaxf(fmaf(f1, scale2[o + 1], scale2[64 + o + 1]), 0.f);
    r.z = fmaxf(fmaf(f2, scale2[o + 2], scale2[64 + o + 2]), 0.f);
    r.w = fmaxf(fmaf(f3, scale2[o + 3], scale2[64 + o + 3]), 0.f);
    reinterpret_cast<float4*>(out)[gid] = r;
}

// ---------------------------------------------------------------------------
extern "C" void kernel_launch(void* const* d_in, const int* in_sizes, int n_in,
                              void* d_out, int out_size, void* d_ws, size_t ws_size,
                              hipStream_t stream) {
    const float* x      = (const float*)d_in[0];
    const float* W_sym  = (const float*)d_in[1];
    const float* e_sym  = (const float*)d_in[2];
    const float* W_con  = (const float*)d_in[3];
    const float* e_con  = (const float*)d_in[4];
    const float* W_dis  = (const float*)d_in[5];
    const float* att    = (const float*)d_in[6];
    const float* b_dis  = (const float*)d_in[7];
    const float* cat_w  = (const float*)d_in[8];
    const float* gammas = (const float*)d_in[9];
    const float* betas  = (const float*)d_in[10];
    const int* rows_sym = (const int*)d_in[11];
    const int* cols_sym = (const int*)d_in[12];
    const int* rows_con = (const int*)d_in[13];
    const int* cols_con = (const int*)d_in[14];
    const int nnz_s = in_sizes[2] / 64;
    const int nnz_c = in_sizes[4] / 64;

    // Workspace carve. out2 aliases xb (dead after h_gemm; out2 written later).
    char* p = (char*)d_ws;
    float* stats  = (float*)p; p += (8 * 384 + 128) * 4;       // stats1 shards + stats2
    float* scale1 = (float*)p; p += 384 * 4;
    float* scale2 = (float*)p; p += 128 * 4;
    short* AAb    = (short*)p; p += (size_t)NN * 64 * 2 * 2;
    short* CB     = (short*)p; p += (size_t)1536 * 8 * 2;
    short* WB     = (short*)p; p += (size_t)2560 * 8 * 2;
    bf16*  xb     = (bf16*)p;  p += (size_t)ELEMS * 2;
    bf16*  db     = (bf16*)p;  p += (size_t)ELEMS * 2;
    bf16*  xsb    = (bf16*)p;  p += (size_t)ELEMS * 2;
    bf16*  ycb    = (bf16*)p;  p += (size_t)ELEMS * 2;
    bf16*  zb     = (bf16*)p;  p += (size_t)ELEMS * 2;
    unsigned* P01 = (unsigned*)p; p += (size_t)ELEMS * 4;      // {h1s|ds}
    unsigned* P23 = (unsigned*)p; p += (size_t)ELEMS * 4;      // {h1c|dc}
    short*    P4  = (short*)p;    p += (size_t)ELEMS * 2;      // hdw
    bf16*  out2   = xb;
    float* stats1 = stats;
    float* stats2 = stats + 8 * 384;

    hipMemsetAsync(stats, 0, (8 * 384 + 128) * 4, stream);
    hipMemsetAsync(AAb, 0, (size_t)NN * 64 * 2 * 2, stream);   // zero background for sparse AA
    prep_kernel<<<27, 256, 0, stream>>>(e_sym, rows_sym, cols_sym, nnz_s,
                                        e_con, rows_con, cols_con, nnz_c,
                                        cat_w, W_sym, W_con, W_dis, AAb, CB, WB);
    pre_pass<<<800, 256, 0, stream>>>(x, xb, db);
    h_gemm<<<dim3(550, 2), 256, 0, stream>>>(xb, db, WB, P01, P23, P4);
    mixer<<<1600, 256, 0, stream>>>(P01, P23, P4, AAb, att, b_dis, xsb, ycb, zb, stats1);
    scale_from_stats<<<1, 192, 0, stream>>>(stats1, gammas, betas, 3, 0, 8, 384, scale1);
    mix_pass<<<550, 256, 0, stream>>>(xsb, ycb, zb, scale1, CB, out2, stats2);
    scale_from_stats<<<1, 64, 0, stream>>>(stats2, gammas, betas, 1, 3, 1, 0, scale2);
    final_pass<<<ELEMS / 1024, 256, 0, stream>>>(out2, scale2, (float*)d_out);
}

// Round 12
// 216.959 us; speedup vs baseline: 4.5944x; 1.1052x over previous
//
#include <hip/hip_runtime.h>
#include <hip/hip_bf16.h>

typedef __hip_bfloat16 bf16;
typedef __attribute__((ext_vector_type(8))) short bf16x8;
typedef __attribute__((ext_vector_type(4))) float f32x4;

#define BT    3200
#define N_    22
#define NO    1408           // N_*64
#define NN    484
#define BTN   70400
#define ELEMS 4505600        // BT*N_*64
#define MAXNZ 128

static __device__ __forceinline__ bf16  f2bf(float v) { return __float2bfloat16(v); }
static __device__ __forceinline__ short fbf(float v) {
    bf16 h = __float2bfloat16(v);
    return *reinterpret_cast<short*>(&h);
}
static __device__ __forceinline__ float sbf(short s) {
    return __uint_as_float(((unsigned)(unsigned short)s) << 16);
}
static __device__ __forceinline__ void unp(unsigned u, float& lo, float& hi) {
    lo = __uint_as_float(u << 16);
    hi = __uint_as_float(u & 0xffff0000u);
}

// ---------------------------------------------------------------------------
// Kernel 1 (prep) v3: blocks 0-1 AA via LDS-staged exp(e) (R11's version made
// 2x nnz uncoalesced global gathers per thread at 0.3% occupancy -> 48 us
// latency-bound; now the loops run entirely from LDS). blocks 2-7 CB
// (verified R5-R11); blocks 8-17 WB (verified R10/R11).
// ---------------------------------------------------------------------------
__global__ void prep_kernel(const float* __restrict__ e_s, const int* __restrict__ rs,
                            const int* __restrict__ cs, int nnz_s,
                            const float* __restrict__ e_c, const int* __restrict__ rc,
                            const int* __restrict__ cc, int nnz_c,
                            const float* __restrict__ cat_w,
                            const float* __restrict__ Wsym, const float* __restrict__ Wcon,
                            const float* __restrict__ Wdis,
                            short* __restrict__ AAb, short* __restrict__ CB,
                            short* __restrict__ WB) {
    const int tid = threadIdx.x;
    if (blockIdx.x < 2) {
        __shared__ float eL[64 * (MAXNZ + 1)];   // stride nnz+1 (odd) -> conflict-free
        __shared__ int rowsL[MAXNZ], colsL[MAXNZ];
        const int t = blockIdx.x;
        const float* e    = t ? e_c : e_s;
        const int*   rows = t ? rc  : rs;
        const int*   cols = t ? cc  : cs;
        const int    nnz  = t ? nnz_c : nnz_s;
        const int    str  = nnz + 1;

        for (int idx = tid; idx < 64 * nnz; idx += 256) {
            int o = idx / nnz, k = idx - o * nnz;      // coalesced global read
            eL[o * str + k] = expf(e[idx]);
        }
        for (int idx = tid; idx < nnz; idx += 256) { rowsL[idx] = rows[idx]; colsL[idx] = cols[idx]; }
        __syncthreads();

        const int o = tid & 63, ig = tid >> 6;         // thread owns rows i = ig+4q
        float s[6];
        #pragma unroll
        for (int q = 0; q < 6; q++) s[q] = 0.f;
        for (int k = 0; k < nnz; k++) {
            int r = rowsL[k];
            float ev = eL[o * str + k];
            #pragma unroll
            for (int q = 0; q < 6; q++)
                if (r == ig + 4 * q) s[q] += ev;
        }
        float inv[6];
        #pragma unroll
        for (int q = 0; q < 6; q++) inv[q] = 1.f / s[q];   // rows >= 22 unused (inf ok)
        for (int k = 0; k < nnz; k++) {
            int r = rowsL[k];
            #pragma unroll
            for (int q = 0; q < 6; q++)
                if (r == ig + 4 * q)
                    AAb[((size_t)(r * N_ + colsL[k]) * 64 + o) * 2 + t] =
                        fbf(eL[o * str + k] * inv[q]);
        }
    } else if (blockIdx.x < 8) {
        int gi = (blockIdx.x - 2) * 256 + tid;     // 0..1535
        if (gi >= 1536) return;
        int nt = gi / 384, rem = gi % 384;
        int kc = rem >> 6, L = rem & 63;
        int n = nt * 16 + (L & 15);
        int kbase = kc * 32 + (L >> 4) * 8;
        float4 w0 = *(const float4*)&cat_w[n * 192 + kbase];
        float4 w1 = *(const float4*)&cat_w[n * 192 + kbase + 4];
        bf16x8 frag;
        frag[0] = fbf(w0.x); frag[1] = fbf(w0.y); frag[2] = fbf(w0.z); frag[3] = fbf(w0.w);
        frag[4] = fbf(w1.x); frag[5] = fbf(w1.y); frag[6] = fbf(w1.z); frag[7] = fbf(w1.w);
        ((bf16x8*)CB)[gi] = frag;
    } else {
        int gi = (blockIdx.x - 8) * 256 + tid;     // 0..2559
        if (gi >= 2560) return;
        int L = gi & 63;
        int q = gi >> 6;          // 0..39
        int nt = q & 3;
        int pk = q >> 2;          // 0..9
        int kc = pk & 1;
        int p  = pk >> 1;         // 0..4
        const float* Wsrc = (p == 0) ? Wsym :
                            (p == 1) ? Wsym + 4096 :
                            (p == 2) ? Wcon :
                            (p == 3) ? Wcon + 4096 : Wdis;
        int n  = nt * 16 + (L & 15);
        int kb = kc * 32 + (L >> 4) * 8;
        bf16x8 frag;
        #pragma unroll
        for (int j = 0; j < 8; j++) frag[j] = fbf(Wsrc[(kb + j) * 64 + n]);
        ((bf16x8*)WB)[gi] = frag;
    }
}

// ---------------------------------------------------------------------------
// Kernel 2: stats + cast, 4 bt per 256-thread block (verified R10/R11).
// ---------------------------------------------------------------------------
__launch_bounds__(256)
__global__ void pre_pass(const float* __restrict__ x,
                         bf16* __restrict__ xb, bf16* __restrict__ db) {
    __shared__ float xt[4 * NO];
    const int tid = threadIdx.x;
    const int w = tid >> 6, L = tid & 63;
    const size_t base = (size_t)blockIdx.x * 4 * NO;
    for (int idx = tid; idx < NO; idx += 256)       // 4*NO/4 float4
        ((float4*)xt)[idx] = ((const float4*)(x + base))[idx];
    __syncthreads();
    const float* xw = xt + w * NO;
    float s = 0.f, s2 = 0.f;
    #pragma unroll
    for (int i = 0; i < N_; i++) { float v = xw[i * 64 + L]; s += v; s2 += v * v; }
    const size_t wb = base + (size_t)w * NO;
    #pragma unroll
    for (int i = 0; i < N_; i++) {
        float v  = xw[i * 64 + L];
        float d2 = s2 - 2.f * v * s + (float)N_ * v * v;
        float d  = sqrtf(fmaxf(d2, 0.f)) + 1e-8f;
        xb[wb + i * 64 + L] = f2bf(v);
        db[wb + i * 64 + L] = f2bf(d);
    }
}

// ---------------------------------------------------------------------------
// Kernel 3: h GEMM v3 — LDS-free (verified R10/R11). grid (550, 2).
// y=0: xb @ {sym0,sym1,con0,con1} -> P01 {h1s|ds<<16}, P23 {h1c|dc<<16}
// y=1: db @ dis -> P4 (bf16)
// ---------------------------------------------------------------------------
__launch_bounds__(256)
__global__ void h_gemm(const bf16* __restrict__ xb, const bf16* __restrict__ db,
                       const short* __restrict__ WB,
                       unsigned* __restrict__ P01, unsigned* __restrict__ P23,
                       short* __restrict__ P4) {
    const int tid = threadIdx.x;
    const int w = tid >> 6, L = tid & 63;
    const int lane16 = L & 15, quad = L >> 4;
    const int R0 = blockIdx.x * 128 + w * 32;
    const bf16x8* WBf = (const bf16x8*)WB;

    if (blockIdx.y == 0) {
        f32x4 acc[4][2][4];   // [p][rt][nt]
        #pragma unroll
        for (int p = 0; p < 4; p++)
            #pragma unroll
            for (int rt = 0; rt < 2; rt++)
                #pragma unroll
                for (int nt = 0; nt < 4; nt++) acc[p][rt][nt] = (f32x4){0.f, 0.f, 0.f, 0.f};

        #pragma unroll
        for (int kc = 0; kc < 2; kc++) {
            bf16x8 av[2];
            #pragma unroll
            for (int rt = 0; rt < 2; rt++) {
                int row = R0 + rt * 16 + lane16;
                av[rt] = *(const bf16x8*)(xb + (size_t)row * 64 + kc * 32 + quad * 8);
            }
            #pragma unroll
            for (int p = 0; p < 4; p++)
                #pragma unroll
                for (int nt = 0; nt < 4; nt++) {
                    bf16x8 bw = WBf[((p * 2 + kc) * 4 + nt) * 64 + L];
                    acc[p][0][nt] = __builtin_amdgcn_mfma_f32_16x16x32_bf16(av[0], bw, acc[p][0][nt], 0, 0, 0);
                    acc[p][1][nt] = __builtin_amdgcn_mfma_f32_16x16x32_bf16(av[1], bw, acc[p][1][nt], 0, 0, 0);
                }
        }

        #pragma unroll
        for (int rt = 0; rt < 2; rt++)
            #pragma unroll
            for (int nt = 0; nt < 4; nt++)
                #pragma unroll
                for (int r = 0; r < 4; r++) {
                    size_t idx = (size_t)(R0 + rt * 16 + quad * 4 + r) * 64 + nt * 16 + lane16;
                    float h0s = acc[0][rt][nt][r], h1s = acc[1][rt][nt][r];
                    float h0c = acc[2][rt][nt][r], h1c = acc[3][rt][nt][r];
                    P01[idx] = (unsigned)(unsigned short)fbf(h1s) |
                               ((unsigned)(unsigned short)fbf(h0s - h1s) << 16);
                    P23[idx] = (unsigned)(unsigned short)fbf(h1c) |
                               ((unsigned)(unsigned short)fbf(h0c - h1c) << 16);
                }
    } else {
        f32x4 acc[2][4];
        #pragma unroll
        for (int rt = 0; rt < 2; rt++)
            #pragma unroll
            for (int nt = 0; nt < 4; nt++) acc[rt][nt] = (f32x4){0.f, 0.f, 0.f, 0.f};

        #pragma unroll
        for (int kc = 0; kc < 2; kc++) {
            bf16x8 av[2];
            #pragma unroll
            for (int rt = 0; rt < 2; rt++) {
                int row = R0 + rt * 16 + lane16;
                av[rt] = *(const bf16x8*)(db + (size_t)row * 64 + kc * 32 + quad * 8);
            }
            #pragma unroll
            for (int nt = 0; nt < 4; nt++) {
                bf16x8 bw = WBf[((4 * 2 + kc) * 4 + nt) * 64 + L];
                acc[0][nt] = __builtin_amdgcn_mfma_f32_16x16x32_bf16(av[0], bw, acc[0][nt], 0, 0, 0);
                acc[1][nt] = __builtin_amdgcn_mfma_f32_16x16x32_bf16(av[1], bw, acc[1][nt], 0, 0, 0);
            }
        }
        #pragma unroll
        for (int rt = 0; rt < 2; rt++)
            #pragma unroll
            for (int nt = 0; nt < 4; nt++)
                #pragma unroll
                for (int r = 0; r < 4; r++) {
                    size_t idx = (size_t)(R0 + rt * 16 + quad * 4 + r) * 64 + nt * 16 + lane16;
                    P4[idx] = fbf(acc[rt][nt][r]);
                }
    }
}

// ---------------------------------------------------------------------------
// Kernel 4: mixer v4 — 2 bt per block (verified R10/R11).
// ---------------------------------------------------------------------------
__launch_bounds__(256)
__global__ void mixer(const unsigned* __restrict__ P01, const unsigned* __restrict__ P23,
                      const short* __restrict__ P4, const short* __restrict__ AAb,
                      const float* __restrict__ att, const float* __restrict__ bdis,
                      bf16* __restrict__ xs, bf16* __restrict__ yc,
                      bf16* __restrict__ z, float* __restrict__ stats1) {
    __shared__ __align__(16) unsigned pp0[2 * NO];  // P01, both bts; reused as red
    __shared__ __align__(16) unsigned pp1[2 * NO];  // P23
    __shared__ __align__(16) short p2[2 * NO];      // P4
    __shared__ float attL[NN];
    float* red = (float*)pp0;

    const int g   = blockIdx.x;
    const int tid = threadIdx.x;
    const size_t base = (size_t)g * 2 * NO;
    const int w = tid >> 6, L = tid & 63;

    for (int idx = tid; idx < 1760; idx += 256) {
        if (idx < 704)       ((uint4*)pp0)[idx]        = ((const uint4*)(P01 + base))[idx];
        else if (idx < 1408) ((uint4*)pp1)[idx - 704]  = ((const uint4*)(P23 + base))[idx - 704];
        else                 ((uint4*)p2)[idx - 1408]  = ((const uint4*)(P4 + base))[idx - 1408];
    }
    for (int idx = tid; idx < NN; idx += 256) attL[idx] = att[idx];
    __syncthreads();

    float mxs[2][6], myc[2][6], mz[2][6];
    #pragma unroll
    for (int b = 0; b < 2; b++)
        #pragma unroll
        for (int k = 0; k < 6; k++) { mxs[b][k] = myc[b][k] = mz[b][k] = 0.f; }

    const unsigned* AAu = (const unsigned*)AAb;
    for (int j = 0; j < N_; j++) {
        float h1s[2], h1c[2], hw[2], dum;
        #pragma unroll
        for (int b = 0; b < 2; b++) {
            unp(pp0[b * NO + j * 64 + L], h1s[b], dum);
            unp(pp1[b * NO + j * 64 + L], h1c[b], dum);
            hw[b] = sbf(p2[b * NO + j * 64 + L]);
        }
        #pragma unroll
        for (int k = 0; k < 6; k++) {
            int i  = w + 4 * k;
            int ii = (i < N_) ? i : 0;
            unsigned a = AAu[(size_t)(ii * N_ + j) * 64 + L];
            float as, ac; unp(a, as, ac);
            float atv = attL[ii * N_ + j];
            #pragma unroll
            for (int b = 0; b < 2; b++) {
                mxs[b][k] = fmaf(as,  h1s[b], mxs[b][k]);
                myc[b][k] = fmaf(ac,  h1c[b], myc[b][k]);
                mz[b][k]  = fmaf(atv, hw[b],  mz[b][k]);
            }
        }
    }

    float bd = bdis[L];
    float st0 = 0.f, st1 = 0.f, st2 = 0.f, st3 = 0.f, st4 = 0.f, st5 = 0.f;
    #pragma unroll
    for (int k = 0; k < 6; k++) {
        int i = w + 4 * k;
        if (i < N_) {
            unsigned ad = AAu[(size_t)(i * 23) * 64 + L];
            float asd, acd; unp(ad, asd, acd);
            #pragma unroll
            for (int b = 0; b < 2; b++) {
                float dum, dsv, dcv;
                unp(pp0[b * NO + i * 64 + L], dum, dsv);
                unp(pp1[b * NO + i * 64 + L], dum, dcv);
                float xsv = mxs[b][k] + asd * dsv;
                float ycv = myc[b][k] + acd * dcv;
                float zv  = mz[b][k] + bd;
                size_t oi = base + b * NO + i * 64 + L;
                xs[oi] = f2bf(xsv); yc[oi] = f2bf(ycv); z[oi] = f2bf(zv);
                st0 += xsv; st1 += xsv * xsv;
                st2 += ycv; st3 += ycv * ycv;
                st4 += zv;  st5 += zv  * zv;
            }
        }
    }

    __syncthreads();                // all pp0 reads done; reuse as red
    red[(w * 6 + 0) * 64 + L] = st0;
    red[(w * 6 + 1) * 64 + L] = st1;
    red[(w * 6 + 2) * 64 + L] = st2;
    red[(w * 6 + 3) * 64 + L] = st3;
    red[(w * 6 + 4) * 64 + L] = st4;
    red[(w * 6 + 5) * 64 + L] = st5;
    __syncthreads();
    float* myStats = stats1 + (size_t)(g & 7) * 384;   // 8-way shard
    for (int qq = tid; qq < 384; qq += 256) {
        int q = qq >> 6, oo = qq & 63;
        float v = (red[q * 64 + oo] + red[(6 + q) * 64 + oo]) +
                  (red[(12 + q) * 64 + oo] + red[(18 + q) * 64 + oo]);
        atomicAdd(&myStats[qq], v);
    }
}

// ---------------------------------------------------------------------------
// Kernel 5: BN affine from (sharded) atomic stats (verified R9-R11).
// ---------------------------------------------------------------------------
__global__ void scale_from_stats(const float* __restrict__ stats,
                                 const float* __restrict__ gammas,
                                 const float* __restrict__ betas,
                                 int nch, int gbase, int nshard, int sstride,
                                 float* __restrict__ scale) {
    int tid = threadIdx.x;
    if (tid >= nch * 64) return;
    int t = tid >> 6, o = tid & 63;
    float S = 0.f, SS = 0.f;
    for (int s = 0; s < nshard; s++) {
        S  += stats[s * sstride + (2 * t) * 64 + o];
        SS += stats[s * sstride + (2 * t + 1) * 64 + o];
    }
    const float invn = 1.f / (float)BTN;
    float mu   = S * invn;
    float var  = SS * invn - mu * mu;
    float rstd = rsqrtf(var + 1e-5f);
    float a = gammas[(gbase + t) * 64 + o] * rstd;
    float c = betas[(gbase + t) * 64 + o] - mu * a;
    scale[t * 128 + o]      = a;
    scale[t * 128 + 64 + o] = c;
}

// ---------------------------------------------------------------------------
// Kernel 6: mix GEMM (verified R5-R11, unchanged).
// ---------------------------------------------------------------------------
__launch_bounds__(256)
__global__ void mix_pass(const bf16* __restrict__ xs, const bf16* __restrict__ yc,
                         const bf16* __restrict__ z, const float* __restrict__ scale1,
                         const short* __restrict__ CB,
                         bf16* __restrict__ out2, float* __restrict__ stats2) {
    __shared__ float sL[384];
    __shared__ float red[512];

    const int tid = threadIdx.x;
    const int w = tid >> 6, L = tid & 63;
    const int lane16 = L & 15, quad = L >> 4;
    const int R0 = blockIdx.x * 128 + w * 32;

    for (int idx = tid; idx < 384; idx += 256) sL[idx] = scale1[idx];
    __syncthreads();

    const bf16* srcs[3] = { xs, yc, z };

    f32x4 acc[2][4];
    #pragma unroll
    for (int rt = 0; rt < 2; rt++)
        #pragma unroll
        for (int nt = 0; nt < 4; nt++)
            acc[rt][nt] = (f32x4){0.f, 0.f, 0.f, 0.f};

    #pragma unroll
    for (int kc = 0; kc < 6; kc++) {
        const int src = kc >> 1;
        const int c0  = (kc & 1) * 32 + quad * 8;
        bf16x8 av[2];
        #pragma unroll
        for (int rt = 0; rt < 2; rt++) {
            int row = R0 + rt * 16 + lane16;
            uint4 u = *(const uint4*)(srcs[src] + (size_t)row * 64 + c0);
            float v[8];
            unp(u.x, v[0], v[1]); unp(u.y, v[2], v[3]);
            unp(u.z, v[4], v[5]); unp(u.w, v[6], v[7]);
            #pragma unroll
            for (int e = 0; e < 8; e++) {
                float t = fmaxf(fmaf(v[e], sL[src * 128 + c0 + e],
                                     sL[src * 128 + 64 + c0 + e]), 0.f);
                av[rt][e] = fbf(t);
            }
        }
        #pragma unroll
        for (int nt = 0; nt < 4; nt++) {
            bf16x8 bw = ((const bf16x8*)CB)[(nt * 6 + kc) * 64 + L];
            acc[0][nt] = __builtin_amdgcn_mfma_f32_16x16x32_bf16(av[0], bw, acc[0][nt], 0, 0, 0);
            acc[1][nt] = __builtin_amdgcn_mfma_f32_16x16x32_bf16(av[1], bw, acc[1][nt], 0, 0, 0);
        }
    }

    float s[4]  = {0.f, 0.f, 0.f, 0.f};
    float s2[4] = {0.f, 0.f, 0.f, 0.f};
    #pragma unroll
    for (int rt = 0; rt < 2; rt++)
        #pragma unroll
        for (int nt = 0; nt < 4; nt++)
            #pragma unroll
            for (int r = 0; r < 4; r++) {
                int row = R0 + rt * 16 + quad * 4 + r;
                int col = nt * 16 + lane16;
                float v = acc[rt][nt][r];
                out2[(size_t)row * 64 + col] = f2bf(v);
                s[nt] += v; s2[nt] += v * v;
            }
    #pragma unroll
    for (int nt = 0; nt < 4; nt++) {
        s[nt]  += __shfl_xor(s[nt], 16);
        s[nt]  += __shfl_xor(s[nt], 32);
        s2[nt] += __shfl_xor(s2[nt], 16);
        s2[nt] += __shfl_xor(s2[nt], 32);
    }
    if (quad == 0) {
        #pragma unroll
        for (int nt = 0; nt < 4; nt++) {
            red[w * 64 + nt * 16 + lane16]       = s[nt];
            red[256 + w * 64 + nt * 16 + lane16] = s2[nt];
        }
    }
    __syncthreads();
    if (tid < 64) {
        float t = red[tid] + red[64 + tid] + red[128 + tid] + red[192 + tid];
        atomicAdd(&stats2[tid], t);
    } else if (tid < 128) {
        int c = tid - 64;
        float t = red[256 + c] + red[320 + c] + red[384 + c] + red[448 + c];
        atomicAdd(&stats2[64 + c], t);
    }
}

// ---------------------------------------------------------------------------
// Kernel 7: final BN + ReLU + f32 store (verified, unchanged).
// ---------------------------------------------------------------------------
__global__ void final_pass(const bf16* __restrict__ out2, const float* __restrict__ scale2,
                           float* __restrict__ out) {
    const int gid = blockIdx.x * 256 + threadIdx.x;
    const int idx = gid * 4;
    ushort4 u = reinterpret_cast<const ushort4*>(out2)[gid];
    const int o = idx & 63;
    float f0, f1, f2, f3;
    unp((unsigned)u.x | ((unsigned)u.y << 16), f0, f1);
    unp((unsigned)u.z | ((unsigned)u.w << 16), f2, f3);
    float4 r;
    r.x = fmaxf(fmaf(f0, scale2[o],     scale2[64 + o]),     0.f);
    r.y = fmaxf(fmaf(f1, scale2[o + 1], scale2[64 + o + 1]), 0.f);
    r.z = fmaxf(fmaf(f2, scale2[o + 2], scale2[64 + o + 2]), 0.f);
    r.w = fmaxf(fmaf(f3, scale2[o + 3], scale2[64 + o + 3]), 0.f);
    reinterpret_cast<float4*>(out)[gid] = r;
}

// ---------------------------------------------------------------------------
extern "C" void kernel_launch(void* const* d_in, const int* in_sizes, int n_in,
                              void* d_out, int out_size, void* d_ws, size_t ws_size,
                              hipStream_t stream) {
    const float* x      = (const float*)d_in[0];
    const float* W_sym  = (const float*)d_in[1];
    const float* e_sym  = (const float*)d_in[2];
    const float* W_con  = (const float*)d_in[3];
    const float* e_con  = (const float*)d_in[4];
    const float* W_dis  = (const float*)d_in[5];
    const float* att    = (const float*)d_in[6];
    const float* b_dis  = (const float*)d_in[7];
    const float* cat_w  = (const float*)d_in[8];
    const float* gammas = (const float*)d_in[9];
    const float* betas  = (const float*)d_in[10];
    const int* rows_sym = (const int*)d_in[11];
    const int* cols_sym = (const int*)d_in[12];
    const int* rows_con = (const int*)d_in[13];
    const int* cols_con = (const int*)d_in[14];
    const int nnz_s = in_sizes[2] / 64;
    const int nnz_c = in_sizes[4] / 64;

    // Workspace carve. out2 aliases xb (dead after h_gemm; out2 written later).
    char* p = (char*)d_ws;
    float* stats  = (float*)p; p += (8 * 384 + 128) * 4;       // stats1 shards + stats2
    float* scale1 = (float*)p; p += 384 * 4;
    float* scale2 = (float*)p; p += 128 * 4;
    short* AAb    = (short*)p; p += (size_t)NN * 64 * 2 * 2;
    short* CB     = (short*)p; p += (size_t)1536 * 8 * 2;
    short* WB     = (short*)p; p += (size_t)2560 * 8 * 2;
    bf16*  xb     = (bf16*)p;  p += (size_t)ELEMS * 2;
    bf16*  db     = (bf16*)p;  p += (size_t)ELEMS * 2;
    bf16*  xsb    = (bf16*)p;  p += (size_t)ELEMS * 2;
    bf16*  ycb    = (bf16*)p;  p += (size_t)ELEMS * 2;
    bf16*  zb     = (bf16*)p;  p += (size_t)ELEMS * 2;
    unsigned* P01 = (unsigned*)p; p += (size_t)ELEMS * 4;      // {h1s|ds}
    unsigned* P23 = (unsigned*)p; p += (size_t)ELEMS * 4;      // {h1c|dc}
    short*    P4  = (short*)p;    p += (size_t)ELEMS * 2;      // hdw
    bf16*  out2   = xb;
    float* stats1 = stats;
    float* stats2 = stats + 8 * 384;

    hipMemsetAsync(stats, 0, (8 * 384 + 128) * 4, stream);
    hipMemsetAsync(AAb, 0, (size_t)NN * 64 * 2 * 2, stream);   // zero background for sparse AA
    prep_kernel<<<18, 256, 0, stream>>>(e_sym, rows_sym, cols_sym, nnz_s,
                                        e_con, rows_con, cols_con, nnz_c,
                                        cat_w, W_sym, W_con, W_dis, AAb, CB, WB);
    pre_pass<<<800, 256, 0, stream>>>(x, xb, db);
    h_gemm<<<dim3(550, 2), 256, 0, stream>>>(xb, db, WB, P01, P23, P4);
    mixer<<<1600, 256, 0, stream>>>(P01, P23, P4, AAb, att, b_dis, xsb, ycb, zb, stats1);
    scale_from_stats<<<1, 192, 0, stream>>>(stats1, gammas, betas, 3, 0, 8, 384, scale1);
    mix_pass<<<550, 256, 0, stream>>>(xsb, ycb, zb, scale1, CB, out2, stats2);
    scale_from_stats<<<1, 64, 0, stream>>>(stats2, gammas, betas, 1, 3, 1, 0, scale2);
    final_pass<<<ELEMS / 1024, 256, 0, stream>>>(out2, scale2, (float*)d_out);
}

// Round 13
// 200.292 us; speedup vs baseline: 4.9767x; 1.0832x over previous
//
#include <hip/hip_runtime.h>
#include <hip/hip_bf16.h>

typedef __hip_bfloat16 bf16;
typedef __attribute__((ext_vector_type(8))) short bf16x8;
typedef __attribute__((ext_vector_type(4))) float f32x4;

#define BT    3200
#define N_    22
#define NO    1408           // N_*64
#define NN    484
#define BTN   70400
#define ELEMS 4505600        // BT*N_*64
#define MAXNZ 128

static __device__ __forceinline__ bf16  f2bf(float v) { return __float2bfloat16(v); }
static __device__ __forceinline__ short fbf(float v) {
    bf16 h = __float2bfloat16(v);
    return *reinterpret_cast<short*>(&h);
}
static __device__ __forceinline__ float sbf(short s) {
    return __uint_as_float(((unsigned)(unsigned short)s) << 16);
}
static __device__ __forceinline__ void unp(unsigned u, float& lo, float& hi) {
    lo = __uint_as_float(u << 16);
    hi = __uint_as_float(u & 0xffff0000u);
}

// ---------------------------------------------------------------------------
// Kernel 1 (prep) v3 (verified R12): blocks 0-1 AA via LDS-staged exp(e);
// blocks 2-7 CB; blocks 8-17 WB.
// ---------------------------------------------------------------------------
__global__ void prep_kernel(const float* __restrict__ e_s, const int* __restrict__ rs,
                            const int* __restrict__ cs, int nnz_s,
                            const float* __restrict__ e_c, const int* __restrict__ rc,
                            const int* __restrict__ cc, int nnz_c,
                            const float* __restrict__ cat_w,
                            const float* __restrict__ Wsym, const float* __restrict__ Wcon,
                            const float* __restrict__ Wdis,
                            short* __restrict__ AAb, short* __restrict__ CB,
                            short* __restrict__ WB) {
    const int tid = threadIdx.x;
    if (blockIdx.x < 2) {
        __shared__ float eL[64 * (MAXNZ + 1)];
        __shared__ int rowsL[MAXNZ], colsL[MAXNZ];
        const int t = blockIdx.x;
        const float* e    = t ? e_c : e_s;
        const int*   rows = t ? rc  : rs;
        const int*   cols = t ? cc  : cs;
        const int    nnz  = t ? nnz_c : nnz_s;
        const int    str  = nnz + 1;

        for (int idx = tid; idx < 64 * nnz; idx += 256) {
            int o = idx / nnz, k = idx - o * nnz;
            eL[o * str + k] = expf(e[idx]);
        }
        for (int idx = tid; idx < nnz; idx += 256) { rowsL[idx] = rows[idx]; colsL[idx] = cols[idx]; }
        __syncthreads();

        const int o = tid & 63, ig = tid >> 6;
        float s[6];
        #pragma unroll
        for (int q = 0; q < 6; q++) s[q] = 0.f;
        for (int k = 0; k < nnz; k++) {
            int r = rowsL[k];
            float ev = eL[o * str + k];
            #pragma unroll
            for (int q = 0; q < 6; q++)
                if (r == ig + 4 * q) s[q] += ev;
        }
        float inv[6];
        #pragma unroll
        for (int q = 0; q < 6; q++) inv[q] = 1.f / s[q];
        for (int k = 0; k < nnz; k++) {
            int r = rowsL[k];
            #pragma unroll
            for (int q = 0; q < 6; q++)
                if (r == ig + 4 * q)
                    AAb[((size_t)(r * N_ + colsL[k]) * 64 + o) * 2 + t] =
                        fbf(eL[o * str + k] * inv[q]);
        }
    } else if (blockIdx.x < 8) {
        int gi = (blockIdx.x - 2) * 256 + tid;
        if (gi >= 1536) return;
        int nt = gi / 384, rem = gi % 384;
        int kc = rem >> 6, L = rem & 63;
        int n = nt * 16 + (L & 15);
        int kbase = kc * 32 + (L >> 4) * 8;
        float4 w0 = *(const float4*)&cat_w[n * 192 + kbase];
        float4 w1 = *(const float4*)&cat_w[n * 192 + kbase + 4];
        bf16x8 frag;
        frag[0] = fbf(w0.x); frag[1] = fbf(w0.y); frag[2] = fbf(w0.z); frag[3] = fbf(w0.w);
        frag[4] = fbf(w1.x); frag[5] = fbf(w1.y); frag[6] = fbf(w1.z); frag[7] = fbf(w1.w);
        ((bf16x8*)CB)[gi] = frag;
    } else {
        int gi = (blockIdx.x - 8) * 256 + tid;
        if (gi >= 2560) return;
        int L = gi & 63;
        int q = gi >> 6;
        int nt = q & 3;
        int pk = q >> 2;
        int kc = pk & 1;
        int p  = pk >> 1;
        const float* Wsrc = (p == 0) ? Wsym :
                            (p == 1) ? Wsym + 4096 :
                            (p == 2) ? Wcon :
                            (p == 3) ? Wcon + 4096 : Wdis;
        int n  = nt * 16 + (L & 15);
        int kb = kc * 32 + (L >> 4) * 8;
        bf16x8 frag;
        #pragma unroll
        for (int j = 0; j < 8; j++) frag[j] = fbf(Wsrc[(kb + j) * 64 + n]);
        ((bf16x8*)WB)[gi] = frag;
    }
}

// ---------------------------------------------------------------------------
// Kernel 2: stats + cast, 4 bt per block (verified R10-R12).
// ---------------------------------------------------------------------------
__launch_bounds__(256)
__global__ void pre_pass(const float* __restrict__ x,
                         bf16* __restrict__ xb, bf16* __restrict__ db) {
    __shared__ float xt[4 * NO];
    const int tid = threadIdx.x;
    const int w = tid >> 6, L = tid & 63;
    const size_t base = (size_t)blockIdx.x * 4 * NO;
    for (int idx = tid; idx < NO; idx += 256)
        ((float4*)xt)[idx] = ((const float4*)(x + base))[idx];
    __syncthreads();
    const float* xw = xt + w * NO;
    float s = 0.f, s2 = 0.f;
    #pragma unroll
    for (int i = 0; i < N_; i++) { float v = xw[i * 64 + L]; s += v; s2 += v * v; }
    const size_t wb = base + (size_t)w * NO;
    #pragma unroll
    for (int i = 0; i < N_; i++) {
        float v  = xw[i * 64 + L];
        float d2 = s2 - 2.f * v * s + (float)N_ * v * v;
        float d  = sqrtf(fmaxf(d2, 0.f)) + 1e-8f;
        xb[wb + i * 64 + L] = f2bf(v);
        db[wb + i * 64 + L] = f2bf(d);
    }
}

// ---------------------------------------------------------------------------
// Kernel 3: FUSED h-GEMM + mixer. grid 1600 (2 bt / block, 44 rows pad 48).
// Wave w owns output col-slice nt=w (16 cols). 5-plane MFMA (30/wave) from
// xb/db A-frags + WB B-frags (both verified), C packed into the SAME LDS
// words the verified mixer consumed: pp0={fbf(h1s)|fbf(h0s-h1s)<<16},
// pp1={h1c|dc}, p2=fbf(hdw). Then the verified R10-R12 mixing body.
// ---------------------------------------------------------------------------
__launch_bounds__(256)
__global__ void fused_hmix(const bf16* __restrict__ xb, const bf16* __restrict__ db,
                           const short* __restrict__ WB, const short* __restrict__ AAb,
                           const float* __restrict__ att, const float* __restrict__ bdis,
                           bf16* __restrict__ xs, bf16* __restrict__ yc,
                           bf16* __restrict__ z, float* __restrict__ stats1) {
    __shared__ __align__(16) unsigned pp0[2 * NO];  // reused as red post-mixing
    __shared__ __align__(16) unsigned pp1[2 * NO];
    __shared__ __align__(16) short p2[2 * NO];
    __shared__ float attL[NN];
    float* red = (float*)pp0;

    const int g   = blockIdx.x;
    const int tid = threadIdx.x;
    const size_t base = (size_t)g * 2 * NO;           // element base (g*44 rows)
    const int w = tid >> 6, L = tid & 63;
    const int lane16 = L & 15, quad = L >> 4;
    const bf16x8* WBf = (const bf16x8*)WB;

    for (int idx = tid; idx < NN; idx += 256) attL[idx] = att[idx];

    // ---- GEMM phase: 5 planes, 3 row-tiles (48 rows >= 44 valid), nt = w
    f32x4 acc[5][3];
    #pragma unroll
    for (int p = 0; p < 5; p++)
        #pragma unroll
        for (int rt = 0; rt < 3; rt++) acc[p][rt] = (f32x4){0.f, 0.f, 0.f, 0.f};

    #pragma unroll
    for (int kc = 0; kc < 2; kc++) {
        bf16x8 ax[3], ad[3];
        #pragma unroll
        for (int rt = 0; rt < 3; rt++) {
            int gr = g * 44 + rt * 16 + lane16;       // global row
            if (gr > BTN - 1) gr = BTN - 1;           // tail clamp (results unused)
            ax[rt] = *(const bf16x8*)(xb + (size_t)gr * 64 + kc * 32 + quad * 8);
            ad[rt] = *(const bf16x8*)(db + (size_t)gr * 64 + kc * 32 + quad * 8);
        }
        #pragma unroll
        for (int p = 0; p < 5; p++) {
            bf16x8 bw = WBf[((p * 2 + kc) * 4 + w) * 64 + L];
            #pragma unroll
            for (int rt = 0; rt < 3; rt++) {
                bf16x8 a = (p < 4) ? ax[rt] : ad[rt];
                acc[p][rt] = __builtin_amdgcn_mfma_f32_16x16x32_bf16(a, bw, acc[p][rt], 0, 0, 0);
            }
        }
    }

    // ---- epilogue -> LDS (C layout row=quad*4+r, col=w*16+lane16)
    {
        int col = w * 16 + lane16;
        #pragma unroll
        for (int rt = 0; rt < 3; rt++)
            #pragma unroll
            for (int r = 0; r < 4; r++) {
                int m = rt * 16 + quad * 4 + r;       // 0..47; m = b*22+i
                if (m < 44) {
                    float h0s = acc[0][rt][r], h1s = acc[1][rt][r];
                    float h0c = acc[2][rt][r], h1c = acc[3][rt][r];
                    pp0[m * 64 + col] = (unsigned)(unsigned short)fbf(h1s) |
                                        ((unsigned)(unsigned short)fbf(h0s - h1s) << 16);
                    pp1[m * 64 + col] = (unsigned)(unsigned short)fbf(h1c) |
                                        ((unsigned)(unsigned short)fbf(h0c - h1c) << 16);
                    p2[m * 64 + col] = fbf(acc[4][rt][r]);
                }
            }
    }
    __syncthreads();

    // ---- mixing phase (verified R10-R12 body, unchanged)
    float mxs[2][6], myc[2][6], mz[2][6];
    #pragma unroll
    for (int b = 0; b < 2; b++)
        #pragma unroll
        for (int k = 0; k < 6; k++) { mxs[b][k] = myc[b][k] = mz[b][k] = 0.f; }

    const unsigned* AAu = (const unsigned*)AAb;
    for (int j = 0; j < N_; j++) {
        float h1s[2], h1c[2], hw[2], dum;
        #pragma unroll
        for (int b = 0; b < 2; b++) {
            unp(pp0[b * NO + j * 64 + L], h1s[b], dum);
            unp(pp1[b * NO + j * 64 + L], h1c[b], dum);
            hw[b] = sbf(p2[b * NO + j * 64 + L]);
        }
        #pragma unroll
        for (int k = 0; k < 6; k++) {
            int i  = w + 4 * k;
            int ii = (i < N_) ? i : 0;
            unsigned a = AAu[(size_t)(ii * N_ + j) * 64 + L];
            float as, ac; unp(a, as, ac);
            float atv = attL[ii * N_ + j];
            #pragma unroll
            for (int b = 0; b < 2; b++) {
                mxs[b][k] = fmaf(as,  h1s[b], mxs[b][k]);
                myc[b][k] = fmaf(ac,  h1c[b], myc[b][k]);
                mz[b][k]  = fmaf(atv, hw[b],  mz[b][k]);
            }
        }
    }

    float bd = bdis[L];
    float st0 = 0.f, st1 = 0.f, st2 = 0.f, st3 = 0.f, st4 = 0.f, st5 = 0.f;
    #pragma unroll
    for (int k = 0; k < 6; k++) {
        int i = w + 4 * k;
        if (i < N_) {
            unsigned ad = AAu[(size_t)(i * 23) * 64 + L];
            float asd, acd; unp(ad, asd, acd);
            #pragma unroll
            for (int b = 0; b < 2; b++) {
                float dum, dsv, dcv;
                unp(pp0[b * NO + i * 64 + L], dum, dsv);
                unp(pp1[b * NO + i * 64 + L], dum, dcv);
                float xsv = mxs[b][k] + asd * dsv;
                float ycv = myc[b][k] + acd * dcv;
                float zv  = mz[b][k] + bd;
                size_t oi = base + b * NO + i * 64 + L;
                xs[oi] = f2bf(xsv); yc[oi] = f2bf(ycv); z[oi] = f2bf(zv);
                st0 += xsv; st1 += xsv * xsv;
                st2 += ycv; st3 += ycv * ycv;
                st4 += zv;  st5 += zv  * zv;
            }
        }
    }

    __syncthreads();                // all pp0 reads done; reuse as red
    red[(w * 6 + 0) * 64 + L] = st0;
    red[(w * 6 + 1) * 64 + L] = st1;
    red[(w * 6 + 2) * 64 + L] = st2;
    red[(w * 6 + 3) * 64 + L] = st3;
    red[(w * 6 + 4) * 64 + L] = st4;
    red[(w * 6 + 5) * 64 + L] = st5;
    __syncthreads();
    float* myStats = stats1 + (size_t)(g & 7) * 384;   // 8-way shard
    for (int qq = tid; qq < 384; qq += 256) {
        int q = qq >> 6, oo = qq & 63;
        float v = (red[q * 64 + oo] + red[(6 + q) * 64 + oo]) +
                  (red[(12 + q) * 64 + oo] + red[(18 + q) * 64 + oo]);
        atomicAdd(&myStats[qq], v);
    }
}

// ---------------------------------------------------------------------------
// Kernel 4: BN affine from (sharded) atomic stats (verified R9-R12).
// ---------------------------------------------------------------------------
__global__ void scale_from_stats(const float* __restrict__ stats,
                                 const float* __restrict__ gammas,
                                 const float* __restrict__ betas,
                                 int nch, int gbase, int nshard, int sstride,
                                 float* __restrict__ scale) {
    int tid = threadIdx.x;
    if (tid >= nch * 64) return;
    int t = tid >> 6, o = tid & 63;
    float S = 0.f, SS = 0.f;
    for (int s = 0; s < nshard; s++) {
        S  += stats[s * sstride + (2 * t) * 64 + o];
        SS += stats[s * sstride + (2 * t + 1) * 64 + o];
    }
    const float invn = 1.f / (float)BTN;
    float mu   = S * invn;
    float var  = SS * invn - mu * mu;
    float rstd = rsqrtf(var + 1e-5f);
    float a = gammas[(gbase + t) * 64 + o] * rstd;
    float c = betas[(gbase + t) * 64 + o] - mu * a;
    scale[t * 128 + o]      = a;
    scale[t * 128 + 64 + o] = c;
}

// ---------------------------------------------------------------------------
// Kernel 5: mix GEMM (verified R5-R12, unchanged).
// ---------------------------------------------------------------------------
__launch_bounds__(256)
__global__ void mix_pass(const bf16* __restrict__ xs, const bf16* __restrict__ yc,
                         const bf16* __restrict__ z, const float* __restrict__ scale1,
                         const short* __restrict__ CB,
                         bf16* __restrict__ out2, float* __restrict__ stats2) {
    __shared__ float sL[384];
    __shared__ float red[512];

    const int tid = threadIdx.x;
    const int w = tid >> 6, L = tid & 63;
    const int lane16 = L & 15, quad = L >> 4;
    const int R0 = blockIdx.x * 128 + w * 32;

    for (int idx = tid; idx < 384; idx += 256) sL[idx] = scale1[idx];
    __syncthreads();

    const bf16* srcs[3] = { xs, yc, z };

    f32x4 acc[2][4];
    #pragma unroll
    for (int rt = 0; rt < 2; rt++)
        #pragma unroll
        for (int nt = 0; nt < 4; nt++)
            acc[rt][nt] = (f32x4){0.f, 0.f, 0.f, 0.f};

    #pragma unroll
    for (int kc = 0; kc < 6; kc++) {
        const int src = kc >> 1;
        const int c0  = (kc & 1) * 32 + quad * 8;
        bf16x8 av[2];
        #pragma unroll
        for (int rt = 0; rt < 2; rt++) {
            int row = R0 + rt * 16 + lane16;
            uint4 u = *(const uint4*)(srcs[src] + (size_t)row * 64 + c0);
            float v[8];
            unp(u.x, v[0], v[1]); unp(u.y, v[2], v[3]);
            unp(u.z, v[4], v[5]); unp(u.w, v[6], v[7]);
            #pragma unroll
            for (int e = 0; e < 8; e++) {
                float t = fmaxf(fmaf(v[e], sL[src * 128 + c0 + e],
                                     sL[src * 128 + 64 + c0 + e]), 0.f);
                av[rt][e] = fbf(t);
            }
        }
        #pragma unroll
        for (int nt = 0; nt < 4; nt++) {
            bf16x8 bw = ((const bf16x8*)CB)[(nt * 6 + kc) * 64 + L];
            acc[0][nt] = __builtin_amdgcn_mfma_f32_16x16x32_bf16(av[0], bw, acc[0][nt], 0, 0, 0);
            acc[1][nt] = __builtin_amdgcn_mfma_f32_16x16x32_bf16(av[1], bw, acc[1][nt], 0, 0, 0);
        }
    }

    float s[4]  = {0.f, 0.f, 0.f, 0.f};
    float s2[4] = {0.f, 0.f, 0.f, 0.f};
    #pragma unroll
    for (int rt = 0; rt < 2; rt++)
        #pragma unroll
        for (int nt = 0; nt < 4; nt++)
            #pragma unroll
            for (int r = 0; r < 4; r++) {
                int row = R0 + rt * 16 + quad * 4 + r;
                int col = nt * 16 + lane16;
                float v = acc[rt][nt][r];
                out2[(size_t)row * 64 + col] = f2bf(v);
                s[nt] += v; s2[nt] += v * v;
            }
    #pragma unroll
    for (int nt = 0; nt < 4; nt++) {
        s[nt]  += __shfl_xor(s[nt], 16);
        s[nt]  += __shfl_xor(s[nt], 32);
        s2[nt] += __shfl_xor(s2[nt], 16);
        s2[nt] += __shfl_xor(s2[nt], 32);
    }
    if (quad == 0) {
        #pragma unroll
        for (int nt = 0; nt < 4; nt++) {
            red[w * 64 + nt * 16 + lane16]       = s[nt];
            red[256 + w * 64 + nt * 16 + lane16] = s2[nt];
        }
    }
    __syncthreads();
    if (tid < 64) {
        float t = red[tid] + red[64 + tid] + red[128 + tid] + red[192 + tid];
        atomicAdd(&stats2[tid], t);
    } else if (tid < 128) {
        int c = tid - 64;
        float t = red[256 + c] + red[320 + c] + red[384 + c] + red[448 + c];
        atomicAdd(&stats2[64 + c], t);
    }
}

// ---------------------------------------------------------------------------
// Kernel 6: final BN + ReLU + f32 store (verified, unchanged).
// ---------------------------------------------------------------------------
__global__ void final_pass(const bf16* __restrict__ out2, const float* __restrict__ scale2,
                           float* __restrict__ out) {
    const int gid = blockIdx.x * 256 + threadIdx.x;
    const int idx = gid * 4;
    ushort4 u = reinterpret_cast<const ushort4*>(out2)[gid];
    const int o = idx & 63;
    float f0, f1, f2, f3;
    unp((unsigned)u.x | ((unsigned)u.y << 16), f0, f1);
    unp((unsigned)u.z | ((unsigned)u.w << 16), f2, f3);
    float4 r;
    r.x = fmaxf(fmaf(f0, scale2[o],     scale2[64 + o]),     0.f);
    r.y = fmaxf(fmaf(f1, scale2[o + 1], scale2[64 + o + 1]), 0.f);
    r.z = fmaxf(fmaf(f2, scale2[o + 2], scale2[64 + o + 2]), 0.f);
    r.w = fmaxf(fmaf(f3, scale2[o + 3], scale2[64 + o + 3]), 0.f);
    reinterpret_cast<float4*>(out)[gid] = r;
}

// ---------------------------------------------------------------------------
extern "C" void kernel_launch(void* const* d_in, const int* in_sizes, int n_in,
                              void* d_out, int out_size, void* d_ws, size_t ws_size,
                              hipStream_t stream) {
    const float* x      = (const float*)d_in[0];
    const float* W_sym  = (const float*)d_in[1];
    const float* e_sym  = (const float*)d_in[2];
    const float* W_con  = (const float*)d_in[3];
    const float* e_con  = (const float*)d_in[4];
    const float* W_dis  = (const float*)d_in[5];
    const float* att    = (const float*)d_in[6];
    const float* b_dis  = (const float*)d_in[7];
    const float* cat_w  = (const float*)d_in[8];
    const float* gammas = (const float*)d_in[9];
    const float* betas  = (const float*)d_in[10];
    const int* rows_sym = (const int*)d_in[11];
    const int* cols_sym = (const int*)d_in[12];
    const int* rows_con = (const int*)d_in[13];
    const int* cols_con = (const int*)d_in[14];
    const int nnz_s = in_sizes[2] / 64;
    const int nnz_c = in_sizes[4] / 64;

    // Workspace carve. out2 aliases xb (dead after fused_hmix; written later).
    char* p = (char*)d_ws;
    float* stats  = (float*)p; p += (8 * 384 + 128) * 4;
    float* scale1 = (float*)p; p += 384 * 4;
    float* scale2 = (float*)p; p += 128 * 4;
    short* AAb    = (short*)p; p += (size_t)NN * 64 * 2 * 2;
    short* CB     = (short*)p; p += (size_t)1536 * 8 * 2;
    short* WB     = (short*)p; p += (size_t)2560 * 8 * 2;
    bf16*  xb     = (bf16*)p;  p += (size_t)ELEMS * 2;
    bf16*  db     = (bf16*)p;  p += (size_t)ELEMS * 2;
    bf16*  xsb    = (bf16*)p;  p += (size_t)ELEMS * 2;
    bf16*  ycb    = (bf16*)p;  p += (size_t)ELEMS * 2;
    bf16*  zb     = (bf16*)p;  p += (size_t)ELEMS * 2;
    bf16*  out2   = xb;
    float* stats1 = stats;
    float* stats2 = stats + 8 * 384;

    hipMemsetAsync(stats, 0, (8 * 384 + 128) * 4, stream);
    hipMemsetAsync(AAb, 0, (size_t)NN * 64 * 2 * 2, stream);
    prep_kernel<<<18, 256, 0, stream>>>(e_sym, rows_sym, cols_sym, nnz_s,
                                        e_con, rows_con, cols_con, nnz_c,
                                        cat_w, W_sym, W_con, W_dis, AAb, CB, WB);
    pre_pass<<<800, 256, 0, stream>>>(x, xb, db);
    fused_hmix<<<1600, 256, 0, stream>>>(xb, db, WB, AAb, att, b_dis,
                                         xsb, ycb, zb, stats1);
    scale_from_stats<<<1, 192, 0, stream>>>(stats1, gammas, betas, 3, 0, 8, 384, scale1);
    mix_pass<<<550, 256, 0, stream>>>(xsb, ycb, zb, scale1, CB, out2, stats2);
    scale_from_stats<<<1, 64, 0, stream>>>(stats2, gammas, betas, 1, 3, 1, 0, scale2);
    final_pass<<<ELEMS / 1024, 256, 0, stream>>>(out2, scale2, (float*)d_out);
}